// Round 12
// baseline (1871.823 us; speedup 1.0000x reference)
//
#include <hip/hip_runtime.h>
#include <stdint.h>

#define B_ 4
#define N_ 8192
#define K_ 16
#define FEAT_ 512
#define GRID_ 45
#define M_ (GRID_*GRID_)

typedef unsigned long long ull;
typedef __bf16 bf16x8 __attribute__((ext_vector_type(8)));
typedef float f32x16 __attribute__((ext_vector_type(16)));

// ---------- helpers ----------

__device__ __forceinline__ unsigned int fmap(float f){
  unsigned int u = __float_as_uint(f);
  return (u & 0x80000000u) ? ~u : (u | 0x80000000u);
}
__device__ __forceinline__ float funmap(unsigned int u){
  return (u & 0x80000000u) ? __uint_as_float(u ^ 0x80000000u) : __uint_as_float(~u);
}

// sorted top-16 insert on packed (fmap(dist)<<32 | idx) keys: lex order ==
// jax.lax.top_k tie-break (lower index first). Order-independent.
__device__ __forceinline__ void ins16(ull (&d)[16], ull k){
  if (k < d[15]){
    bool c[16];
#pragma unroll
    for (int s = 0; s < 16; ++s) c[s] = k < d[s];
#pragma unroll
    for (int s = 15; s >= 1; --s) d[s] = c[s-1] ? d[s-1] : (c[s] ? k : d[s]);
    if (c[0]) d[0] = k;
  }
}

// stable u32-key/u32-idx sorted insert, strict < : with ascending-idx scan
// order this reproduces (dist, idx) lex semantics exactly at ~70% the cost.
__device__ __forceinline__ void ins16b(unsigned (&dk)[16], unsigned (&di)[16],
                                       unsigned k, unsigned id){
  if (k < dk[16-1]){
    bool c[16];
#pragma unroll
    for (int s = 0; s < 16; ++s) c[s] = k < dk[s];
#pragma unroll
    for (int s = 15; s >= 1; --s){
      dk[s] = c[s-1] ? dk[s-1] : (c[s] ? k  : dk[s]);
      di[s] = c[s-1] ? di[s-1] : (c[s] ? id : di[s]);
    }
    if (c[0]){ dk[0] = k; di[0] = id; }
  }
}

#define GLDS16(l, g) __builtin_amdgcn_global_load_lds((const __attribute__((address_space(1))) void*)(g), (__attribute__((address_space(3))) void*)(l), 16, 0, 0)
#define GLDS4(l, g)  __builtin_amdgcn_global_load_lds((const __attribute__((address_space(1))) void*)(g), (__attribute__((address_space(3))) void*)(l), 4, 0, 0)

#define KEY_INF 0xFF800000FFFFFFFFull

// ---------- init ----------
__global__ void k_init(unsigned int* glob){
  int i = blockIdx.x*256 + threadIdx.x;
  if (i < B_*1024) glob[i] = 0x007FFFFFu;   // fmap(-inf)
}

// ---------- KNN #1: nearest other point (exact fp32) ----------
__global__ __launch_bounds__(256) void k_nn1(const float* __restrict__ pts,
                                             unsigned long long* __restrict__ nn64){
  __shared__ float sp[2048*3];
  int b = blockIdx.z, s = blockIdx.y;
  int c0 = s*2048;
  const float* P = pts + (size_t)b*N_*3;
  for (int i = threadIdx.x; i < 2048*3; i += 256) sp[i] = P[c0*3 + i];
  __syncthreads();
  int n = blockIdx.x*256 + threadIdx.x;
  float qx = P[n*3], qy = P[n*3+1], qz = P[n*3+2];
  float best = 1e30f; int bi = 0;
  for (int j = 0; j < 2048; ++j){
    float dx = qx - sp[j*3], dy = qy - sp[j*3+1], dz = qz - sp[j*3+2];
    float d2 = fmaf(dx,dx, fmaf(dy,dy, dz*dz));
    int cj = c0 + j;
    if (d2 < best && cj != n){ best = d2; bi = cj; }
  }
  unsigned long long key = ((unsigned long long)__float_as_uint(best) << 32) | (unsigned int)bi;
  atomicMin(&nn64[(size_t)b*N_ + n], key);
}

// ---------- local_cov + 3 convs (12->64->64->64, relu each) ----------
__global__ __launch_bounds__(256) void k_cov_mlp(const float* __restrict__ pts,
    const unsigned long long* __restrict__ nn64,
    const float* __restrict__ w1, const float* __restrict__ b1,
    const float* __restrict__ w2, const float* __restrict__ b2,
    const float* __restrict__ w3, const float* __restrict__ b3,
    float* __restrict__ xout){
  __shared__ __align__(16) float W1t[12*64];
  __shared__ __align__(16) float W2t[64*64];
  __shared__ __align__(16) float W3t[64*64];
  __shared__ float B1[64], B2[64], B3[64];
  __shared__ __align__(16) float x0[64][12];
  __shared__ __align__(16) float h1[64][64];
  __shared__ __align__(16) float h2[64][64];
  int b = blockIdx.y; int n0 = blockIdx.x*64; int tid = threadIdx.x;
  for (int i = tid; i < 12*64; i += 256){ int o = i % 64, ci = i / 64; W1t[i] = w1[o*12 + ci]; }
  for (int i = tid; i < 64*64; i += 256){ int o = i % 64, ci = i / 64; W2t[i] = w2[o*64 + ci]; W3t[i] = w3[o*64 + ci]; }
  if (tid < 64){ B1[tid]=b1[tid]; B2[tid]=b2[tid]; B3[tid]=b3[tid]; }
  {
    int p = tid % 64, cg = tid / 64;
    int n = n0 + p;
    const float* P = pts + ((size_t)b*N_ + n)*3;
    int nb = (int)(nn64[(size_t)b*N_ + n] & 0xFFFFFFFFull);
    const float* Q = pts + ((size_t)b*N_ + nb)*3;
    if (cg == 0){ x0[p][0]=P[0]; x0[p][1]=P[1]; x0[p][2]=P[2]; }
    else { int i = cg-1; float pi = P[i];
      x0[p][3+i*3+0]=pi*Q[0]; x0[p][3+i*3+1]=pi*Q[1]; x0[p][3+i*3+2]=pi*Q[2]; }
  }
  __syncthreads();
  { int o = tid % 64, pg = tid / 64;
    for (int p = pg; p < 64; p += 4){
      float acc = B1[o];
#pragma unroll
      for (int ci = 0; ci < 12; ++ci) acc = fmaf(W1t[ci*64+o], x0[p][ci], acc);
      h1[p][o] = fmaxf(acc, 0.f);
    } }
  __syncthreads();
  { int o = tid % 64, pg = tid / 64;
    for (int p = pg; p < 64; p += 4){
      float acc = B2[o];
#pragma unroll
      for (int ci = 0; ci < 64; ++ci) acc = fmaf(W2t[ci*64+o], h1[p][ci], acc);
      h2[p][o] = fmaxf(acc, 0.f);
    } }
  __syncthreads();
  { int o = tid % 64, pg = tid / 64;
    for (int p = pg; p < 64; p += 4){
      float acc = B3[o];
#pragma unroll
      for (int ci = 0; ci < 64; ++ci) acc = fmaf(W3t[ci*64+o], h2[p][ci], acc);
      xout[((size_t)b*N_ + n0 + p)*64 + o] = fmaxf(acc, 0.f);
    } }
}

// ---------- prep: bf16 hi/lo split into K-major granule layout + norms ----------
// T layout: [b][kf][pl 2][hi8 2][n 8192][16B granule]; granule = 8 bf16 ch.
template<int KF>
__global__ __launch_bounds__(256) void k_prep4(const float* __restrict__ f,
    unsigned short* __restrict__ T, float* __restrict__ cc){
  int b = blockIdx.y; int n = blockIdx.x*256 + threadIdx.x;
  const float* src = f + ((size_t)b*N_ + n)*(KF*16);
  char* Tb = (char*)T;
  float ss = 0.f;
#pragma unroll
  for (int kf = 0; kf < KF; ++kf){
    float v[16];
#pragma unroll
    for (int c4 = 0; c4 < 4; ++c4){
      float4 t4 = *(const float4*)&src[kf*16 + c4*4];
      v[c4*4]=t4.x; v[c4*4+1]=t4.y; v[c4*4+2]=t4.z; v[c4*4+3]=t4.w;
    }
    unsigned short hs[16], ls[16];
#pragma unroll
    for (int c = 0; c < 16; ++c){
      float x = v[c];
      ss = fmaf(x, x, ss);
      __bf16 h = (__bf16)x;
      __bf16 l = (__bf16)(x - (float)h);
      hs[c] = __builtin_bit_cast(unsigned short, h);
      ls[c] = __builtin_bit_cast(unsigned short, l);
    }
    size_t base = ((((size_t)b*KF + kf)*2)*2)*(size_t)(N_*16) + (size_t)n*16;
    const size_t HS = (size_t)N_*16;           // hi8 stride
    const size_t PS = 2*HS;                    // plane stride
    *(uint4*)(Tb + base)            = *(uint4*)&hs[0];
    *(uint4*)(Tb + base + HS)       = *(uint4*)&hs[8];
    *(uint4*)(Tb + base + PS)       = *(uint4*)&ls[0];
    *(uint4*)(Tb + base + PS + HS)  = *(uint4*)&ls[8];
  }
  cc[(size_t)b*N_ + n] = ss;
}

// ---------- fused single-pass KNN: MFMA + LDS-queued stable u32 top-16 ----------
// Slot-major queue P[slot][tid] (conflict-free); push ~6 instr; drains are
// wave-coherent but rare; drain reads LDS directly (no register snapshot).
template<int KF, int MW, int S>
__global__ __launch_bounds__(256, MW) void k_knnF(const unsigned short* __restrict__ T,
    const float* __restrict__ ccg, ull* __restrict__ qkeys){
  extern __shared__ char smem[];
  constexpr int NT = (N_/S)/64;
  char* As = smem;                              // KF*4096
  char* Cs = smem + KF*4096;                    // 256
  unsigned* Pk = (unsigned*)(smem + KF*4096 + 256);       // [8][256]
  unsigned* Pi = Pk + 8*256;                              // [8][256]

  const int tid = threadIdx.x, lane = tid & 63, wid = tid >> 6;
  const int hi = lane >> 5, l31 = lane & 31;
  const int b = blockIdx.z, sp = blockIdx.y, q0 = blockIdx.x*128;
  const int c0 = sp*(N_/S);
  const char* Tb = (const char*)T;
  const size_t HS = (size_t)N_*16, PS = 2*HS, KS = 4*HS;
  const size_t Bb = (size_t)b*KF*KS;
  const float* ccb = ccg + (size_t)b*N_;

  const int q = q0 + wid*32 + l31;
  bf16x8 qh[KF], ql[KF];
#pragma unroll
  for (int kf = 0; kf < KF; ++kf){
    size_t o = Bb + kf*KS + hi*HS + (size_t)q*16;
    qh[kf] = *(const bf16x8*)(Tb + o);
    ql[kf] = *(const bf16x8*)(Tb + o + PS);
  }

  unsigned dk[16], di[16];
#pragma unroll
  for (int t = 0; t < 16; ++t){ dk[t] = 0xFFFFFFFFu; di[t] = 0xFFFFFFFFu; }
  float kapf = __builtin_inff();
  int cnt = 0;

  auto drain = [&](){
#pragma unroll
    for (int t = 0; t < 8; ++t)
      if (t < cnt) ins16b(dk, di, Pk[t*256 + tid], Pi[t*256 + tid]);
    cnt = 0;
    unsigned kk = dk[15];
    kapf = (kk >= 0xFF800000u) ? __builtin_inff() : funmap(kk);
  };

  auto stage = [&](int t0){
#pragma unroll
    for (int si = 0; si < KF; ++si){
      int s = wid + 4*si;
      int kf = s >> 2, pl = (s >> 1) & 1, h = s & 1;
      GLDS16(As + s*1024,
             Tb + Bb + kf*KS + pl*PS + h*HS + (size_t)(c0 + t0)*16);
    }
    if (wid == 0) GLDS4(Cs, (const char*)(ccb + c0 + t0));
  };

  for (int t = 0; t < NT; ++t){
    const int t0 = t*64;
    __syncthreads();                   // all waves done reading previous tile
    stage(t0);
    asm volatile("s_waitcnt vmcnt(0)" ::: "memory");
    __syncthreads();                   // tile visible to all waves

    const char* Ab = As + hi*1024 + l31*16;
    const float* cct = (const float*)Cs;
#pragma unroll
    for (int i = 0; i < 2; ++i){
      f32x16 acc = (f32x16)(0.f);
#pragma unroll
      for (int kf = 0; kf < KF; ++kf){
        bf16x8 ah = *(const bf16x8*)(Ab + kf*4096 + i*512);
        bf16x8 al = *(const bf16x8*)(Ab + kf*4096 + 2048 + i*512);
        acc = __builtin_amdgcn_mfma_f32_32x32x16_bf16(ah, qh[kf], acc, 0, 0, 0);
        acc = __builtin_amdgcn_mfma_f32_32x32x16_bf16(ah, ql[kf], acc, 0, 0, 0);
        acc = __builtin_amdgcn_mfma_f32_32x32x16_bf16(al, qh[kf], acc, 0, 0, 0);
      }
      // v = cc - 2<q,c> (qq dropped: constant per-query shift, order-preserving)
      if (t == 0){
        // seed tile: unconditional inserts -> tight kappa, no queue storm
#pragma unroll
        for (int rq = 0; rq < 4; ++rq){
          float4 c4 = *(const float4*)(cct + i*32 + 4*hi + 8*rq);
          int rowb = c0 + i*32 + 4*hi + 8*rq;
          ins16b(dk, di, fmap(fmaf(-2.f, acc[rq*4+0], c4.x)), (unsigned)(rowb+0));
          ins16b(dk, di, fmap(fmaf(-2.f, acc[rq*4+1], c4.y)), (unsigned)(rowb+1));
          ins16b(dk, di, fmap(fmaf(-2.f, acc[rq*4+2], c4.z)), (unsigned)(rowb+2));
          ins16b(dk, di, fmap(fmaf(-2.f, acc[rq*4+3], c4.w)), (unsigned)(rowb+3));
        }
        unsigned kk = dk[15];
        kapf = (kk >= 0xFF800000u) ? __builtin_inff() : funmap(kk);
      } else {
#pragma unroll
        for (int rq = 0; rq < 4; ++rq){
          float4 c4 = *(const float4*)(cct + i*32 + 4*hi + 8*rq);
          int rowb = c0 + t0 + i*32 + 4*hi + 8*rq;
          float v0 = fmaf(-2.f, acc[rq*4+0], c4.x);
          float v1 = fmaf(-2.f, acc[rq*4+1], c4.y);
          float v2 = fmaf(-2.f, acc[rq*4+2], c4.z);
          float v3 = fmaf(-2.f, acc[rq*4+3], c4.w);
          if (fminf(fminf(v0, v1), fminf(v2, v3)) < kapf){
            if (v0 < kapf){ Pk[cnt*256+tid] = fmap(v0); Pi[cnt*256+tid] = (unsigned)(rowb+0); ++cnt; }
            if (v1 < kapf){ Pk[cnt*256+tid] = fmap(v1); Pi[cnt*256+tid] = (unsigned)(rowb+1); ++cnt; }
            if (v2 < kapf){ Pk[cnt*256+tid] = fmap(v2); Pi[cnt*256+tid] = (unsigned)(rowb+2); ++cnt; }
            if (v3 < kapf){ Pk[cnt*256+tid] = fmap(v3); Pi[cnt*256+tid] = (unsigned)(rowb+3); ++cnt; }
          }
          if (__any(cnt >= 5)) drain();
        }
      }
    }
  }
  drain();
  // write region (q, sp, hi): 16 packed keys, sentinel-padded
  ull* op = qkeys + (((size_t)((size_t)b*N_ + q)*S + sp)*2 + hi)*16;
#pragma unroll
  for (int t = 0; t < 16; ++t) op[t] = ((ull)dk[t] << 32) | di[t];
}

// ---------- final exact top-16 over S*2 regions x 16 keys ----------
template<int S>
__global__ void k_sel(const ull* __restrict__ qkeys, int* __restrict__ idxout){
  int i = blockIdx.x*256 + threadIdx.x;
  if (i >= B_*N_) return;
  ull best[16];
#pragma unroll
  for (int t = 0; t < 16; ++t) best[t] = KEY_INF;
  const ull* kp = qkeys + (size_t)i*(S*32);
  for (int t = 0; t < S*32; ++t) ins16(best, kp[t]);
  int* op = idxout + (size_t)i*16;
#pragma unroll
  for (int t = 0; t < 16; ++t) op[t] = (int)(best[t] & 0xffffffffu);
}

// ---------- maxpool(x) + conv 64->64 relu + conv 64->128 ----------
__global__ __launch_bounds__(256) void k_gpool_mlp(const float* __restrict__ x,
    const int* __restrict__ idx,
    const float* __restrict__ g1a, const float* __restrict__ g1ab,
    const float* __restrict__ g1b, const float* __restrict__ g1bb,
    float* __restrict__ gout){
  __shared__ __align__(16) float Wt1[64*64];
  __shared__ __align__(16) float Wt2[64*128];
  __shared__ float Ba[64], Bb[128];
  __shared__ __align__(16) float m[64][64];
  __shared__ __align__(16) float r[64][64];
  int b = blockIdx.y; int n0 = blockIdx.x*64; int tid = threadIdx.x;
  for (int i = tid; i < 64*64; i += 256){ int o = i%64, ci = i/64; Wt1[i] = g1a[o*64+ci]; }
  for (int i = tid; i < 64*128; i += 256){ int o = i%128, ci = i/128; Wt2[i] = g1b[o*64+ci]; }
  if (tid < 64) Ba[tid] = g1ab[tid];
  if (tid < 128) Bb[tid] = g1bb[tid];
  { int p = tid/4, cg = tid%4; int n = n0 + p;
    const int* ip = idx + ((size_t)b*N_ + n)*16;
    float mm[16];
#pragma unroll
    for (int u = 0; u < 16; ++u) mm[u] = -1e30f;
    for (int k = 0; k < 16; ++k){
      int nb = ip[k];
      const float4* src = (const float4*)(x + ((size_t)b*N_ + nb)*64 + cg*16);
#pragma unroll
      for (int u = 0; u < 4; ++u){
        float4 v = src[u];
        mm[4*u  ] = fmaxf(mm[4*u  ], v.x); mm[4*u+1] = fmaxf(mm[4*u+1], v.y);
        mm[4*u+2] = fmaxf(mm[4*u+2], v.z); mm[4*u+3] = fmaxf(mm[4*u+3], v.w);
      }
    }
#pragma unroll
    for (int u = 0; u < 16; ++u) m[p][cg*16+u] = mm[u];
  }
  __syncthreads();
  { int o = tid%64, pg = tid/64;
    float acc[16];
#pragma unroll
    for (int u = 0; u < 16; ++u) acc[u] = Ba[o];
    for (int ci = 0; ci < 64; ci += 4){
      float w0 = Wt1[ci*64+o], w1_ = Wt1[(ci+1)*64+o], w2_ = Wt1[(ci+2)*64+o], w3_ = Wt1[(ci+3)*64+o];
#pragma unroll
      for (int u = 0; u < 16; ++u){
        float4 mv = *(const float4*)&m[pg*16+u][ci];
        acc[u] = fmaf(w0, mv.x, acc[u]); acc[u] = fmaf(w1_, mv.y, acc[u]);
        acc[u] = fmaf(w2_, mv.z, acc[u]); acc[u] = fmaf(w3_, mv.w, acc[u]);
      }
    }
#pragma unroll
    for (int u = 0; u < 16; ++u) r[pg*16+u][o] = fmaxf(acc[u], 0.f);
  }
  __syncthreads();
  { int o = tid%128, pg = tid/128;   // no relu on this conv
    float acc[32];
#pragma unroll
    for (int u = 0; u < 32; ++u) acc[u] = Bb[o];
    for (int ci = 0; ci < 64; ci += 4){
      float w0 = Wt2[ci*128+o], w1_ = Wt2[(ci+1)*128+o], w2_ = Wt2[(ci+2)*128+o], w3_ = Wt2[(ci+3)*128+o];
#pragma unroll
      for (int u = 0; u < 32; ++u){
        float4 rv = *(const float4*)&r[pg*32+u][ci];
        acc[u] = fmaf(w0, rv.x, acc[u]); acc[u] = fmaf(w1_, rv.y, acc[u]);
        acc[u] = fmaf(w2_, rv.z, acc[u]); acc[u] = fmaf(w3_, rv.w, acc[u]);
      }
    }
#pragma unroll
    for (int u = 0; u < 32; ++u)
      gout[((size_t)b*N_ + n0 + pg*32 + u)*128 + o] = acc[u];
  }
}

// ---------- maxpool(g) + conv 128->128 relu + conv 128->1024 + global max ----------
__global__ __launch_bounds__(256) void k_hpool_max(const float* __restrict__ g,
    const int* __restrict__ idx,
    const float* __restrict__ g2a, const float* __restrict__ g2ab,
    const float* __restrict__ g2b, const float* __restrict__ g2bb,
    unsigned int* __restrict__ glob){
  __shared__ __align__(16) float m[32][128];
  __shared__ __align__(16) float t[32][128];
  int b = blockIdx.y; int n0 = blockIdx.x*32; int tid = threadIdx.x;
  { int p = tid/8, cg = tid%8; int n = n0+p;
    const int* ip = idx + ((size_t)b*N_+n)*16;
    float mm[16];
#pragma unroll
    for (int u = 0; u < 16; ++u) mm[u] = -1e30f;
    for (int k = 0; k < 16; ++k){
      int nb = ip[k];
      const float4* src = (const float4*)(g + ((size_t)b*N_+nb)*128 + cg*16);
#pragma unroll
      for (int u = 0; u < 4; ++u){
        float4 v = src[u];
        mm[4*u  ] = fmaxf(mm[4*u  ], v.x); mm[4*u+1] = fmaxf(mm[4*u+1], v.y);
        mm[4*u+2] = fmaxf(mm[4*u+2], v.z); mm[4*u+3] = fmaxf(mm[4*u+3], v.w);
      }
    }
#pragma unroll
    for (int u = 0; u < 16; ++u) m[p][cg*16+u] = mm[u];
  }
  __syncthreads();
  { int o = tid%128, pg = tid/128;
    float acc[16];
#pragma unroll
    for (int u = 0; u < 16; ++u) acc[u] = g2ab[o];
    const float4* wrow = (const float4*)(g2a + (size_t)o*128);
    for (int c4 = 0; c4 < 32; ++c4){
      float4 wv = wrow[c4];
#pragma unroll
      for (int u = 0; u < 16; ++u){
        float4 mv = *(const float4*)&m[pg*16+u][c4*4];
        acc[u] = fmaf(wv.x,mv.x,acc[u]); acc[u] = fmaf(wv.y,mv.y,acc[u]);
        acc[u] = fmaf(wv.z,mv.z,acc[u]); acc[u] = fmaf(wv.w,mv.w,acc[u]);
      }
    }
#pragma unroll
    for (int u = 0; u < 16; ++u) t[pg*16+u][o] = fmaxf(acc[u], 0.f);
  }
  __syncthreads();
  for (int oc = 0; oc < 4; ++oc){
    int o = oc*256 + tid;
    const float4* wrow = (const float4*)(g2b + (size_t)o*128);
    float acc[32];
#pragma unroll
    for (int u = 0; u < 32; ++u) acc[u] = 0.f;
    for (int c4 = 0; c4 < 32; ++c4){
      float4 wv = wrow[c4];
#pragma unroll
      for (int u = 0; u < 32; ++u){
        float4 tv = *(const float4*)&t[u][c4*4];
        acc[u] = fmaf(wv.x,tv.x,acc[u]); acc[u] = fmaf(wv.y,tv.y,acc[u]);
        acc[u] = fmaf(wv.z,tv.z,acc[u]); acc[u] = fmaf(wv.w,tv.w,acc[u]);
      }
    }
    float bias = g2bb[o];
    float mx = -1e30f;
#pragma unroll
    for (int u = 0; u < 32; ++u) mx = fmaxf(mx, acc[u] + bias);
    atomicMax(&glob[b*1024 + o], fmap(mx));
  }
}

// ---------- code MLP + decoder base precompute ----------
__global__ __launch_bounds__(512) void k_code(const unsigned int* __restrict__ glob,
    const float* __restrict__ m1, const float* __restrict__ m1b,
    const float* __restrict__ m2, const float* __restrict__ m2b,
    const float* __restrict__ f1a, const float* __restrict__ f1ab,
    const float* __restrict__ f2a, const float* __restrict__ f2ab,
    float* __restrict__ base1, float* __restrict__ base2){
  __shared__ __align__(16) float gl_s[1024];
  __shared__ __align__(16) float hid_s[512];
  __shared__ __align__(16) float code_s[512];
  int b = blockIdx.x; int tid = threadIdx.x;
  for (int i = tid; i < 1024; i += 512) gl_s[i] = funmap(glob[b*1024+i]);
  __syncthreads();
  { float acc = m1b[tid];
    const float4* wr = (const float4*)(m1 + (size_t)tid*1024);
    for (int c4 = 0; c4 < 256; ++c4){ float4 wv = wr[c4]; float4 gv = *(const float4*)&gl_s[c4*4];
      acc = fmaf(wv.x,gv.x,acc); acc = fmaf(wv.y,gv.y,acc);
      acc = fmaf(wv.z,gv.z,acc); acc = fmaf(wv.w,gv.w,acc); }
    hid_s[tid] = fmaxf(acc, 0.f);
  }
  __syncthreads();
  { float acc = m2b[tid];
    const float4* wr = (const float4*)(m2 + (size_t)tid*512);
    for (int c4 = 0; c4 < 128; ++c4){ float4 wv = wr[c4]; float4 hv = *(const float4*)&hid_s[c4*4];
      acc = fmaf(wv.x,hv.x,acc); acc = fmaf(wv.y,hv.y,acc);
      acc = fmaf(wv.z,hv.z,acc); acc = fmaf(wv.w,hv.w,acc); }
    code_s[tid] = acc;
  }
  __syncthreads();
  { float acc = f1ab[tid];
    const float* wr = f1a + (size_t)tid*514;
    for (int c = 0; c < 512; ++c) acc = fmaf(wr[c], code_s[c], acc);
    base1[b*512 + tid] = acc;
  }
  { float acc = f2ab[tid];
    const float* wr = f2a + (size_t)tid*515;
    for (int c = 0; c < 512; ++c) acc = fmaf(wr[c], code_s[c], acc);
    base2[b*512 + tid] = acc;
  }
}

// ---------- folding decoder ----------
template<int NIN>
__global__ __launch_bounds__(256) void k_fold(const float* __restrict__ base,
    const float* __restrict__ fa,
    const float* __restrict__ fb, const float* __restrict__ fbb,
    const float* __restrict__ fc, const float* __restrict__ fcb,
    const float* __restrict__ pin, float* __restrict__ pout){
  __shared__ __align__(16) float y1[32][512];
  __shared__ __align__(16) float y2[32][516];
  __shared__ float pcoord[32][NIN];
  int b = blockIdx.y; int m0 = blockIdx.x*32; int tid = threadIdx.x;
  if (tid < 32*NIN){
    int p = tid / NIN, c = tid % NIN;
    int mm = min(m0 + p, M_-1);
    float v;
    if (NIN == 2){
      const float step = 0.6f/44.f;
      int ii = (c == 0) ? (mm/GRID_) : (mm%GRID_);
      v = -0.3f + step*ii;
    } else {
      v = pin[((size_t)b*M_ + mm)*3 + c];
    }
    pcoord[p][c] = v;
  }
  __syncthreads();
  const int stride_a = 512 + NIN;
  for (int rep = 0; rep < 2; ++rep){
    int o = rep*256 + tid;
    float av[NIN];
#pragma unroll
    for (int c = 0; c < NIN; ++c) av[c] = fa[(size_t)o*stride_a + 512 + c];
    float bv = base[b*512 + o];
    for (int p = 0; p < 32; ++p){
      float acc = bv;
#pragma unroll
      for (int c = 0; c < NIN; ++c) acc = fmaf(av[c], pcoord[p][c], acc);
      y1[p][o] = fmaxf(acc, 0.f);
    }
  }
  __syncthreads();
  for (int rep = 0; rep < 2; ++rep){
    int o2 = rep*256 + tid;
    const float* wr = fb + (size_t)o2*512;
    float acc[32];
#pragma unroll
    for (int u = 0; u < 32; ++u) acc[u] = 0.f;
    for (int c4 = 0; c4 < 128; ++c4){
      float4 wv = *(const float4*)&wr[c4*4];
#pragma unroll
      for (int u = 0; u < 32; ++u){
        float4 yv = *(const float4*)&y1[u][c4*4];
        acc[u] = fmaf(wv.x,yv.x,acc[u]); acc[u] = fmaf(wv.y,yv.y,acc[u]);
        acc[u] = fmaf(wv.z,yv.z,acc[u]); acc[u] = fmaf(wv.w,yv.w,acc[u]);
      }
    }
    float bias = fbb[o2];
#pragma unroll
    for (int u = 0; u < 32; ++u) y2[u][o2] = fmaxf(acc[u] + bias, 0.f);
  }
  __syncthreads();
  if (tid < 96){
    int p = tid / 3, c = tid % 3;
    const float* wr = fc + (size_t)c*512;
    float acc = fcb[c];
    for (int o4 = 0; o4 < 128; ++o4){
      float4 wv = *(const float4*)&wr[o4*4];
      float4 yv = *(const float4*)&y2[p][o4*4];
      acc = fmaf(wv.x,yv.x,acc); acc = fmaf(wv.y,yv.y,acc);
      acc = fmaf(wv.z,yv.z,acc); acc = fmaf(wv.w,yv.w,acc);
    }
    int mm = m0 + p;
    if (mm < M_) pout[((size_t)b*M_ + mm)*3 + c] = acc;
  }
}

// ---------- launcher ----------
extern "C" void kernel_launch(void* const* d_in, const int* in_sizes, int n_in,
                              void* d_out, int out_size, void* d_ws, size_t ws_size,
                              hipStream_t stream){
  const float* pts  = (const float*)d_in[0];
  const float* w1   = (const float*)d_in[1];  const float* b1   = (const float*)d_in[2];
  const float* w2   = (const float*)d_in[3];  const float* b2   = (const float*)d_in[4];
  const float* w3   = (const float*)d_in[5];  const float* b3   = (const float*)d_in[6];
  const float* g1a  = (const float*)d_in[7];  const float* g1ab = (const float*)d_in[8];
  const float* g1b  = (const float*)d_in[9];  const float* g1bb = (const float*)d_in[10];
  const float* g2a  = (const float*)d_in[11]; const float* g2ab = (const float*)d_in[12];
  const float* g2b  = (const float*)d_in[13]; const float* g2bb = (const float*)d_in[14];
  const float* m1   = (const float*)d_in[15]; const float* m1b  = (const float*)d_in[16];
  const float* m2   = (const float*)d_in[17]; const float* m2b  = (const float*)d_in[18];
  const float* f1a  = (const float*)d_in[19]; const float* f1ab = (const float*)d_in[20];
  const float* f1b  = (const float*)d_in[21]; const float* f1bb = (const float*)d_in[22];
  const float* f1c  = (const float*)d_in[23]; const float* f1cb = (const float*)d_in[24];
  const float* f2a  = (const float*)d_in[25]; const float* f2ab = (const float*)d_in[26];
  const float* f2b  = (const float*)d_in[27]; const float* f2bb = (const float*)d_in[28];
  const float* f2c  = (const float*)d_in[29]; const float* f2cb = (const float*)d_in[30];
  float* out = (float*)d_out;

  char* w = (char*)d_ws;
  auto alloc = [&](size_t bytes){ char* p = w; w += (bytes + 255) & ~(size_t)255; return p; };
  unsigned long long* nn64 = (unsigned long long*)alloc((size_t)B_*N_*8);
  float* x    = (float*)alloc((size_t)B_*N_*64*4);
  float* g    = (float*)alloc((size_t)B_*N_*128*4);
  unsigned short* T64  = (unsigned short*)alloc((size_t)B_*4*4*N_*16);   //  8MB
  unsigned short* T128 = (unsigned short*)alloc((size_t)B_*8*4*N_*16);   // 16MB
  float* ccf  = (float*)alloc((size_t)B_*N_*4);
  int*   idx  = (int*)alloc((size_t)B_*N_*16*4);
  ull*   qkeys = (ull*)alloc((size_t)B_*N_*4*2*16*8);                    // 32MB
  unsigned int* glob = (unsigned int*)alloc((size_t)B_*1024*4);
  float* base1 = (float*)alloc((size_t)B_*512*4);
  float* base2 = (float*)alloc((size_t)B_*512*4);
  float* mid   = (float*)alloc((size_t)B_*M_*3*4);
  (void)ws_size; (void)in_sizes; (void)n_in; (void)out_size;

  const int QB = 2*8*256*4;                 // 16 KB queue planes
  const int SMEM4 = 4*4096 + 256 + QB;      // 33,024 B -> 4 blocks/CU
  const int SMEM8 = 8*4096 + 256 + QB;      // 49,408 B -> 3 blocks/CU
  hipFuncSetAttribute((const void*)k_knnF<4,4,4>, hipFuncAttributeMaxDynamicSharedMemorySize, SMEM4);
  hipFuncSetAttribute((const void*)k_knnF<8,3,4>, hipFuncAttributeMaxDynamicSharedMemorySize, SMEM8);

  hipMemsetAsync(nn64, 0xFF, (size_t)B_*N_*8, stream);
  k_init<<<dim3((B_*1024+255)/256), 256, 0, stream>>>(glob);
  k_nn1<<<dim3(N_/256, 4, B_), 256, 0, stream>>>(pts, nn64);
  k_cov_mlp<<<dim3(N_/64, B_), 256, 0, stream>>>(pts, nn64, w1,b1,w2,b2,w3,b3, x);

  k_prep4<4><<<dim3(N_/256, B_), 256, 0, stream>>>(x, T64, ccf);
  k_knnF<4,4,4><<<dim3(N_/128, 4, B_), 256, SMEM4, stream>>>(T64, ccf, qkeys);
  k_sel<4><<<dim3(B_*N_/256), 256, 0, stream>>>(qkeys, idx);

  k_gpool_mlp<<<dim3(N_/64, B_), 256, 0, stream>>>(x, idx, g1a,g1ab,g1b,g1bb, g);

  k_prep4<8><<<dim3(N_/256, B_), 256, 0, stream>>>(g, T128, ccf);
  k_knnF<8,3,4><<<dim3(N_/128, 4, B_), 256, SMEM8, stream>>>(T128, ccf, qkeys);
  k_sel<4><<<dim3(B_*N_/256), 256, 0, stream>>>(qkeys, idx);

  k_hpool_max<<<dim3(N_/32, B_), 256, 0, stream>>>(g, idx, g2a,g2ab,g2b,g2bb, glob);
  k_code<<<dim3(B_), 512, 0, stream>>>(glob, m1,m1b,m2,m2b, f1a,f1ab, f2a,f2ab, base1, base2);
  k_fold<2><<<dim3((M_+31)/32, B_), 256, 0, stream>>>(base1, f1a, f1b, f1bb, f1c, f1cb, nullptr, mid);
  k_fold<3><<<dim3((M_+31)/32, B_), 256, 0, stream>>>(base2, f2a, f2b, f2bb, f2c, f2cb, mid, out);
}

// Round 13
// 1781.145 us; speedup vs baseline: 1.0509x; 1.0509x over previous
//
#include <hip/hip_runtime.h>
#include <stdint.h>

#define B_ 4
#define N_ 8192
#define K_ 16
#define FEAT_ 512
#define GRID_ 45
#define M_ (GRID_*GRID_)

typedef unsigned long long ull;
typedef __bf16 bf16x8 __attribute__((ext_vector_type(8)));
typedef float f32x16 __attribute__((ext_vector_type(16)));

// ---------- helpers ----------

__device__ __forceinline__ unsigned int fmap(float f){
  unsigned int u = __float_as_uint(f);
  return (u & 0x80000000u) ? ~u : (u | 0x80000000u);
}
__device__ __forceinline__ float funmap(unsigned int u){
  return (u & 0x80000000u) ? __uint_as_float(u ^ 0x80000000u) : __uint_as_float(~u);
}

// sorted top-16 insert on packed (fmap(dist)<<32 | idx) keys: lex order ==
// jax.lax.top_k tie-break (lower index first). Order-independent.
__device__ __forceinline__ void ins16(ull (&d)[16], ull k){
  if (k < d[15]){
    bool c[16];
#pragma unroll
    for (int s = 0; s < 16; ++s) c[s] = k < d[s];
#pragma unroll
    for (int s = 15; s >= 1; --s) d[s] = c[s-1] ? d[s-1] : (c[s] ? k : d[s]);
    if (c[0]) d[0] = k;
  }
}

// stable u32-key/u32-idx sorted insert, strict < : with ascending-idx scan
// order this reproduces (dist, idx) lex semantics exactly at ~70% the cost.
__device__ __forceinline__ void ins16b(unsigned (&dk)[16], unsigned (&di)[16],
                                       unsigned k, unsigned id){
  if (k < dk[15]){
    bool c[16];
#pragma unroll
    for (int s = 0; s < 16; ++s) c[s] = k < dk[s];
#pragma unroll
    for (int s = 15; s >= 1; --s){
      dk[s] = c[s-1] ? dk[s-1] : (c[s] ? k  : dk[s]);
      di[s] = c[s-1] ? di[s-1] : (c[s] ? id : di[s]);
    }
    if (c[0]){ dk[0] = k; di[0] = id; }
  }
}

#define GLDS16(l, g) __builtin_amdgcn_global_load_lds((const __attribute__((address_space(1))) void*)(g), (__attribute__((address_space(3))) void*)(l), 16, 0, 0)
#define GLDS4(l, g)  __builtin_amdgcn_global_load_lds((const __attribute__((address_space(1))) void*)(g), (__attribute__((address_space(3))) void*)(l), 4, 0, 0)

#define KEY_INF 0xFF800000FFFFFFFFull

// ---------- init ----------
__global__ void k_init(unsigned int* glob){
  int i = blockIdx.x*256 + threadIdx.x;
  if (i < B_*1024) glob[i] = 0x007FFFFFu;   // fmap(-inf)
}

// ---------- KNN #1: nearest other point (exact fp32, float4 LDS) ----------
__global__ __launch_bounds__(256) void k_nn1(const float* __restrict__ pts,
                                             unsigned long long* __restrict__ nn64){
  __shared__ __align__(16) float sp4[2048][4];
  int b = blockIdx.z, s = blockIdx.y;
  int c0 = s*2048;
  const float* P = pts + (size_t)b*N_*3;
  for (int p = threadIdx.x; p < 2048; p += 256){
    const float* src = P + (size_t)(c0 + p)*3;
    sp4[p][0] = src[0]; sp4[p][1] = src[1]; sp4[p][2] = src[2]; sp4[p][3] = 0.f;
  }
  __syncthreads();
  int n = blockIdx.x*256 + threadIdx.x;
  float qx = P[n*3], qy = P[n*3+1], qz = P[n*3+2];
  float best = 1e30f; int bi = 0;
  for (int j = 0; j < 2048; ++j){
    float4 sv = *(const float4*)sp4[j];
    float dx = qx - sv.x, dy = qy - sv.y, dz = qz - sv.z;
    float d2 = fmaf(dx,dx, fmaf(dy,dy, dz*dz));
    int cj = c0 + j;
    if (d2 < best && cj != n){ best = d2; bi = cj; }
  }
  unsigned long long key = ((unsigned long long)__float_as_uint(best) << 32) | (unsigned int)bi;
  atomicMin(&nn64[(size_t)b*N_ + n], key);
}

// ---------- local_cov + 3 convs (12->64->64->64, relu each) ----------
__global__ __launch_bounds__(256) void k_cov_mlp(const float* __restrict__ pts,
    const unsigned long long* __restrict__ nn64,
    const float* __restrict__ w1, const float* __restrict__ b1,
    const float* __restrict__ w2, const float* __restrict__ b2,
    const float* __restrict__ w3, const float* __restrict__ b3,
    float* __restrict__ xout){
  __shared__ __align__(16) float W1t[12*64];
  __shared__ __align__(16) float W2t[64*64];
  __shared__ __align__(16) float W3t[64*64];
  __shared__ float B1[64], B2[64], B3[64];
  __shared__ __align__(16) float x0[64][12];
  __shared__ __align__(16) float h1[64][64];
  __shared__ __align__(16) float h2[64][64];
  int b = blockIdx.y; int n0 = blockIdx.x*64; int tid = threadIdx.x;
  for (int i = tid; i < 12*64; i += 256){ int o = i % 64, ci = i / 64; W1t[i] = w1[o*12 + ci]; }
  for (int i = tid; i < 64*64; i += 256){ int o = i % 64, ci = i / 64; W2t[i] = w2[o*64 + ci]; W3t[i] = w3[o*64 + ci]; }
  if (tid < 64){ B1[tid]=b1[tid]; B2[tid]=b2[tid]; B3[tid]=b3[tid]; }
  {
    int p = tid % 64, cg = tid / 64;
    int n = n0 + p;
    const float* P = pts + ((size_t)b*N_ + n)*3;
    int nb = (int)(nn64[(size_t)b*N_ + n] & 0xFFFFFFFFull);
    const float* Q = pts + ((size_t)b*N_ + nb)*3;
    if (cg == 0){ x0[p][0]=P[0]; x0[p][1]=P[1]; x0[p][2]=P[2]; }
    else { int i = cg-1; float pi = P[i];
      x0[p][3+i*3+0]=pi*Q[0]; x0[p][3+i*3+1]=pi*Q[1]; x0[p][3+i*3+2]=pi*Q[2]; }
  }
  __syncthreads();
  { int o = tid % 64, pg = tid / 64;
    for (int p = pg; p < 64; p += 4){
      float acc = B1[o];
#pragma unroll
      for (int ci = 0; ci < 12; ++ci) acc = fmaf(W1t[ci*64+o], x0[p][ci], acc);
      h1[p][o] = fmaxf(acc, 0.f);
    } }
  __syncthreads();
  { int o = tid % 64, pg = tid / 64;
    for (int p = pg; p < 64; p += 4){
      float acc = B2[o];
#pragma unroll
      for (int ci = 0; ci < 64; ++ci) acc = fmaf(W2t[ci*64+o], h1[p][ci], acc);
      h2[p][o] = fmaxf(acc, 0.f);
    } }
  __syncthreads();
  { int o = tid % 64, pg = tid / 64;
    for (int p = pg; p < 64; p += 4){
      float acc = B3[o];
#pragma unroll
      for (int ci = 0; ci < 64; ++ci) acc = fmaf(W3t[ci*64+o], h2[p][ci], acc);
      xout[((size_t)b*N_ + n0 + p)*64 + o] = fmaxf(acc, 0.f);
    } }
}

// ---------- prep: bf16 hi/lo split into K-major granule layout + norms ----------
// T layout: [b][kf][pl 2][hi8 2][n 8192][16B granule]; granule = 8 bf16 ch.
template<int KF>
__global__ __launch_bounds__(256) void k_prep4(const float* __restrict__ f,
    unsigned short* __restrict__ T, float* __restrict__ cc){
  int b = blockIdx.y; int n = blockIdx.x*256 + threadIdx.x;
  const float* src = f + ((size_t)b*N_ + n)*(KF*16);
  char* Tb = (char*)T;
  float ss = 0.f;
#pragma unroll
  for (int kf = 0; kf < KF; ++kf){
    float v[16];
#pragma unroll
    for (int c4 = 0; c4 < 4; ++c4){
      float4 t4 = *(const float4*)&src[kf*16 + c4*4];
      v[c4*4]=t4.x; v[c4*4+1]=t4.y; v[c4*4+2]=t4.z; v[c4*4+3]=t4.w;
    }
    unsigned short hs[16], ls[16];
#pragma unroll
    for (int c = 0; c < 16; ++c){
      float x = v[c];
      ss = fmaf(x, x, ss);
      __bf16 h = (__bf16)x;
      __bf16 l = (__bf16)(x - (float)h);
      hs[c] = __builtin_bit_cast(unsigned short, h);
      ls[c] = __builtin_bit_cast(unsigned short, l);
    }
    size_t base = ((((size_t)b*KF + kf)*2)*2)*(size_t)(N_*16) + (size_t)n*16;
    const size_t HS = (size_t)N_*16;           // hi8 stride
    const size_t PS = 2*HS;                    // plane stride
    *(uint4*)(Tb + base)            = *(uint4*)&hs[0];
    *(uint4*)(Tb + base + HS)       = *(uint4*)&hs[8];
    *(uint4*)(Tb + base + PS)       = *(uint4*)&ls[0];
    *(uint4*)(Tb + base + PS + HS)  = *(uint4*)&ls[8];
  }
  cc[(size_t)b*N_ + n] = ss;
}

// ---------- fused single-pass KNN: MFMA + gated stable u32 top-16 ----------
// Single LDS buffer; S-way candidate split; lane owns region (q, sp, hi);
// in-region scan is ascending-idx so stable strict-< insert == lex top-k.
template<int KF, int MW, int S>
__global__ __launch_bounds__(256, MW) void k_knnF(const unsigned short* __restrict__ T,
    const float* __restrict__ ccg, ull* __restrict__ qkeys){
  extern __shared__ char smem[];
  constexpr int NT = (N_/S)/64;
  char* As = smem;                    // KF*4096
  char* Cs = smem + KF*4096;          // 256

  const int tid = threadIdx.x, lane = tid & 63, wid = tid >> 6;
  const int hi = lane >> 5, l31 = lane & 31;
  const int b = blockIdx.z, sp = blockIdx.y, q0 = blockIdx.x*128;
  const int c0 = sp*(N_/S);
  const char* Tb = (const char*)T;
  const size_t HS = (size_t)N_*16, PS = 2*HS, KS = 4*HS;
  const size_t Bb = (size_t)b*KF*KS;
  const float* ccb = ccg + (size_t)b*N_;

  const int q = q0 + wid*32 + l31;
  bf16x8 qh[KF], ql[KF];
#pragma unroll
  for (int kf = 0; kf < KF; ++kf){
    size_t o = Bb + kf*KS + hi*HS + (size_t)q*16;
    qh[kf] = *(const bf16x8*)(Tb + o);
    ql[kf] = *(const bf16x8*)(Tb + o + PS);
  }

  unsigned dk[16], di[16];
#pragma unroll
  for (int t = 0; t < 16; ++t){ dk[t] = 0xFFFFFFFFu; di[t] = 0xFFFFFFFFu; }
  float kapf = __builtin_inff();

  auto stage = [&](int t0){
#pragma unroll
    for (int si = 0; si < KF; ++si){
      int s = wid + 4*si;
      int kf = s >> 2, pl = (s >> 1) & 1, h = s & 1;
      GLDS16(As + s*1024,
             Tb + Bb + kf*KS + pl*PS + h*HS + (size_t)(c0 + t0)*16);
    }
    if (wid == 0) GLDS4(Cs, (const char*)(ccb + c0 + t0));
  };

  for (int t = 0; t < NT; ++t){
    const int t0 = t*64;
    __syncthreads();                   // all waves done reading previous tile
    stage(t0);
    asm volatile("s_waitcnt vmcnt(0)" ::: "memory");
    __syncthreads();                   // tile visible to all waves

    const char* Ab = As + hi*1024 + l31*16;
    const float* cct = (const float*)Cs;
#pragma unroll
    for (int i = 0; i < 2; ++i){
      f32x16 acc = (f32x16)(0.f);
#pragma unroll
      for (int kf = 0; kf < KF; ++kf){
        bf16x8 ah = *(const bf16x8*)(Ab + kf*4096 + i*512);
        bf16x8 al = *(const bf16x8*)(Ab + kf*4096 + 2048 + i*512);
        acc = __builtin_amdgcn_mfma_f32_32x32x16_bf16(ah, qh[kf], acc, 0, 0, 0);
        acc = __builtin_amdgcn_mfma_f32_32x32x16_bf16(ah, ql[kf], acc, 0, 0, 0);
        acc = __builtin_amdgcn_mfma_f32_32x32x16_bf16(al, qh[kf], acc, 0, 0, 0);
      }
      // v = cc - 2<q,c> (qq dropped: constant per-query shift, order-preserving)
#pragma unroll
      for (int rq = 0; rq < 4; ++rq){
        float4 c4 = *(const float4*)(cct + i*32 + 4*hi + 8*rq);
        int rowb = c0 + t0 + i*32 + 4*hi + 8*rq;
        float v0 = fmaf(-2.f, acc[rq*4+0], c4.x);
        float v1 = fmaf(-2.f, acc[rq*4+1], c4.y);
        float v2 = fmaf(-2.f, acc[rq*4+2], c4.z);
        float v3 = fmaf(-2.f, acc[rq*4+3], c4.w);
        if (fminf(fminf(v0, v1), fminf(v2, v3)) < kapf){
          if (v0 < kapf) ins16b(dk, di, fmap(v0), (unsigned)(rowb+0));
          if (v1 < kapf) ins16b(dk, di, fmap(v1), (unsigned)(rowb+1));
          if (v2 < kapf) ins16b(dk, di, fmap(v2), (unsigned)(rowb+2));
          if (v3 < kapf) ins16b(dk, di, fmap(v3), (unsigned)(rowb+3));
          unsigned kk = dk[15];
          kapf = (kk >= 0xFF800000u) ? __builtin_inff() : funmap(kk);
        }
      }
    }
  }
  // write region (q, sp, hi): 16 packed keys, sentinel-padded
  ull* op = qkeys + (((size_t)((size_t)b*N_ + q)*S + sp)*2 + hi)*16;
#pragma unroll
  for (int t = 0; t < 16; ++t) op[t] = ((ull)dk[t] << 32) | di[t];
}

// ---------- final exact top-16 over S*2 regions x 16 keys ----------
template<int S>
__global__ void k_sel(const ull* __restrict__ qkeys, int* __restrict__ idxout){
  int i = blockIdx.x*256 + threadIdx.x;
  if (i >= B_*N_) return;
  ull best[16];
#pragma unroll
  for (int t = 0; t < 16; ++t) best[t] = KEY_INF;
  const ull* kp = qkeys + (size_t)i*(S*32);
  for (int t = 0; t < S*32; ++t) ins16(best, kp[t]);
  int* op = idxout + (size_t)i*16;
#pragma unroll
  for (int t = 0; t < 16; ++t) op[t] = (int)(best[t] & 0xffffffffu);
}

// ---------- maxpool(x) + conv 64->64 relu + conv 64->128 ----------
__global__ __launch_bounds__(256) void k_gpool_mlp(const float* __restrict__ x,
    const int* __restrict__ idx,
    const float* __restrict__ g1a, const float* __restrict__ g1ab,
    const float* __restrict__ g1b, const float* __restrict__ g1bb,
    float* __restrict__ gout){
  __shared__ __align__(16) float Wt1[64*64];
  __shared__ __align__(16) float Wt2[64*128];
  __shared__ float Ba[64], Bb[128];
  __shared__ __align__(16) float m[64][64];
  __shared__ __align__(16) float r[64][64];
  int b = blockIdx.y; int n0 = blockIdx.x*64; int tid = threadIdx.x;
  for (int i = tid; i < 64*64; i += 256){ int o = i%64, ci = i/64; Wt1[i] = g1a[o*64+ci]; }
  for (int i = tid; i < 64*128; i += 256){ int o = i%128, ci = i/128; Wt2[i] = g1b[o*64+ci]; }
  if (tid < 64) Ba[tid] = g1ab[tid];
  if (tid < 128) Bb[tid] = g1bb[tid];
  { int p = tid/4, cg = tid%4; int n = n0 + p;
    const int* ip = idx + ((size_t)b*N_ + n)*16;
    float mm[16];
#pragma unroll
    for (int u = 0; u < 16; ++u) mm[u] = -1e30f;
    for (int k = 0; k < 16; ++k){
      int nb = ip[k];
      const float4* src = (const float4*)(x + ((size_t)b*N_ + nb)*64 + cg*16);
#pragma unroll
      for (int u = 0; u < 4; ++u){
        float4 v = src[u];
        mm[4*u  ] = fmaxf(mm[4*u  ], v.x); mm[4*u+1] = fmaxf(mm[4*u+1], v.y);
        mm[4*u+2] = fmaxf(mm[4*u+2], v.z); mm[4*u+3] = fmaxf(mm[4*u+3], v.w);
      }
    }
#pragma unroll
    for (int u = 0; u < 16; ++u) m[p][cg*16+u] = mm[u];
  }
  __syncthreads();
  { int o = tid%64, pg = tid/64;
    float acc[16];
#pragma unroll
    for (int u = 0; u < 16; ++u) acc[u] = Ba[o];
    for (int ci = 0; ci < 64; ci += 4){
      float w0 = Wt1[ci*64+o], w1_ = Wt1[(ci+1)*64+o], w2_ = Wt1[(ci+2)*64+o], w3_ = Wt1[(ci+3)*64+o];
#pragma unroll
      for (int u = 0; u < 16; ++u){
        float4 mv = *(const float4*)&m[pg*16+u][ci];
        acc[u] = fmaf(w0, mv.x, acc[u]); acc[u] = fmaf(w1_, mv.y, acc[u]);
        acc[u] = fmaf(w2_, mv.z, acc[u]); acc[u] = fmaf(w3_, mv.w, acc[u]);
      }
    }
#pragma unroll
    for (int u = 0; u < 16; ++u) r[pg*16+u][o] = fmaxf(acc[u], 0.f);
  }
  __syncthreads();
  { int o = tid%128, pg = tid/128;   // no relu on this conv
    float acc[32];
#pragma unroll
    for (int u = 0; u < 32; ++u) acc[u] = Bb[o];
    for (int ci = 0; ci < 64; ci += 4){
      float w0 = Wt2[ci*128+o], w1_ = Wt2[(ci+1)*128+o], w2_ = Wt2[(ci+2)*128+o], w3_ = Wt2[(ci+3)*128+o];
#pragma unroll
      for (int u = 0; u < 32; ++u){
        float4 rv = *(const float4*)&r[pg*32+u][ci];
        acc[u] = fmaf(w0, rv.x, acc[u]); acc[u] = fmaf(w1_, rv.y, acc[u]);
        acc[u] = fmaf(w2_, rv.z, acc[u]); acc[u] = fmaf(w3_, rv.w, acc[u]);
      }
    }
#pragma unroll
    for (int u = 0; u < 32; ++u)
      gout[((size_t)b*N_ + n0 + pg*32 + u)*128 + o] = acc[u];
  }
}

// ---------- maxpool(g) + conv 128->128 relu + conv 128->1024 + global max ----------
__global__ __launch_bounds__(256) void k_hpool_max(const float* __restrict__ g,
    const int* __restrict__ idx,
    const float* __restrict__ g2a, const float* __restrict__ g2ab,
    const float* __restrict__ g2b, const float* __restrict__ g2bb,
    unsigned int* __restrict__ glob){
  __shared__ __align__(16) float m[32][128];
  __shared__ __align__(16) float t[32][128];
  int b = blockIdx.y; int n0 = blockIdx.x*32; int tid = threadIdx.x;
  { int p = tid/8, cg = tid%8; int n = n0+p;
    const int* ip = idx + ((size_t)b*N_+n)*16;
    float mm[16];
#pragma unroll
    for (int u = 0; u < 16; ++u) mm[u] = -1e30f;
    for (int k = 0; k < 16; ++k){
      int nb = ip[k];
      const float4* src = (const float4*)(g + ((size_t)b*N_+nb)*128 + cg*16);
#pragma unroll
      for (int u = 0; u < 4; ++u){
        float4 v = src[u];
        mm[4*u  ] = fmaxf(mm[4*u  ], v.x); mm[4*u+1] = fmaxf(mm[4*u+1], v.y);
        mm[4*u+2] = fmaxf(mm[4*u+2], v.z); mm[4*u+3] = fmaxf(mm[4*u+3], v.w);
      }
    }
#pragma unroll
    for (int u = 0; u < 16; ++u) m[p][cg*16+u] = mm[u];
  }
  __syncthreads();
  { int o = tid%128, pg = tid/128;
    float acc[16];
#pragma unroll
    for (int u = 0; u < 16; ++u) acc[u] = g2ab[o];
    const float4* wrow = (const float4*)(g2a + (size_t)o*128);
    for (int c4 = 0; c4 < 32; ++c4){
      float4 wv = wrow[c4];
#pragma unroll
      for (int u = 0; u < 16; ++u){
        float4 mv = *(const float4*)&m[pg*16+u][c4*4];
        acc[u] = fmaf(wv.x,mv.x,acc[u]); acc[u] = fmaf(wv.y,mv.y,acc[u]);
        acc[u] = fmaf(wv.z,mv.z,acc[u]); acc[u] = fmaf(wv.w,mv.w,acc[u]);
      }
    }
#pragma unroll
    for (int u = 0; u < 16; ++u) t[pg*16+u][o] = fmaxf(acc[u], 0.f);
  }
  __syncthreads();
  for (int oc = 0; oc < 4; ++oc){
    int o = oc*256 + tid;
    const float4* wrow = (const float4*)(g2b + (size_t)o*128);
    float acc[32];
#pragma unroll
    for (int u = 0; u < 32; ++u) acc[u] = 0.f;
    for (int c4 = 0; c4 < 32; ++c4){
      float4 wv = wrow[c4];
#pragma unroll
      for (int u = 0; u < 32; ++u){
        float4 tv = *(const float4*)&t[u][c4*4];
        acc[u] = fmaf(wv.x,tv.x,acc[u]); acc[u] = fmaf(wv.y,tv.y,acc[u]);
        acc[u] = fmaf(wv.z,tv.z,acc[u]); acc[u] = fmaf(wv.w,tv.w,acc[u]);
      }
    }
    float bias = g2bb[o];
    float mx = -1e30f;
#pragma unroll
    for (int u = 0; u < 32; ++u) mx = fmaxf(mx, acc[u] + bias);
    atomicMax(&glob[b*1024 + o], fmap(mx));
  }
}

// ---------- code MLP + decoder base precompute ----------
__global__ __launch_bounds__(512) void k_code(const unsigned int* __restrict__ glob,
    const float* __restrict__ m1, const float* __restrict__ m1b,
    const float* __restrict__ m2, const float* __restrict__ m2b,
    const float* __restrict__ f1a, const float* __restrict__ f1ab,
    const float* __restrict__ f2a, const float* __restrict__ f2ab,
    float* __restrict__ base1, float* __restrict__ base2){
  __shared__ __align__(16) float gl_s[1024];
  __shared__ __align__(16) float hid_s[512];
  __shared__ __align__(16) float code_s[512];
  int b = blockIdx.x; int tid = threadIdx.x;
  for (int i = tid; i < 1024; i += 512) gl_s[i] = funmap(glob[b*1024+i]);
  __syncthreads();
  { float acc = m1b[tid];
    const float4* wr = (const float4*)(m1 + (size_t)tid*1024);
    for (int c4 = 0; c4 < 256; ++c4){ float4 wv = wr[c4]; float4 gv = *(const float4*)&gl_s[c4*4];
      acc = fmaf(wv.x,gv.x,acc); acc = fmaf(wv.y,gv.y,acc);
      acc = fmaf(wv.z,gv.z,acc); acc = fmaf(wv.w,gv.w,acc); }
    hid_s[tid] = fmaxf(acc, 0.f);
  }
  __syncthreads();
  { float acc = m2b[tid];
    const float4* wr = (const float4*)(m2 + (size_t)tid*512);
    for (int c4 = 0; c4 < 128; ++c4){ float4 wv = wr[c4]; float4 hv = *(const float4*)&hid_s[c4*4];
      acc = fmaf(wv.x,hv.x,acc); acc = fmaf(wv.y,hv.y,acc);
      acc = fmaf(wv.z,hv.z,acc); acc = fmaf(wv.w,hv.w,acc); }
    code_s[tid] = acc;
  }
  __syncthreads();
  { float acc = f1ab[tid];
    const float* wr = f1a + (size_t)tid*514;
    for (int c = 0; c < 512; ++c) acc = fmaf(wr[c], code_s[c], acc);
    base1[b*512 + tid] = acc;
  }
  { float acc = f2ab[tid];
    const float* wr = f2a + (size_t)tid*515;
    for (int c = 0; c < 512; ++c) acc = fmaf(wr[c], code_s[c], acc);
    base2[b*512 + tid] = acc;
  }
}

// ---------- folding decoder ----------
template<int NIN>
__global__ __launch_bounds__(256) void k_fold(const float* __restrict__ base,
    const float* __restrict__ fa,
    const float* __restrict__ fb, const float* __restrict__ fbb,
    const float* __restrict__ fc, const float* __restrict__ fcb,
    const float* __restrict__ pin, float* __restrict__ pout){
  __shared__ __align__(16) float y1[32][512];
  __shared__ __align__(16) float y2[32][516];
  __shared__ float pcoord[32][NIN];
  int b = blockIdx.y; int m0 = blockIdx.x*32; int tid = threadIdx.x;
  if (tid < 32*NIN){
    int p = tid / NIN, c = tid % NIN;
    int mm = min(m0 + p, M_-1);
    float v;
    if (NIN == 2){
      const float step = 0.6f/44.f;
      int ii = (c == 0) ? (mm/GRID_) : (mm%GRID_);
      v = -0.3f + step*ii;
    } else {
      v = pin[((size_t)b*M_ + mm)*3 + c];
    }
    pcoord[p][c] = v;
  }
  __syncthreads();
  const int stride_a = 512 + NIN;
  for (int rep = 0; rep < 2; ++rep){
    int o = rep*256 + tid;
    float av[NIN];
#pragma unroll
    for (int c = 0; c < NIN; ++c) av[c] = fa[(size_t)o*stride_a + 512 + c];
    float bv = base[b*512 + o];
    for (int p = 0; p < 32; ++p){
      float acc = bv;
#pragma unroll
      for (int c = 0; c < NIN; ++c) acc = fmaf(av[c], pcoord[p][c], acc);
      y1[p][o] = fmaxf(acc, 0.f);
    }
  }
  __syncthreads();
  for (int rep = 0; rep < 2; ++rep){
    int o2 = rep*256 + tid;
    const float* wr = fb + (size_t)o2*512;
    float acc[32];
#pragma unroll
    for (int u = 0; u < 32; ++u) acc[u] = 0.f;
    for (int c4 = 0; c4 < 128; ++c4){
      float4 wv = *(const float4*)&wr[c4*4];
#pragma unroll
      for (int u = 0; u < 32; ++u){
        float4 yv = *(const float4*)&y1[u][c4*4];
        acc[u] = fmaf(wv.x,yv.x,acc[u]); acc[u] = fmaf(wv.y,yv.y,acc[u]);
        acc[u] = fmaf(wv.z,yv.z,acc[u]); acc[u] = fmaf(wv.w,yv.w,acc[u]);
      }
    }
    float bias = fbb[o2];
#pragma unroll
    for (int u = 0; u < 32; ++u) y2[u][o2] = fmaxf(acc[u] + bias, 0.f);
  }
  __syncthreads();
  if (tid < 96){
    int p = tid / 3, c = tid % 3;
    const float* wr = fc + (size_t)c*512;
    float acc = fcb[c];
    for (int o4 = 0; o4 < 128; ++o4){
      float4 wv = *(const float4*)&wr[o4*4];
      float4 yv = *(const float4*)&y2[p][o4*4];
      acc = fmaf(wv.x,yv.x,acc); acc = fmaf(wv.y,yv.y,acc);
      acc = fmaf(wv.z,yv.z,acc); acc = fmaf(wv.w,yv.w,acc);
    }
    int mm = m0 + p;
    if (mm < M_) pout[((size_t)b*M_ + mm)*3 + c] = acc;
  }
}

// ---------- launcher ----------
extern "C" void kernel_launch(void* const* d_in, const int* in_sizes, int n_in,
                              void* d_out, int out_size, void* d_ws, size_t ws_size,
                              hipStream_t stream){
  const float* pts  = (const float*)d_in[0];
  const float* w1   = (const float*)d_in[1];  const float* b1   = (const float*)d_in[2];
  const float* w2   = (const float*)d_in[3];  const float* b2   = (const float*)d_in[4];
  const float* w3   = (const float*)d_in[5];  const float* b3   = (const float*)d_in[6];
  const float* g1a  = (const float*)d_in[7];  const float* g1ab = (const float*)d_in[8];
  const float* g1b  = (const float*)d_in[9];  const float* g1bb = (const float*)d_in[10];
  const float* g2a  = (const float*)d_in[11]; const float* g2ab = (const float*)d_in[12];
  const float* g2b  = (const float*)d_in[13]; const float* g2bb = (const float*)d_in[14];
  const float* m1   = (const float*)d_in[15]; const float* m1b  = (const float*)d_in[16];
  const float* m2   = (const float*)d_in[17]; const float* m2b  = (const float*)d_in[18];
  const float* f1a  = (const float*)d_in[19]; const float* f1ab = (const float*)d_in[20];
  const float* f1b  = (const float*)d_in[21]; const float* f1bb = (const float*)d_in[22];
  const float* f1c  = (const float*)d_in[23]; const float* f1cb = (const float*)d_in[24];
  const float* f2a  = (const float*)d_in[25]; const float* f2ab = (const float*)d_in[26];
  const float* f2b  = (const float*)d_in[27]; const float* f2bb = (const float*)d_in[28];
  const float* f2c  = (const float*)d_in[29]; const float* f2cb = (const float*)d_in[30];
  float* out = (float*)d_out;

  char* w = (char*)d_ws;
  auto alloc = [&](size_t bytes){ char* p = w; w += (bytes + 255) & ~(size_t)255; return p; };
  unsigned long long* nn64 = (unsigned long long*)alloc((size_t)B_*N_*8);
  float* x    = (float*)alloc((size_t)B_*N_*64*4);
  float* g    = (float*)alloc((size_t)B_*N_*128*4);
  unsigned short* T64  = (unsigned short*)alloc((size_t)B_*4*4*N_*16);   //  8MB
  unsigned short* T128 = (unsigned short*)alloc((size_t)B_*8*4*N_*16);   // 16MB
  float* ccf  = (float*)alloc((size_t)B_*N_*4);
  int*   idx  = (int*)alloc((size_t)B_*N_*16*4);
  ull*   qkeys = (ull*)alloc((size_t)B_*N_*4*2*16*8);                    // 32MB
  unsigned int* glob = (unsigned int*)alloc((size_t)B_*1024*4);
  float* base1 = (float*)alloc((size_t)B_*512*4);
  float* base2 = (float*)alloc((size_t)B_*512*4);
  float* mid   = (float*)alloc((size_t)B_*M_*3*4);
  (void)ws_size; (void)in_sizes; (void)n_in; (void)out_size;

  const int SMEM4 = 4*4096 + 256;    // 16,640 B
  const int SMEM8 = 8*4096 + 256;    // 33,024 B -> 4 blocks/CU at MW=4
  hipFuncSetAttribute((const void*)k_knnF<4,4,4>, hipFuncAttributeMaxDynamicSharedMemorySize, SMEM4);
  hipFuncSetAttribute((const void*)k_knnF<8,4,4>, hipFuncAttributeMaxDynamicSharedMemorySize, SMEM8);

  hipMemsetAsync(nn64, 0xFF, (size_t)B_*N_*8, stream);
  k_init<<<dim3((B_*1024+255)/256), 256, 0, stream>>>(glob);
  k_nn1<<<dim3(N_/256, 4, B_), 256, 0, stream>>>(pts, nn64);
  k_cov_mlp<<<dim3(N_/64, B_), 256, 0, stream>>>(pts, nn64, w1,b1,w2,b2,w3,b3, x);

  k_prep4<4><<<dim3(N_/256, B_), 256, 0, stream>>>(x, T64, ccf);
  k_knnF<4,4,4><<<dim3(N_/128, 4, B_), 256, SMEM4, stream>>>(T64, ccf, qkeys);
  k_sel<4><<<dim3(B_*N_/256), 256, 0, stream>>>(qkeys, idx);

  k_gpool_mlp<<<dim3(N_/64, B_), 256, 0, stream>>>(x, idx, g1a,g1ab,g1b,g1bb, g);

  k_prep4<8><<<dim3(N_/256, B_), 256, 0, stream>>>(g, T128, ccf);
  k_knnF<8,4,4><<<dim3(N_/128, 4, B_), 256, SMEM8, stream>>>(T128, ccf, qkeys);
  k_sel<4><<<dim3(B_*N_/256), 256, 0, stream>>>(qkeys, idx);

  k_hpool_max<<<dim3(N_/32, B_), 256, 0, stream>>>(g, idx, g2a,g2ab,g2b,g2bb, glob);
  k_code<<<dim3(B_), 512, 0, stream>>>(glob, m1,m1b,m2,m2b, f1a,f1ab, f2a,f2ab, base1, base2);
  k_fold<2><<<dim3((M_+31)/32, B_), 256, 0, stream>>>(base1, f1a, f1b, f1bb, f1c, f1cb, nullptr, mid);
  k_fold<3><<<dim3((M_+31)/32, B_), 256, 0, stream>>>(base2, f2a, f2b, f2bb, f2c, f2cb, mid, out);
}

// Round 14
// 1638.205 us; speedup vs baseline: 1.1426x; 1.0873x over previous
//
#include <hip/hip_runtime.h>
#include <stdint.h>

#define B_ 4
#define N_ 8192
#define K_ 16
#define FEAT_ 512
#define GRID_ 45
#define M_ (GRID_*GRID_)

typedef unsigned long long ull;
typedef __bf16 bf16x8 __attribute__((ext_vector_type(8)));
typedef float f32x16 __attribute__((ext_vector_type(16)));

// ---------- helpers ----------

__device__ __forceinline__ unsigned int fmap(float f){
  unsigned int u = __float_as_uint(f);
  return (u & 0x80000000u) ? ~u : (u | 0x80000000u);
}
__device__ __forceinline__ float funmap(unsigned int u){
  return (u & 0x80000000u) ? __uint_as_float(u ^ 0x80000000u) : __uint_as_float(~u);
}

__device__ __forceinline__ void ins16(ull (&d)[16], ull k){
  if (k < d[15]){
    bool c[16];
#pragma unroll
    for (int s = 0; s < 16; ++s) c[s] = k < d[s];
#pragma unroll
    for (int s = 15; s >= 1; --s) d[s] = c[s-1] ? d[s-1] : (c[s] ? k : d[s]);
    if (c[0]) d[0] = k;
  }
}

// stable u32-key/u32-idx sorted insert, strict < : ascending-idx scan order
// reproduces (dist, idx) lex semantics exactly.
__device__ __forceinline__ void ins16b(unsigned (&dk)[16], unsigned (&di)[16],
                                       unsigned k, unsigned id){
  if (k < dk[15]){
    bool c[16];
#pragma unroll
    for (int s = 0; s < 16; ++s) c[s] = k < dk[s];
#pragma unroll
    for (int s = 15; s >= 1; --s){
      dk[s] = c[s-1] ? dk[s-1] : (c[s] ? k  : dk[s]);
      di[s] = c[s-1] ? di[s-1] : (c[s] ? id : di[s]);
    }
    if (c[0]){ dk[0] = k; di[0] = id; }
  }
}

__device__ __forceinline__ void bsplit(float x, unsigned short& h, unsigned short& l){
  __bf16 hh = (__bf16)x;
  __bf16 ll = (__bf16)(x - (float)hh);
  h = __builtin_bit_cast(unsigned short, hh);
  l = __builtin_bit_cast(unsigned short, ll);
}

#define GLDS16(l, g) __builtin_amdgcn_global_load_lds((const __attribute__((address_space(1))) void*)(g), (__attribute__((address_space(3))) void*)(l), 16, 0, 0)
#define GLDS4(l, g)  __builtin_amdgcn_global_load_lds((const __attribute__((address_space(1))) void*)(g), (__attribute__((address_space(3))) void*)(l), 4, 0, 0)

#define KEY_INF 0xFF800000FFFFFFFFull

// ---------- init ----------
__global__ void k_init(unsigned int* glob){
  int i = blockIdx.x*256 + threadIdx.x;
  if (i < B_*1024) glob[i] = 0x007FFFFFu;   // fmap(-inf)
}

// ---------- KNN #1: nearest other point (exact fp32, float4 LDS) ----------
__global__ __launch_bounds__(256) void k_nn1(const float* __restrict__ pts,
                                             unsigned long long* __restrict__ nn64){
  __shared__ __align__(16) float sp4[2048][4];
  int b = blockIdx.z, s = blockIdx.y;
  int c0 = s*2048;
  const float* P = pts + (size_t)b*N_*3;
  for (int p = threadIdx.x; p < 2048; p += 256){
    const float* src = P + (size_t)(c0 + p)*3;
    sp4[p][0] = src[0]; sp4[p][1] = src[1]; sp4[p][2] = src[2]; sp4[p][3] = 0.f;
  }
  __syncthreads();
  int n = blockIdx.x*256 + threadIdx.x;
  float qx = P[n*3], qy = P[n*3+1], qz = P[n*3+2];
  float best = 1e30f; int bi = 0;
  for (int j = 0; j < 2048; ++j){
    float4 sv = *(const float4*)sp4[j];
    float dx = qx - sv.x, dy = qy - sv.y, dz = qz - sv.z;
    float d2 = fmaf(dx,dx, fmaf(dy,dy, dz*dz));
    int cj = c0 + j;
    if (d2 < best && cj != n){ best = d2; bi = cj; }
  }
  unsigned long long key = ((unsigned long long)__float_as_uint(best) << 32) | (unsigned int)bi;
  atomicMin(&nn64[(size_t)b*N_ + n], key);
}

// ---------- local_cov + 3 convs + fused T64/cc emit ----------
__global__ __launch_bounds__(256) void k_cov_mlp(const float* __restrict__ pts,
    const unsigned long long* __restrict__ nn64,
    const float* __restrict__ w1, const float* __restrict__ b1,
    const float* __restrict__ w2, const float* __restrict__ b2,
    const float* __restrict__ w3, const float* __restrict__ b3,
    float* __restrict__ xout, unsigned short* __restrict__ T,
    float* __restrict__ cc){
  __shared__ __align__(16) float W1t[12*64];
  __shared__ __align__(16) float W2t[64*64];
  __shared__ __align__(16) float W3t[64*64];
  __shared__ float B1[64], B2[64], B3[64];
  __shared__ __align__(16) float x0[64][12];
  __shared__ __align__(16) float h1[64][64];
  __shared__ __align__(16) float h2[64][64];
  int b = blockIdx.y; int n0 = blockIdx.x*64; int tid = threadIdx.x;
  for (int i = tid; i < 12*64; i += 256){ int o = i % 64, ci = i / 64; W1t[i] = w1[o*12 + ci]; }
  for (int i = tid; i < 64*64; i += 256){ int o = i % 64, ci = i / 64; W2t[i] = w2[o*64 + ci]; W3t[i] = w3[o*64 + ci]; }
  if (tid < 64){ B1[tid]=b1[tid]; B2[tid]=b2[tid]; B3[tid]=b3[tid]; }
  {
    int p = tid % 64, cg = tid / 64;
    int n = n0 + p;
    const float* P = pts + ((size_t)b*N_ + n)*3;
    int nb = (int)(nn64[(size_t)b*N_ + n] & 0xFFFFFFFFull);
    const float* Q = pts + ((size_t)b*N_ + nb)*3;
    if (cg == 0){ x0[p][0]=P[0]; x0[p][1]=P[1]; x0[p][2]=P[2]; }
    else { int i = cg-1; float pi = P[i];
      x0[p][3+i*3+0]=pi*Q[0]; x0[p][3+i*3+1]=pi*Q[1]; x0[p][3+i*3+2]=pi*Q[2]; }
  }
  __syncthreads();
  { int o = tid % 64, pg = tid / 64;
    for (int p = pg; p < 64; p += 4){
      float acc = B1[o];
#pragma unroll
      for (int ci = 0; ci < 12; ++ci) acc = fmaf(W1t[ci*64+o], x0[p][ci], acc);
      h1[p][o] = fmaxf(acc, 0.f);
    } }
  __syncthreads();
  { int o = tid % 64, pg = tid / 64;
    for (int p = pg; p < 64; p += 4){
      float acc = B2[o];
#pragma unroll
      for (int ci = 0; ci < 64; ++ci) acc = fmaf(W2t[ci*64+o], h1[p][ci], acc);
      h2[p][o] = fmaxf(acc, 0.f);
    } }
  __syncthreads();
  { int o = tid % 64, pg = tid / 64;
    for (int p = pg; p < 64; p += 4){
      float acc = B3[o];
#pragma unroll
      for (int ci = 0; ci < 64; ++ci) acc = fmaf(W3t[ci*64+o], h2[p][ci], acc);
      float r = fmaxf(acc, 0.f);
      xout[((size_t)b*N_ + n0 + p)*64 + o] = r;
      h1[p][o] = r;                       // h1 free after phase 2: reuse for x3
    } }
  __syncthreads();
  // fused prep<4>: granule emit (8 bf16 ch per 16B) + per-row norms
  {
    char* Tb = (char*)T;
    const size_t HS = (size_t)N_*16, PS = 2*HS, KS = 4*HS;
    const size_t Bb = (size_t)b*4*KS;
    for (int e = tid; e < 64*8; e += 256){
      int p = e >> 3, gg = e & 7;
      int kf = gg >> 1, h = gg & 1;
      unsigned short hs[8], ls[8];
#pragma unroll
      for (int j = 0; j < 8; ++j) bsplit(h1[p][gg*8+j], hs[j], ls[j]);
      size_t base = Bb + (size_t)kf*KS + (size_t)h*HS + (size_t)(n0+p)*16;
      *(uint4*)(Tb + base)      = *(uint4*)hs;
      *(uint4*)(Tb + base + PS) = *(uint4*)ls;
    }
    if (tid < 64){
      float ss = 0.f;
#pragma unroll 8
      for (int c = 0; c < 64; ++c){ float v = h1[tid][(c + tid) & 63]; ss = fmaf(v, v, ss); }
      cc[(size_t)b*N_ + n0 + tid] = ss;
    }
  }
}

// ---------- prep: bf16 hi/lo split into K-major granule layout + norms ----------
template<int KF>
__global__ __launch_bounds__(256) void k_prep4(const float* __restrict__ f,
    unsigned short* __restrict__ T, float* __restrict__ cc){
  int b = blockIdx.y; int n = blockIdx.x*256 + threadIdx.x;
  const float* src = f + ((size_t)b*N_ + n)*(KF*16);
  char* Tb = (char*)T;
  float ss = 0.f;
#pragma unroll
  for (int kf = 0; kf < KF; ++kf){
    float v[16];
#pragma unroll
    for (int c4 = 0; c4 < 4; ++c4){
      float4 t4 = *(const float4*)&src[kf*16 + c4*4];
      v[c4*4]=t4.x; v[c4*4+1]=t4.y; v[c4*4+2]=t4.z; v[c4*4+3]=t4.w;
    }
    unsigned short hs[16], ls[16];
#pragma unroll
    for (int c = 0; c < 16; ++c){
      float x = v[c];
      ss = fmaf(x, x, ss);
      bsplit(x, hs[c], ls[c]);
    }
    size_t base = ((((size_t)b*KF + kf)*2)*2)*(size_t)(N_*16) + (size_t)n*16;
    const size_t HS = (size_t)N_*16;
    const size_t PS = 2*HS;
    *(uint4*)(Tb + base)            = *(uint4*)&hs[0];
    *(uint4*)(Tb + base + HS)       = *(uint4*)&hs[8];
    *(uint4*)(Tb + base + PS)       = *(uint4*)&ls[0];
    *(uint4*)(Tb + base + PS + HS)  = *(uint4*)&ls[8];
  }
  cc[(size_t)b*N_ + n] = ss;
}

// ---------- fused single-pass KNN: MFMA + gated stable u32 top-16 ----------
template<int KF, int MW, int S>
__global__ __launch_bounds__(256, MW) void k_knnF(const unsigned short* __restrict__ T,
    const float* __restrict__ ccg, ull* __restrict__ qkeys){
  extern __shared__ char smem[];
  constexpr int NT = (N_/S)/64;
  char* As = smem;                    // KF*4096
  char* Cs = smem + KF*4096;          // 256

  const int tid = threadIdx.x, lane = tid & 63, wid = tid >> 6;
  const int hi = lane >> 5, l31 = lane & 31;
  const int b = blockIdx.z, sp = blockIdx.y, q0 = blockIdx.x*128;
  const int c0 = sp*(N_/S);
  const char* Tb = (const char*)T;
  const size_t HS = (size_t)N_*16, PS = 2*HS, KS = 4*HS;
  const size_t Bb = (size_t)b*KF*KS;
  const float* ccb = ccg + (size_t)b*N_;

  const int q = q0 + wid*32 + l31;
  bf16x8 qh[KF], ql[KF];
#pragma unroll
  for (int kf = 0; kf < KF; ++kf){
    size_t o = Bb + kf*KS + hi*HS + (size_t)q*16;
    qh[kf] = *(const bf16x8*)(Tb + o);
    ql[kf] = *(const bf16x8*)(Tb + o + PS);
  }

  unsigned dk[16], di[16];
#pragma unroll
  for (int t = 0; t < 16; ++t){ dk[t] = 0xFFFFFFFFu; di[t] = 0xFFFFFFFFu; }
  float kapf = __builtin_inff();

  auto stage = [&](int t0){
#pragma unroll
    for (int si = 0; si < KF; ++si){
      int s = wid + 4*si;
      int kf = s >> 2, pl = (s >> 1) & 1, h = s & 1;
      GLDS16(As + s*1024,
             Tb + Bb + kf*KS + pl*PS + h*HS + (size_t)(c0 + t0)*16);
    }
    if (wid == 0) GLDS4(Cs, (const char*)(ccb + c0 + t0));
  };

  for (int t = 0; t < NT; ++t){
    const int t0 = t*64;
    __syncthreads();
    stage(t0);
    asm volatile("s_waitcnt vmcnt(0)" ::: "memory");
    __syncthreads();

    const char* Ab = As + hi*1024 + l31*16;
    const float* cct = (const float*)Cs;
#pragma unroll
    for (int i = 0; i < 2; ++i){
      f32x16 acc = (f32x16)(0.f);
#pragma unroll
      for (int kf = 0; kf < KF; ++kf){
        bf16x8 ah = *(const bf16x8*)(Ab + kf*4096 + i*512);
        bf16x8 al = *(const bf16x8*)(Ab + kf*4096 + 2048 + i*512);
        acc = __builtin_amdgcn_mfma_f32_32x32x16_bf16(ah, qh[kf], acc, 0, 0, 0);
        acc = __builtin_amdgcn_mfma_f32_32x32x16_bf16(ah, ql[kf], acc, 0, 0, 0);
        acc = __builtin_amdgcn_mfma_f32_32x32x16_bf16(al, qh[kf], acc, 0, 0, 0);
      }
#pragma unroll
      for (int rq = 0; rq < 4; ++rq){
        float4 c4 = *(const float4*)(cct + i*32 + 4*hi + 8*rq);
        int rowb = c0 + t0 + i*32 + 4*hi + 8*rq;
        float v0 = fmaf(-2.f, acc[rq*4+0], c4.x);
        float v1 = fmaf(-2.f, acc[rq*4+1], c4.y);
        float v2 = fmaf(-2.f, acc[rq*4+2], c4.z);
        float v3 = fmaf(-2.f, acc[rq*4+3], c4.w);
        if (fminf(fminf(v0, v1), fminf(v2, v3)) < kapf){
          if (v0 < kapf) ins16b(dk, di, fmap(v0), (unsigned)(rowb+0));
          if (v1 < kapf) ins16b(dk, di, fmap(v1), (unsigned)(rowb+1));
          if (v2 < kapf) ins16b(dk, di, fmap(v2), (unsigned)(rowb+2));
          if (v3 < kapf) ins16b(dk, di, fmap(v3), (unsigned)(rowb+3));
          unsigned kk = dk[15];
          kapf = (kk >= 0xFF800000u) ? __builtin_inff() : funmap(kk);
        }
      }
    }
  }
  ull* op = qkeys + (((size_t)((size_t)b*N_ + q)*S + sp)*2 + hi)*16;
#pragma unroll
  for (int t = 0; t < 16; ++t) op[t] = ((ull)dk[t] << 32) | di[t];
}

// ---------- final exact top-16 over S*2 regions x 16 keys ----------
template<int S>
__global__ void k_sel(const ull* __restrict__ qkeys, int* __restrict__ idxout){
  int i = blockIdx.x*256 + threadIdx.x;
  if (i >= B_*N_) return;
  ull best[16];
#pragma unroll
  for (int t = 0; t < 16; ++t) best[t] = KEY_INF;
  const ull* kp = qkeys + (size_t)i*(S*32);
  for (int t = 0; t < S*32; ++t) ins16(best, kp[t]);
  int* op = idxout + (size_t)i*16;
#pragma unroll
  for (int t = 0; t < 16; ++t) op[t] = (int)(best[t] & 0xffffffffu);
}

// ---------- maxpool(x) + conv 64->64 relu + conv 64->128 ----------
__global__ __launch_bounds__(256) void k_gpool_mlp(const float* __restrict__ x,
    const int* __restrict__ idx,
    const float* __restrict__ g1a, const float* __restrict__ g1ab,
    const float* __restrict__ g1b, const float* __restrict__ g1bb,
    float* __restrict__ gout){
  __shared__ __align__(16) float Wt1[64*64];
  __shared__ __align__(16) float Wt2[64*128];
  __shared__ float Ba[64], Bb[128];
  __shared__ __align__(16) float m[64][64];
  __shared__ __align__(16) float r[64][64];
  int b = blockIdx.y; int n0 = blockIdx.x*64; int tid = threadIdx.x;
  for (int i = tid; i < 64*64; i += 256){ int o = i%64, ci = i/64; Wt1[i] = g1a[o*64+ci]; }
  for (int i = tid; i < 64*128; i += 256){ int o = i%128, ci = i/128; Wt2[i] = g1b[o*64+ci]; }
  if (tid < 64) Ba[tid] = g1ab[tid];
  if (tid < 128) Bb[tid] = g1bb[tid];
  { int p = tid/4, cg = tid%4; int n = n0 + p;
    const int* ip = idx + ((size_t)b*N_ + n)*16;
    float mm[16];
#pragma unroll
    for (int u = 0; u < 16; ++u) mm[u] = -1e30f;
    for (int k = 0; k < 16; ++k){
      int nb = ip[k];
      const float4* src = (const float4*)(x + ((size_t)b*N_ + nb)*64 + cg*16);
#pragma unroll
      for (int u = 0; u < 4; ++u){
        float4 v = src[u];
        mm[4*u  ] = fmaxf(mm[4*u  ], v.x); mm[4*u+1] = fmaxf(mm[4*u+1], v.y);
        mm[4*u+2] = fmaxf(mm[4*u+2], v.z); mm[4*u+3] = fmaxf(mm[4*u+3], v.w);
      }
    }
#pragma unroll
    for (int u = 0; u < 16; ++u) m[p][cg*16+u] = mm[u];
  }
  __syncthreads();
  { int o = tid%64, pg = tid/64;
    float acc[16];
#pragma unroll
    for (int u = 0; u < 16; ++u) acc[u] = Ba[o];
    for (int ci = 0; ci < 64; ci += 4){
      float w0 = Wt1[ci*64+o], w1_ = Wt1[(ci+1)*64+o], w2_ = Wt1[(ci+2)*64+o], w3_ = Wt1[(ci+3)*64+o];
#pragma unroll
      for (int u = 0; u < 16; ++u){
        float4 mv = *(const float4*)&m[pg*16+u][ci];
        acc[u] = fmaf(w0, mv.x, acc[u]); acc[u] = fmaf(w1_, mv.y, acc[u]);
        acc[u] = fmaf(w2_, mv.z, acc[u]); acc[u] = fmaf(w3_, mv.w, acc[u]);
      }
    }
#pragma unroll
    for (int u = 0; u < 16; ++u) r[pg*16+u][o] = fmaxf(acc[u], 0.f);
  }
  __syncthreads();
  { int o = tid%128, pg = tid/128;   // no relu on this conv
    float acc[32];
#pragma unroll
    for (int u = 0; u < 32; ++u) acc[u] = Bb[o];
    for (int ci = 0; ci < 64; ci += 4){
      float w0 = Wt2[ci*128+o], w1_ = Wt2[(ci+1)*128+o], w2_ = Wt2[(ci+2)*128+o], w3_ = Wt2[(ci+3)*128+o];
#pragma unroll
      for (int u = 0; u < 32; ++u){
        float4 rv = *(const float4*)&r[pg*32+u][ci];
        acc[u] = fmaf(w0, rv.x, acc[u]); acc[u] = fmaf(w1_, rv.y, acc[u]);
        acc[u] = fmaf(w2_, rv.z, acc[u]); acc[u] = fmaf(w3_, rv.w, acc[u]);
      }
    }
#pragma unroll
    for (int u = 0; u < 32; ++u)
      gout[((size_t)b*N_ + n0 + pg*32 + u)*128 + o] = acc[u];
  }
}

// ---------- maxpool(g) + conv 128->128 relu + conv 128->1024 + global max ----------
__global__ __launch_bounds__(256) void k_hpool_max(const float* __restrict__ g,
    const int* __restrict__ idx,
    const float* __restrict__ g2a, const float* __restrict__ g2ab,
    const float* __restrict__ g2b, const float* __restrict__ g2bb,
    unsigned int* __restrict__ glob){
  __shared__ __align__(16) float m[32][128];
  __shared__ __align__(16) float t[32][128];
  int b = blockIdx.y; int n0 = blockIdx.x*32; int tid = threadIdx.x;
  { int p = tid/8, cg = tid%8; int n = n0+p;
    const int* ip = idx + ((size_t)b*N_+n)*16;
    float mm[16];
#pragma unroll
    for (int u = 0; u < 16; ++u) mm[u] = -1e30f;
    for (int k = 0; k < 16; ++k){
      int nb = ip[k];
      const float4* src = (const float4*)(g + ((size_t)b*N_+nb)*128 + cg*16);
#pragma unroll
      for (int u = 0; u < 4; ++u){
        float4 v = src[u];
        mm[4*u  ] = fmaxf(mm[4*u  ], v.x); mm[4*u+1] = fmaxf(mm[4*u+1], v.y);
        mm[4*u+2] = fmaxf(mm[4*u+2], v.z); mm[4*u+3] = fmaxf(mm[4*u+3], v.w);
      }
    }
#pragma unroll
    for (int u = 0; u < 16; ++u) m[p][cg*16+u] = mm[u];
  }
  __syncthreads();
  { int o = tid%128, pg = tid/128;
    float acc[16];
#pragma unroll
    for (int u = 0; u < 16; ++u) acc[u] = g2ab[o];
    const float4* wrow = (const float4*)(g2a + (size_t)o*128);
    for (int c4 = 0; c4 < 32; ++c4){
      float4 wv = wrow[c4];
#pragma unroll
      for (int u = 0; u < 16; ++u){
        float4 mv = *(const float4*)&m[pg*16+u][c4*4];
        acc[u] = fmaf(wv.x,mv.x,acc[u]); acc[u] = fmaf(wv.y,mv.y,acc[u]);
        acc[u] = fmaf(wv.z,mv.z,acc[u]); acc[u] = fmaf(wv.w,mv.w,acc[u]);
      }
    }
#pragma unroll
    for (int u = 0; u < 16; ++u) t[pg*16+u][o] = fmaxf(acc[u], 0.f);
  }
  __syncthreads();
  for (int oc = 0; oc < 4; ++oc){
    int o = oc*256 + tid;
    const float4* wrow = (const float4*)(g2b + (size_t)o*128);
    float acc[32];
#pragma unroll
    for (int u = 0; u < 32; ++u) acc[u] = 0.f;
    for (int c4 = 0; c4 < 32; ++c4){
      float4 wv = wrow[c4];
#pragma unroll
      for (int u = 0; u < 32; ++u){
        float4 tv = *(const float4*)&t[u][c4*4];
        acc[u] = fmaf(wv.x,tv.x,acc[u]); acc[u] = fmaf(wv.y,tv.y,acc[u]);
        acc[u] = fmaf(wv.z,tv.z,acc[u]); acc[u] = fmaf(wv.w,tv.w,acc[u]);
      }
    }
    float bias = g2bb[o];
    float mx = -1e30f;
#pragma unroll
    for (int u = 0; u < 32; ++u) mx = fmaxf(mx, acc[u] + bias);
    atomicMax(&glob[b*1024 + o], fmap(mx));
  }
}

// ---------- code MLP + decoder base precompute ----------
__global__ __launch_bounds__(512) void k_code(const unsigned int* __restrict__ glob,
    const float* __restrict__ m1, const float* __restrict__ m1b,
    const float* __restrict__ m2, const float* __restrict__ m2b,
    const float* __restrict__ f1a, const float* __restrict__ f1ab,
    const float* __restrict__ f2a, const float* __restrict__ f2ab,
    float* __restrict__ base1, float* __restrict__ base2){
  __shared__ __align__(16) float gl_s[1024];
  __shared__ __align__(16) float hid_s[512];
  __shared__ __align__(16) float code_s[512];
  int b = blockIdx.x; int tid = threadIdx.x;
  for (int i = tid; i < 1024; i += 512) gl_s[i] = funmap(glob[b*1024+i]);
  __syncthreads();
  { float acc = m1b[tid];
    const float4* wr = (const float4*)(m1 + (size_t)tid*1024);
    for (int c4 = 0; c4 < 256; ++c4){ float4 wv = wr[c4]; float4 gv = *(const float4*)&gl_s[c4*4];
      acc = fmaf(wv.x,gv.x,acc); acc = fmaf(wv.y,gv.y,acc);
      acc = fmaf(wv.z,gv.z,acc); acc = fmaf(wv.w,gv.w,acc); }
    hid_s[tid] = fmaxf(acc, 0.f);
  }
  __syncthreads();
  { float acc = m2b[tid];
    const float4* wr = (const float4*)(m2 + (size_t)tid*512);
    for (int c4 = 0; c4 < 128; ++c4){ float4 wv = wr[c4]; float4 hv = *(const float4*)&hid_s[c4*4];
      acc = fmaf(wv.x,hv.x,acc); acc = fmaf(wv.y,hv.y,acc);
      acc = fmaf(wv.z,hv.z,acc); acc = fmaf(wv.w,hv.w,acc); }
    code_s[tid] = acc;
  }
  __syncthreads();
  { float acc = f1ab[tid];
    const float* wr = f1a + (size_t)tid*514;
    for (int c = 0; c < 512; ++c) acc = fmaf(wr[c], code_s[c], acc);
    base1[b*512 + tid] = acc;
  }
  { float acc = f2ab[tid];
    const float* wr = f2a + (size_t)tid*515;
    for (int c = 0; c < 512; ++c) acc = fmaf(wr[c], code_s[c], acc);
    base2[b*512 + tid] = acc;
  }
}

// ---------- folding decoder (16-point tiles -> 2 blocks/CU) ----------
template<int NIN>
__global__ __launch_bounds__(256) void k_fold(const float* __restrict__ base,
    const float* __restrict__ fa,
    const float* __restrict__ fb, const float* __restrict__ fbb,
    const float* __restrict__ fc, const float* __restrict__ fcb,
    const float* __restrict__ pin, float* __restrict__ pout){
  __shared__ __align__(16) float y1[16][512];
  __shared__ __align__(16) float y2[16][516];
  __shared__ float pcoord[16][NIN];
  int b = blockIdx.y; int m0 = blockIdx.x*16; int tid = threadIdx.x;
  if (tid < 16*NIN){
    int p = tid / NIN, c = tid % NIN;
    int mm = min(m0 + p, M_-1);
    float v;
    if (NIN == 2){
      const float step = 0.6f/44.f;
      int ii = (c == 0) ? (mm/GRID_) : (mm%GRID_);
      v = -0.3f + step*ii;
    } else {
      v = pin[((size_t)b*M_ + mm)*3 + c];
    }
    pcoord[p][c] = v;
  }
  __syncthreads();
  const int stride_a = 512 + NIN;
  for (int rep = 0; rep < 2; ++rep){
    int o = rep*256 + tid;
    float av[NIN];
#pragma unroll
    for (int c = 0; c < NIN; ++c) av[c] = fa[(size_t)o*stride_a + 512 + c];
    float bv = base[b*512 + o];
#pragma unroll
    for (int p = 0; p < 16; ++p){
      float acc = bv;
#pragma unroll
      for (int c = 0; c < NIN; ++c) acc = fmaf(av[c], pcoord[p][c], acc);
      y1[p][o] = fmaxf(acc, 0.f);
    }
  }
  __syncthreads();
  for (int rep = 0; rep < 2; ++rep){
    int o2 = rep*256 + tid;
    const float* wr = fb + (size_t)o2*512;
    float acc[16];
#pragma unroll
    for (int u = 0; u < 16; ++u) acc[u] = 0.f;
    for (int c4 = 0; c4 < 128; ++c4){
      float4 wv = *(const float4*)&wr[c4*4];
#pragma unroll
      for (int u = 0; u < 16; ++u){
        float4 yv = *(const float4*)&y1[u][c4*4];
        acc[u] = fmaf(wv.x,yv.x,acc[u]); acc[u] = fmaf(wv.y,yv.y,acc[u]);
        acc[u] = fmaf(wv.z,yv.z,acc[u]); acc[u] = fmaf(wv.w,yv.w,acc[u]);
      }
    }
    float bias = fbb[o2];
#pragma unroll
    for (int u = 0; u < 16; ++u) y2[u][o2] = fmaxf(acc[u] + bias, 0.f);
  }
  __syncthreads();
  if (tid < 48){
    int p = tid / 3, c = tid % 3;
    const float* wr = fc + (size_t)c*512;
    float acc = fcb[c];
    for (int o4 = 0; o4 < 128; ++o4){
      float4 wv = *(const float4*)&wr[o4*4];
      float4 yv = *(const float4*)&y2[p][o4*4];
      acc = fmaf(wv.x,yv.x,acc); acc = fmaf(wv.y,yv.y,acc);
      acc = fmaf(wv.z,yv.z,acc); acc = fmaf(wv.w,yv.w,acc);
    }
    int mm = m0 + p;
    if (mm < M_) pout[((size_t)b*M_ + mm)*3 + c] = acc;
  }
}

// ---------- launcher ----------
extern "C" void kernel_launch(void* const* d_in, const int* in_sizes, int n_in,
                              void* d_out, int out_size, void* d_ws, size_t ws_size,
                              hipStream_t stream){
  const float* pts  = (const float*)d_in[0];
  const float* w1   = (const float*)d_in[1];  const float* b1   = (const float*)d_in[2];
  const float* w2   = (const float*)d_in[3];  const float* b2   = (const float*)d_in[4];
  const float* w3   = (const float*)d_in[5];  const float* b3   = (const float*)d_in[6];
  const float* g1a  = (const float*)d_in[7];  const float* g1ab = (const float*)d_in[8];
  const float* g1b  = (const float*)d_in[9];  const float* g1bb = (const float*)d_in[10];
  const float* g2a  = (const float*)d_in[11]; const float* g2ab = (const float*)d_in[12];
  const float* g2b  = (const float*)d_in[13]; const float* g2bb = (const float*)d_in[14];
  const float* m1   = (const float*)d_in[15]; const float* m1b  = (const float*)d_in[16];
  const float* m2   = (const float*)d_in[17]; const float* m2b  = (const float*)d_in[18];
  const float* f1a  = (const float*)d_in[19]; const float* f1ab = (const float*)d_in[20];
  const float* f1b  = (const float*)d_in[21]; const float* f1bb = (const float*)d_in[22];
  const float* f1c  = (const float*)d_in[23]; const float* f1cb = (const float*)d_in[24];
  const float* f2a  = (const float*)d_in[25]; const float* f2ab = (const float*)d_in[26];
  const float* f2b  = (const float*)d_in[27]; const float* f2bb = (const float*)d_in[28];
  const float* f2c  = (const float*)d_in[29]; const float* f2cb = (const float*)d_in[30];
  float* out = (float*)d_out;

  char* w = (char*)d_ws;
  auto alloc = [&](size_t bytes){ char* p = w; w += (bytes + 255) & ~(size_t)255; return p; };
  unsigned long long* nn64 = (unsigned long long*)alloc((size_t)B_*N_*8);
  float* x    = (float*)alloc((size_t)B_*N_*64*4);
  float* g    = (float*)alloc((size_t)B_*N_*128*4);
  unsigned short* T64  = (unsigned short*)alloc((size_t)B_*4*4*N_*16);   //  8MB
  unsigned short* T128 = (unsigned short*)alloc((size_t)B_*8*4*N_*16);   // 16MB
  float* ccf  = (float*)alloc((size_t)B_*N_*4);
  int*   idx  = (int*)alloc((size_t)B_*N_*16*4);
  ull*   qkeys = (ull*)alloc((size_t)B_*N_*4*2*16*8);                    // 32MB
  unsigned int* glob = (unsigned int*)alloc((size_t)B_*1024*4);
  float* base1 = (float*)alloc((size_t)B_*512*4);
  float* base2 = (float*)alloc((size_t)B_*512*4);
  float* mid   = (float*)alloc((size_t)B_*M_*3*4);
  (void)ws_size; (void)in_sizes; (void)n_in; (void)out_size;

  const int SMEM4 = 4*4096 + 256;    // 16,640 B
  const int SMEM8 = 8*4096 + 256;    // 33,024 B
  hipFuncSetAttribute((const void*)k_knnF<4,4,4>, hipFuncAttributeMaxDynamicSharedMemorySize, SMEM4);
  hipFuncSetAttribute((const void*)k_knnF<8,3,4>, hipFuncAttributeMaxDynamicSharedMemorySize, SMEM8);

  hipMemsetAsync(nn64, 0xFF, (size_t)B_*N_*8, stream);
  k_init<<<dim3((B_*1024+255)/256), 256, 0, stream>>>(glob);
  k_nn1<<<dim3(N_/256, 4, B_), 256, 0, stream>>>(pts, nn64);
  k_cov_mlp<<<dim3(N_/64, B_), 256, 0, stream>>>(pts, nn64, w1,b1,w2,b2,w3,b3, x, T64, ccf);

  k_knnF<4,4,4><<<dim3(N_/128, 4, B_), 256, SMEM4, stream>>>(T64, ccf, qkeys);
  k_sel<4><<<dim3(B_*N_/256), 256, 0, stream>>>(qkeys, idx);

  k_gpool_mlp<<<dim3(N_/64, B_), 256, 0, stream>>>(x, idx, g1a,g1ab,g1b,g1bb, g);

  k_prep4<8><<<dim3(N_/256, B_), 256, 0, stream>>>(g, T128, ccf);
  k_knnF<8,3,4><<<dim3(N_/128, 4, B_), 256, SMEM8, stream>>>(T128, ccf, qkeys);
  k_sel<4><<<dim3(B_*N_/256), 256, 0, stream>>>(qkeys, idx);

  k_hpool_max<<<dim3(N_/32, B_), 256, 0, stream>>>(g, idx, g2a,g2ab,g2b,g2bb, glob);
  k_code<<<dim3(B_), 512, 0, stream>>>(glob, m1,m1b,m2,m2b, f1a,f1ab, f2a,f2ab, base1, base2);
  k_fold<2><<<dim3((M_+15)/16, B_), 256, 0, stream>>>(base1, f1a, f1b, f1bb, f1c, f1cb, nullptr, mid);
  k_fold<3><<<dim3((M_+15)/16, B_), 256, 0, stream>>>(base2, f2a, f2b, f2bb, f2c, f2cb, mid, out);
}

// Round 15
// 1624.091 us; speedup vs baseline: 1.1525x; 1.0087x over previous
//
#include <hip/hip_runtime.h>
#include <stdint.h>

#define B_ 4
#define N_ 8192
#define K_ 16
#define FEAT_ 512
#define GRID_ 45
#define M_ (GRID_*GRID_)

typedef unsigned long long ull;
typedef __bf16 bf16x8 __attribute__((ext_vector_type(8)));
typedef float f32x16 __attribute__((ext_vector_type(16)));

// ---------- helpers ----------

__device__ __forceinline__ unsigned int fmap(float f){
  unsigned int u = __float_as_uint(f);
  return (u & 0x80000000u) ? ~u : (u | 0x80000000u);
}
__device__ __forceinline__ float funmap(unsigned int u){
  return (u & 0x80000000u) ? __uint_as_float(u ^ 0x80000000u) : __uint_as_float(~u);
}

// stable u32-key/u32-idx sorted insert, strict < : ascending-idx scan order
// reproduces (dist, idx) lex semantics exactly.
__device__ __forceinline__ void ins16b(unsigned (&dk)[16], unsigned (&di)[16],
                                       unsigned k, unsigned id){
  if (k < dk[15]){
    bool c[16];
#pragma unroll
    for (int s = 0; s < 16; ++s) c[s] = k < dk[s];
#pragma unroll
    for (int s = 15; s >= 1; --s){
      dk[s] = c[s-1] ? dk[s-1] : (c[s] ? k  : dk[s]);
      di[s] = c[s-1] ? di[s-1] : (c[s] ? id : di[s]);
    }
    if (c[0]){ dk[0] = k; di[0] = id; }
  }
}

// bitonic cleanup sort of a 16-element bitonic sequence (ascending)
__device__ __forceinline__ void bsort16(ull (&c)[16]){
#pragma unroll
  for (int d = 8; d >= 1; d >>= 1){
#pragma unroll
    for (int i = 0; i < 16; ++i){
      if (!(i & d)){
        ull x = c[i], y = c[i|d];
        bool lt = x < y;
        c[i]   = lt ? x : y;
        c[i|d] = lt ? y : x;
      }
    }
  }
}
// merge two sorted-ascending 16-lists -> sorted-ascending lowest 16 of union
__device__ __forceinline__ void bmerge16(ull (&a)[16], const ull (&b)[16]){
#pragma unroll
  for (int i = 0; i < 16; ++i){
    ull bv = b[15-i];
    a[i] = a[i] < bv ? a[i] : bv;
  }
  bsort16(a);
}

__device__ __forceinline__ void bsplit(float x, unsigned short& h, unsigned short& l){
  __bf16 hh = (__bf16)x;
  __bf16 ll = (__bf16)(x - (float)hh);
  h = __builtin_bit_cast(unsigned short, hh);
  l = __builtin_bit_cast(unsigned short, ll);
}

#define GLDS16(l, g) __builtin_amdgcn_global_load_lds((const __attribute__((address_space(1))) void*)(g), (__attribute__((address_space(3))) void*)(l), 16, 0, 0)
#define GLDS4(l, g)  __builtin_amdgcn_global_load_lds((const __attribute__((address_space(1))) void*)(g), (__attribute__((address_space(3))) void*)(l), 4, 0, 0)

#define KEY_INF 0xFF800000FFFFFFFFull

// ---------- init ----------
__global__ void k_init(unsigned int* glob){
  int i = blockIdx.x*256 + threadIdx.x;
  if (i < B_*1024) glob[i] = 0x007FFFFFu;   // fmap(-inf)
}

// ---------- KNN #1: nearest other point (exact fp32, float4 LDS) ----------
__global__ __launch_bounds__(256) void k_nn1(const float* __restrict__ pts,
                                             unsigned long long* __restrict__ nn64){
  __shared__ __align__(16) float sp4[2048][4];
  int b = blockIdx.z, s = blockIdx.y;
  int c0 = s*2048;
  const float* P = pts + (size_t)b*N_*3;
  for (int p = threadIdx.x; p < 2048; p += 256){
    const float* src = P + (size_t)(c0 + p)*3;
    sp4[p][0] = src[0]; sp4[p][1] = src[1]; sp4[p][2] = src[2]; sp4[p][3] = 0.f;
  }
  __syncthreads();
  int n = blockIdx.x*256 + threadIdx.x;
  float qx = P[n*3], qy = P[n*3+1], qz = P[n*3+2];
  float best = 1e30f; int bi = 0;
  for (int j = 0; j < 2048; ++j){
    float4 sv = *(const float4*)sp4[j];
    float dx = qx - sv.x, dy = qy - sv.y, dz = qz - sv.z;
    float d2 = fmaf(dx,dx, fmaf(dy,dy, dz*dz));
    int cj = c0 + j;
    if (d2 < best && cj != n){ best = d2; bi = cj; }
  }
  unsigned long long key = ((unsigned long long)__float_as_uint(best) << 32) | (unsigned int)bi;
  atomicMin(&nn64[(size_t)b*N_ + n], key);
}

// ---------- local_cov + 3 convs + fused T64/cc emit ----------
__global__ __launch_bounds__(256) void k_cov_mlp(const float* __restrict__ pts,
    const unsigned long long* __restrict__ nn64,
    const float* __restrict__ w1, const float* __restrict__ b1,
    const float* __restrict__ w2, const float* __restrict__ b2,
    const float* __restrict__ w3, const float* __restrict__ b3,
    float* __restrict__ xout, unsigned short* __restrict__ T,
    float* __restrict__ cc){
  __shared__ __align__(16) float W1t[12*64];
  __shared__ __align__(16) float W2t[64*64];
  __shared__ __align__(16) float W3t[64*64];
  __shared__ float B1[64], B2[64], B3[64];
  __shared__ __align__(16) float x0[64][12];
  __shared__ __align__(16) float h1[64][64];
  __shared__ __align__(16) float h2[64][64];
  int b = blockIdx.y; int n0 = blockIdx.x*64; int tid = threadIdx.x;
  for (int i = tid; i < 12*64; i += 256){ int o = i % 64, ci = i / 64; W1t[i] = w1[o*12 + ci]; }
  for (int i = tid; i < 64*64; i += 256){ int o = i % 64, ci = i / 64; W2t[i] = w2[o*64 + ci]; W3t[i] = w3[o*64 + ci]; }
  if (tid < 64){ B1[tid]=b1[tid]; B2[tid]=b2[tid]; B3[tid]=b3[tid]; }
  {
    int p = tid % 64, cg = tid / 64;
    int n = n0 + p;
    const float* P = pts + ((size_t)b*N_ + n)*3;
    int nb = (int)(nn64[(size_t)b*N_ + n] & 0xFFFFFFFFull);
    const float* Q = pts + ((size_t)b*N_ + nb)*3;
    if (cg == 0){ x0[p][0]=P[0]; x0[p][1]=P[1]; x0[p][2]=P[2]; }
    else { int i = cg-1; float pi = P[i];
      x0[p][3+i*3+0]=pi*Q[0]; x0[p][3+i*3+1]=pi*Q[1]; x0[p][3+i*3+2]=pi*Q[2]; }
  }
  __syncthreads();
  { int o = tid % 64, pg = tid / 64;
    for (int p = pg; p < 64; p += 4){
      float acc = B1[o];
#pragma unroll
      for (int ci = 0; ci < 12; ++ci) acc = fmaf(W1t[ci*64+o], x0[p][ci], acc);
      h1[p][o] = fmaxf(acc, 0.f);
    } }
  __syncthreads();
  { int o = tid % 64, pg = tid / 64;
    for (int p = pg; p < 64; p += 4){
      float acc = B2[o];
#pragma unroll
      for (int ci = 0; ci < 64; ++ci) acc = fmaf(W2t[ci*64+o], h1[p][ci], acc);
      h2[p][o] = fmaxf(acc, 0.f);
    } }
  __syncthreads();
  { int o = tid % 64, pg = tid / 64;
    for (int p = pg; p < 64; p += 4){
      float acc = B3[o];
#pragma unroll
      for (int ci = 0; ci < 64; ++ci) acc = fmaf(W3t[ci*64+o], h2[p][ci], acc);
      float r = fmaxf(acc, 0.f);
      xout[((size_t)b*N_ + n0 + p)*64 + o] = r;
      h1[p][o] = r;                       // h1 free after phase 2: reuse for x3
    } }
  __syncthreads();
  // fused prep<4>: granule emit (8 bf16 ch per 16B) + per-row norms
  {
    char* Tb = (char*)T;
    const size_t HS = (size_t)N_*16, PS = 2*HS, KS = 4*HS;
    const size_t Bb = (size_t)b*4*KS;
    for (int e = tid; e < 64*8; e += 256){
      int p = e >> 3, gg = e & 7;
      int kf = gg >> 1, h = gg & 1;
      unsigned short hs[8], ls[8];
#pragma unroll
      for (int j = 0; j < 8; ++j) bsplit(h1[p][gg*8+j], hs[j], ls[j]);
      size_t base = Bb + (size_t)kf*KS + (size_t)h*HS + (size_t)(n0+p)*16;
      *(uint4*)(Tb + base)      = *(uint4*)hs;
      *(uint4*)(Tb + base + PS) = *(uint4*)ls;
    }
    if (tid < 64){
      float ss = 0.f;
#pragma unroll 8
      for (int c = 0; c < 64; ++c){ float v = h1[tid][(c + tid) & 63]; ss = fmaf(v, v, ss); }
      cc[(size_t)b*N_ + n0 + tid] = ss;
    }
  }
}

// ---------- prep: bf16 hi/lo split into K-major granule layout + norms ----------
template<int KF>
__global__ __launch_bounds__(256) void k_prep4(const float* __restrict__ f,
    unsigned short* __restrict__ T, float* __restrict__ cc){
  int b = blockIdx.y; int n = blockIdx.x*256 + threadIdx.x;
  const float* src = f + ((size_t)b*N_ + n)*(KF*16);
  char* Tb = (char*)T;
  float ss = 0.f;
#pragma unroll
  for (int kf = 0; kf < KF; ++kf){
    float v[16];
#pragma unroll
    for (int c4 = 0; c4 < 4; ++c4){
      float4 t4 = *(const float4*)&src[kf*16 + c4*4];
      v[c4*4]=t4.x; v[c4*4+1]=t4.y; v[c4*4+2]=t4.z; v[c4*4+3]=t4.w;
    }
    unsigned short hs[16], ls[16];
#pragma unroll
    for (int c = 0; c < 16; ++c){
      float x = v[c];
      ss = fmaf(x, x, ss);
      bsplit(x, hs[c], ls[c]);
    }
    size_t base = ((((size_t)b*KF + kf)*2)*2)*(size_t)(N_*16) + (size_t)n*16;
    const size_t HS = (size_t)N_*16;
    const size_t PS = 2*HS;
    *(uint4*)(Tb + base)            = *(uint4*)&hs[0];
    *(uint4*)(Tb + base + HS)       = *(uint4*)&hs[8];
    *(uint4*)(Tb + base + PS)       = *(uint4*)&ls[0];
    *(uint4*)(Tb + base + PS + HS)  = *(uint4*)&ls[8];
  }
  cc[(size_t)b*N_ + n] = ss;
}

// ---------- fused single-pass KNN: MFMA + gated stable u32 top-16 ----------
// S=2: longer per-region scans lower late-scan insert probability (the
// wave-coherent body count), at identical total MFMA work.
template<int KF, int MW, int S>
__global__ __launch_bounds__(256, MW) void k_knnF(const unsigned short* __restrict__ T,
    const float* __restrict__ ccg, ull* __restrict__ qkeys){
  extern __shared__ char smem[];
  constexpr int NT = (N_/S)/64;
  char* As = smem;                    // KF*4096
  char* Cs = smem + KF*4096;          // 256

  const int tid = threadIdx.x, lane = tid & 63, wid = tid >> 6;
  const int hi = lane >> 5, l31 = lane & 31;
  const int b = blockIdx.z, sp = blockIdx.y, q0 = blockIdx.x*128;
  const int c0 = sp*(N_/S);
  const char* Tb = (const char*)T;
  const size_t HS = (size_t)N_*16, PS = 2*HS, KS = 4*HS;
  const size_t Bb = (size_t)b*KF*KS;
  const float* ccb = ccg + (size_t)b*N_;

  const int q = q0 + wid*32 + l31;
  bf16x8 qh[KF], ql[KF];
#pragma unroll
  for (int kf = 0; kf < KF; ++kf){
    size_t o = Bb + kf*KS + hi*HS + (size_t)q*16;
    qh[kf] = *(const bf16x8*)(Tb + o);
    ql[kf] = *(const bf16x8*)(Tb + o + PS);
  }

  unsigned dk[16], di[16];
#pragma unroll
  for (int t = 0; t < 16; ++t){ dk[t] = 0xFFFFFFFFu; di[t] = 0xFFFFFFFFu; }
  float kapf = __builtin_inff();

  auto stage = [&](int t0){
#pragma unroll
    for (int si = 0; si < KF; ++si){
      int s = wid + 4*si;
      int kf = s >> 2, pl = (s >> 1) & 1, h = s & 1;
      GLDS16(As + s*1024,
             Tb + Bb + kf*KS + pl*PS + h*HS + (size_t)(c0 + t0)*16);
    }
    if (wid == 0) GLDS4(Cs, (const char*)(ccb + c0 + t0));
  };

  for (int t = 0; t < NT; ++t){
    const int t0 = t*64;
    __syncthreads();
    stage(t0);
    asm volatile("s_waitcnt vmcnt(0)" ::: "memory");
    __syncthreads();

    const char* Ab = As + hi*1024 + l31*16;
    const float* cct = (const float*)Cs;
#pragma unroll
    for (int i = 0; i < 2; ++i){
      f32x16 acc = (f32x16)(0.f);
#pragma unroll
      for (int kf = 0; kf < KF; ++kf){
        bf16x8 ah = *(const bf16x8*)(Ab + kf*4096 + i*512);
        bf16x8 al = *(const bf16x8*)(Ab + kf*4096 + 2048 + i*512);
        acc = __builtin_amdgcn_mfma_f32_32x32x16_bf16(ah, qh[kf], acc, 0, 0, 0);
        acc = __builtin_amdgcn_mfma_f32_32x32x16_bf16(ah, ql[kf], acc, 0, 0, 0);
        acc = __builtin_amdgcn_mfma_f32_32x32x16_bf16(al, qh[kf], acc, 0, 0, 0);
      }
#pragma unroll
      for (int rq = 0; rq < 4; ++rq){
        float4 c4 = *(const float4*)(cct + i*32 + 4*hi + 8*rq);
        int rowb = c0 + t0 + i*32 + 4*hi + 8*rq;
        float v0 = fmaf(-2.f, acc[rq*4+0], c4.x);
        float v1 = fmaf(-2.f, acc[rq*4+1], c4.y);
        float v2 = fmaf(-2.f, acc[rq*4+2], c4.z);
        float v3 = fmaf(-2.f, acc[rq*4+3], c4.w);
        if (fminf(fminf(v0, v1), fminf(v2, v3)) < kapf){
          if (v0 < kapf) ins16b(dk, di, fmap(v0), (unsigned)(rowb+0));
          if (v1 < kapf) ins16b(dk, di, fmap(v1), (unsigned)(rowb+1));
          if (v2 < kapf) ins16b(dk, di, fmap(v2), (unsigned)(rowb+2));
          if (v3 < kapf) ins16b(dk, di, fmap(v3), (unsigned)(rowb+3));
          unsigned kk = dk[15];
          kapf = (kk >= 0xFF800000u) ? __builtin_inff() : funmap(kk);
        }
      }
    }
  }
  ull* op = qkeys + (((size_t)((size_t)b*N_ + q)*S + sp)*2 + hi)*16;
#pragma unroll
  for (int t = 0; t < 16; ++t) op[t] = ((ull)dk[t] << 32) | di[t];
}

// ---------- final exact top-16: bitonic tree-merge of S*2 sorted regions ----------
template<int S>
__global__ void k_sel(const ull* __restrict__ qkeys, int* __restrict__ idxout){
  int i = blockIdx.x*256 + threadIdx.x;
  if (i >= B_*N_) return;
  const ull* kp = qkeys + (size_t)i*(S*32);
  ull a[16], t[16];
#pragma unroll
  for (int u = 0; u < 16; ++u) a[u] = kp[u];
#pragma unroll
  for (int r = 1; r < S*2; ++r){
#pragma unroll
    for (int u = 0; u < 16; ++u) t[u] = kp[r*16 + u];
    bmerge16(a, t);
  }
  int* op = idxout + (size_t)i*16;
#pragma unroll
  for (int u = 0; u < 16; ++u) op[u] = (int)(a[u] & 0xffffffffu);
}

// ---------- maxpool(x) + conv 64->64 relu + conv 64->128 ----------
__global__ __launch_bounds__(256) void k_gpool_mlp(const float* __restrict__ x,
    const int* __restrict__ idx,
    const float* __restrict__ g1a, const float* __restrict__ g1ab,
    const float* __restrict__ g1b, const float* __restrict__ g1bb,
    float* __restrict__ gout){
  __shared__ __align__(16) float Wt1[64*64];
  __shared__ __align__(16) float Wt2[64*128];
  __shared__ float Ba[64], Bb[128];
  __shared__ __align__(16) float m[64][64];
  __shared__ __align__(16) float r[64][64];
  int b = blockIdx.y; int n0 = blockIdx.x*64; int tid = threadIdx.x;
  for (int i = tid; i < 64*64; i += 256){ int o = i%64, ci = i/64; Wt1[i] = g1a[o*64+ci]; }
  for (int i = tid; i < 64*128; i += 256){ int o = i%128, ci = i/128; Wt2[i] = g1b[o*64+ci]; }
  if (tid < 64) Ba[tid] = g1ab[tid];
  if (tid < 128) Bb[tid] = g1bb[tid];
  { int p = tid/4, cg = tid%4; int n = n0 + p;
    const int* ip = idx + ((size_t)b*N_ + n)*16;
    float mm[16];
#pragma unroll
    for (int u = 0; u < 16; ++u) mm[u] = -1e30f;
    for (int k = 0; k < 16; ++k){
      int nb = ip[k];
      const float4* src = (const float4*)(x + ((size_t)b*N_ + nb)*64 + cg*16);
#pragma unroll
      for (int u = 0; u < 4; ++u){
        float4 v = src[u];
        mm[4*u  ] = fmaxf(mm[4*u  ], v.x); mm[4*u+1] = fmaxf(mm[4*u+1], v.y);
        mm[4*u+2] = fmaxf(mm[4*u+2], v.z); mm[4*u+3] = fmaxf(mm[4*u+3], v.w);
      }
    }
#pragma unroll
    for (int u = 0; u < 16; ++u) m[p][cg*16+u] = mm[u];
  }
  __syncthreads();
  { int o = tid%64, pg = tid/64;
    float acc[16];
#pragma unroll
    for (int u = 0; u < 16; ++u) acc[u] = Ba[o];
    for (int ci = 0; ci < 64; ci += 4){
      float w0 = Wt1[ci*64+o], w1_ = Wt1[(ci+1)*64+o], w2_ = Wt1[(ci+2)*64+o], w3_ = Wt1[(ci+3)*64+o];
#pragma unroll
      for (int u = 0; u < 16; ++u){
        float4 mv = *(const float4*)&m[pg*16+u][ci];
        acc[u] = fmaf(w0, mv.x, acc[u]); acc[u] = fmaf(w1_, mv.y, acc[u]);
        acc[u] = fmaf(w2_, mv.z, acc[u]); acc[u] = fmaf(w3_, mv.w, acc[u]);
      }
    }
#pragma unroll
    for (int u = 0; u < 16; ++u) r[pg*16+u][o] = fmaxf(acc[u], 0.f);
  }
  __syncthreads();
  { int o = tid%128, pg = tid/128;   // no relu on this conv
    float acc[32];
#pragma unroll
    for (int u = 0; u < 32; ++u) acc[u] = Bb[o];
    for (int ci = 0; ci < 64; ci += 4){
      float w0 = Wt2[ci*128+o], w1_ = Wt2[(ci+1)*128+o], w2_ = Wt2[(ci+2)*128+o], w3_ = Wt2[(ci+3)*128+o];
#pragma unroll
      for (int u = 0; u < 32; ++u){
        float4 rv = *(const float4*)&r[pg*32+u][ci];
        acc[u] = fmaf(w0, rv.x, acc[u]); acc[u] = fmaf(w1_, rv.y, acc[u]);
        acc[u] = fmaf(w2_, rv.z, acc[u]); acc[u] = fmaf(w3_, rv.w, acc[u]);
      }
    }
#pragma unroll
    for (int u = 0; u < 32; ++u)
      gout[((size_t)b*N_ + n0 + pg*32 + u)*128 + o] = acc[u];
  }
}

// ---------- maxpool(g) + conv 128->128 relu + conv 128->1024 + global max ----------
__global__ __launch_bounds__(256) void k_hpool_max(const float* __restrict__ g,
    const int* __restrict__ idx,
    const float* __restrict__ g2a, const float* __restrict__ g2ab,
    const float* __restrict__ g2b, const float* __restrict__ g2bb,
    unsigned int* __restrict__ glob){
  __shared__ __align__(16) float m[32][128];
  __shared__ __align__(16) float t[32][128];
  int b = blockIdx.y; int n0 = blockIdx.x*32; int tid = threadIdx.x;
  { int p = tid/8, cg = tid%8; int n = n0+p;
    const int* ip = idx + ((size_t)b*N_+n)*16;
    float mm[16];
#pragma unroll
    for (int u = 0; u < 16; ++u) mm[u] = -1e30f;
    for (int k = 0; k < 16; ++k){
      int nb = ip[k];
      const float4* src = (const float4*)(g + ((size_t)b*N_+nb)*128 + cg*16);
#pragma unroll
      for (int u = 0; u < 4; ++u){
        float4 v = src[u];
        mm[4*u  ] = fmaxf(mm[4*u  ], v.x); mm[4*u+1] = fmaxf(mm[4*u+1], v.y);
        mm[4*u+2] = fmaxf(mm[4*u+2], v.z); mm[4*u+3] = fmaxf(mm[4*u+3], v.w);
      }
    }
#pragma unroll
    for (int u = 0; u < 16; ++u) m[p][cg*16+u] = mm[u];
  }
  __syncthreads();
  { int o = tid%128, pg = tid/128;
    float acc[16];
#pragma unroll
    for (int u = 0; u < 16; ++u) acc[u] = g2ab[o];
    const float4* wrow = (const float4*)(g2a + (size_t)o*128);
    for (int c4 = 0; c4 < 32; ++c4){
      float4 wv = wrow[c4];
#pragma unroll
      for (int u = 0; u < 16; ++u){
        float4 mv = *(const float4*)&m[pg*16+u][c4*4];
        acc[u] = fmaf(wv.x,mv.x,acc[u]); acc[u] = fmaf(wv.y,mv.y,acc[u]);
        acc[u] = fmaf(wv.z,mv.z,acc[u]); acc[u] = fmaf(wv.w,mv.w,acc[u]);
      }
    }
#pragma unroll
    for (int u = 0; u < 16; ++u) t[pg*16+u][o] = fmaxf(acc[u], 0.f);
  }
  __syncthreads();
  for (int oc = 0; oc < 4; ++oc){
    int o = oc*256 + tid;
    const float4* wrow = (const float4*)(g2b + (size_t)o*128);
    float acc[32];
#pragma unroll
    for (int u = 0; u < 32; ++u) acc[u] = 0.f;
    for (int c4 = 0; c4 < 32; ++c4){
      float4 wv = wrow[c4];
#pragma unroll
      for (int u = 0; u < 32; ++u){
        float4 tv = *(const float4*)&t[u][c4*4];
        acc[u] = fmaf(wv.x,tv.x,acc[u]); acc[u] = fmaf(wv.y,tv.y,acc[u]);
        acc[u] = fmaf(wv.z,tv.z,acc[u]); acc[u] = fmaf(wv.w,tv.w,acc[u]);
      }
    }
    float bias = g2bb[o];
    float mx = -1e30f;
#pragma unroll
    for (int u = 0; u < 32; ++u) mx = fmaxf(mx, acc[u] + bias);
    atomicMax(&glob[b*1024 + o], fmap(mx));
  }
}

// ---------- code MLP + decoder base precompute ----------
__global__ __launch_bounds__(512) void k_code(const unsigned int* __restrict__ glob,
    const float* __restrict__ m1, const float* __restrict__ m1b,
    const float* __restrict__ m2, const float* __restrict__ m2b,
    const float* __restrict__ f1a, const float* __restrict__ f1ab,
    const float* __restrict__ f2a, const float* __restrict__ f2ab,
    float* __restrict__ base1, float* __restrict__ base2){
  __shared__ __align__(16) float gl_s[1024];
  __shared__ __align__(16) float hid_s[512];
  __shared__ __align__(16) float code_s[512];
  int b = blockIdx.x; int tid = threadIdx.x;
  for (int i = tid; i < 1024; i += 512) gl_s[i] = funmap(glob[b*1024+i]);
  __syncthreads();
  { float acc = m1b[tid];
    const float4* wr = (const float4*)(m1 + (size_t)tid*1024);
    for (int c4 = 0; c4 < 256; ++c4){ float4 wv = wr[c4]; float4 gv = *(const float4*)&gl_s[c4*4];
      acc = fmaf(wv.x,gv.x,acc); acc = fmaf(wv.y,gv.y,acc);
      acc = fmaf(wv.z,gv.z,acc); acc = fmaf(wv.w,gv.w,acc); }
    hid_s[tid] = fmaxf(acc, 0.f);
  }
  __syncthreads();
  { float acc = m2b[tid];
    const float4* wr = (const float4*)(m2 + (size_t)tid*512);
    for (int c4 = 0; c4 < 128; ++c4){ float4 wv = wr[c4]; float4 hv = *(const float4*)&hid_s[c4*4];
      acc = fmaf(wv.x,hv.x,acc); acc = fmaf(wv.y,hv.y,acc);
      acc = fmaf(wv.z,hv.z,acc); acc = fmaf(wv.w,hv.w,acc); }
    code_s[tid] = acc;
  }
  __syncthreads();
  { float acc = f1ab[tid];
    const float* wr = f1a + (size_t)tid*514;
    for (int c = 0; c < 512; ++c) acc = fmaf(wr[c], code_s[c], acc);
    base1[b*512 + tid] = acc;
  }
  { float acc = f2ab[tid];
    const float* wr = f2a + (size_t)tid*515;
    for (int c = 0; c < 512; ++c) acc = fmaf(wr[c], code_s[c], acc);
    base2[b*512 + tid] = acc;
  }
}

// ---------- folding decoder (16-point tiles -> 2 blocks/CU) ----------
template<int NIN>
__global__ __launch_bounds__(256) void k_fold(const float* __restrict__ base,
    const float* __restrict__ fa,
    const float* __restrict__ fb, const float* __restrict__ fbb,
    const float* __restrict__ fc, const float* __restrict__ fcb,
    const float* __restrict__ pin, float* __restrict__ pout){
  __shared__ __align__(16) float y1[16][512];
  __shared__ __align__(16) float y2[16][516];
  __shared__ float pcoord[16][NIN];
  int b = blockIdx.y; int m0 = blockIdx.x*16; int tid = threadIdx.x;
  if (tid < 16*NIN){
    int p = tid / NIN, c = tid % NIN;
    int mm = min(m0 + p, M_-1);
    float v;
    if (NIN == 2){
      const float step = 0.6f/44.f;
      int ii = (c == 0) ? (mm/GRID_) : (mm%GRID_);
      v = -0.3f + step*ii;
    } else {
      v = pin[((size_t)b*M_ + mm)*3 + c];
    }
    pcoord[p][c] = v;
  }
  __syncthreads();
  const int stride_a = 512 + NIN;
  for (int rep = 0; rep < 2; ++rep){
    int o = rep*256 + tid;
    float av[NIN];
#pragma unroll
    for (int c = 0; c < NIN; ++c) av[c] = fa[(size_t)o*stride_a + 512 + c];
    float bv = base[b*512 + o];
#pragma unroll
    for (int p = 0; p < 16; ++p){
      float acc = bv;
#pragma unroll
      for (int c = 0; c < NIN; ++c) acc = fmaf(av[c], pcoord[p][c], acc);
      y1[p][o] = fmaxf(acc, 0.f);
    }
  }
  __syncthreads();
  for (int rep = 0; rep < 2; ++rep){
    int o2 = rep*256 + tid;
    const float* wr = fb + (size_t)o2*512;
    float acc[16];
#pragma unroll
    for (int u = 0; u < 16; ++u) acc[u] = 0.f;
    for (int c4 = 0; c4 < 128; ++c4){
      float4 wv = *(const float4*)&wr[c4*4];
#pragma unroll
      for (int u = 0; u < 16; ++u){
        float4 yv = *(const float4*)&y1[u][c4*4];
        acc[u] = fmaf(wv.x,yv.x,acc[u]); acc[u] = fmaf(wv.y,yv.y,acc[u]);
        acc[u] = fmaf(wv.z,yv.z,acc[u]); acc[u] = fmaf(wv.w,yv.w,acc[u]);
      }
    }
    float bias = fbb[o2];
#pragma unroll
    for (int u = 0; u < 16; ++u) y2[u][o2] = fmaxf(acc[u] + bias, 0.f);
  }
  __syncthreads();
  if (tid < 48){
    int p = tid / 3, c = tid % 3;
    const float* wr = fc + (size_t)c*512;
    float acc = fcb[c];
    for (int o4 = 0; o4 < 128; ++o4){
      float4 wv = *(const float4*)&wr[o4*4];
      float4 yv = *(const float4*)&y2[p][o4*4];
      acc = fmaf(wv.x,yv.x,acc); acc = fmaf(wv.y,yv.y,acc);
      acc = fmaf(wv.z,yv.z,acc); acc = fmaf(wv.w,yv.w,acc);
    }
    int mm = m0 + p;
    if (mm < M_) pout[((size_t)b*M_ + mm)*3 + c] = acc;
  }
}

// ---------- launcher ----------
extern "C" void kernel_launch(void* const* d_in, const int* in_sizes, int n_in,
                              void* d_out, int out_size, void* d_ws, size_t ws_size,
                              hipStream_t stream){
  const float* pts  = (const float*)d_in[0];
  const float* w1   = (const float*)d_in[1];  const float* b1   = (const float*)d_in[2];
  const float* w2   = (const float*)d_in[3];  const float* b2   = (const float*)d_in[4];
  const float* w3   = (const float*)d_in[5];  const float* b3   = (const float*)d_in[6];
  const float* g1a  = (const float*)d_in[7];  const float* g1ab = (const float*)d_in[8];
  const float* g1b  = (const float*)d_in[9];  const float* g1bb = (const float*)d_in[10];
  const float* g2a  = (const float*)d_in[11]; const float* g2ab = (const float*)d_in[12];
  const float* g2b  = (const float*)d_in[13]; const float* g2bb = (const float*)d_in[14];
  const float* m1   = (const float*)d_in[15]; const float* m1b  = (const float*)d_in[16];
  const float* m2   = (const float*)d_in[17]; const float* m2b  = (const float*)d_in[18];
  const float* f1a  = (const float*)d_in[19]; const float* f1ab = (const float*)d_in[20];
  const float* f1b  = (const float*)d_in[21]; const float* f1bb = (const float*)d_in[22];
  const float* f1c  = (const float*)d_in[23]; const float* f1cb = (const float*)d_in[24];
  const float* f2a  = (const float*)d_in[25]; const float* f2ab = (const float*)d_in[26];
  const float* f2b  = (const float*)d_in[27]; const float* f2bb = (const float*)d_in[28];
  const float* f2c  = (const float*)d_in[29]; const float* f2cb = (const float*)d_in[30];
  float* out = (float*)d_out;

  char* w = (char*)d_ws;
  auto alloc = [&](size_t bytes){ char* p = w; w += (bytes + 255) & ~(size_t)255; return p; };
  unsigned long long* nn64 = (unsigned long long*)alloc((size_t)B_*N_*8);
  float* x    = (float*)alloc((size_t)B_*N_*64*4);
  float* g    = (float*)alloc((size_t)B_*N_*128*4);
  unsigned short* T64  = (unsigned short*)alloc((size_t)B_*4*4*N_*16);   //  8MB
  unsigned short* T128 = (unsigned short*)alloc((size_t)B_*8*4*N_*16);   // 16MB
  float* ccf  = (float*)alloc((size_t)B_*N_*4);
  int*   idx  = (int*)alloc((size_t)B_*N_*16*4);
  ull*   qkeys = (ull*)alloc((size_t)B_*N_*4*2*16*8);                    // 32MB
  unsigned int* glob = (unsigned int*)alloc((size_t)B_*1024*4);
  float* base1 = (float*)alloc((size_t)B_*512*4);
  float* base2 = (float*)alloc((size_t)B_*512*4);
  float* mid   = (float*)alloc((size_t)B_*M_*3*4);
  (void)ws_size; (void)in_sizes; (void)n_in; (void)out_size;

  const int SMEM4 = 4*4096 + 256;    // 16,640 B
  const int SMEM8 = 8*4096 + 256;    // 33,024 B
  hipFuncSetAttribute((const void*)k_knnF<4,2,2>, hipFuncAttributeMaxDynamicSharedMemorySize, SMEM4);
  hipFuncSetAttribute((const void*)k_knnF<8,2,2>, hipFuncAttributeMaxDynamicSharedMemorySize, SMEM8);

  hipMemsetAsync(nn64, 0xFF, (size_t)B_*N_*8, stream);
  k_init<<<dim3((B_*1024+255)/256), 256, 0, stream>>>(glob);
  k_nn1<<<dim3(N_/256, 4, B_), 256, 0, stream>>>(pts, nn64);
  k_cov_mlp<<<dim3(N_/64, B_), 256, 0, stream>>>(pts, nn64, w1,b1,w2,b2,w3,b3, x, T64, ccf);

  k_knnF<4,2,2><<<dim3(N_/128, 2, B_), 256, SMEM4, stream>>>(T64, ccf, qkeys);
  k_sel<2><<<dim3(B_*N_/256), 256, 0, stream>>>(qkeys, idx);

  k_gpool_mlp<<<dim3(N_/64, B_), 256, 0, stream>>>(x, idx, g1a,g1ab,g1b,g1bb, g);

  k_prep4<8><<<dim3(N_/256, B_), 256, 0, stream>>>(g, T128, ccf);
  k_knnF<8,2,2><<<dim3(N_/128, 2, B_), 256, SMEM8, stream>>>(T128, ccf, qkeys);
  k_sel<2><<<dim3(B_*N_/256), 256, 0, stream>>>(qkeys, idx);

  k_hpool_max<<<dim3(N_/32, B_), 256, 0, stream>>>(g, idx, g2a,g2ab,g2b,g2bb, glob);
  k_code<<<dim3(B_), 512, 0, stream>>>(glob, m1,m1b,m2,m2b, f1a,f1ab, f2a,f2ab, base1, base2);
  k_fold<2><<<dim3((M_+15)/16, B_), 256, 0, stream>>>(base1, f1a, f1b, f1bb, f1c, f1cb, nullptr, mid);
  k_fold<3><<<dim3((M_+15)/16, B_), 256, 0, stream>>>(base2, f2a, f2b, f2bb, f2c, f2cb, mid, out);
}

// Round 16
// 1567.330 us; speedup vs baseline: 1.1943x; 1.0362x over previous
//
#include <hip/hip_runtime.h>
#include <stdint.h>

#define B_ 4
#define N_ 8192
#define K_ 16
#define FEAT_ 512
#define GRID_ 45
#define M_ (GRID_*GRID_)

typedef unsigned long long ull;
typedef __bf16 bf16x8 __attribute__((ext_vector_type(8)));
typedef float f32x16 __attribute__((ext_vector_type(16)));

// ---------- helpers ----------

__device__ __forceinline__ unsigned int fmap(float f){
  unsigned int u = __float_as_uint(f);
  return (u & 0x80000000u) ? ~u : (u | 0x80000000u);
}
__device__ __forceinline__ float funmap(unsigned int u){
  return (u & 0x80000000u) ? __uint_as_float(u ^ 0x80000000u) : __uint_as_float(~u);
}

// stable u32-key/u32-idx sorted insert, strict < : ascending-idx scan order
// reproduces (dist, idx) lex semantics exactly.
__device__ __forceinline__ void ins16b(unsigned (&dk)[16], unsigned (&di)[16],
                                       unsigned k, unsigned id){
  if (k < dk[15]){
    bool c[16];
#pragma unroll
    for (int s = 0; s < 16; ++s) c[s] = k < dk[s];
#pragma unroll
    for (int s = 15; s >= 1; --s){
      dk[s] = c[s-1] ? dk[s-1] : (c[s] ? k  : dk[s]);
      di[s] = c[s-1] ? di[s-1] : (c[s] ? id : di[s]);
    }
    if (c[0]){ dk[0] = k; di[0] = id; }
  }
}

// bitonic cleanup sort of a 16-element bitonic sequence (ascending)
__device__ __forceinline__ void bsort16(ull (&c)[16]){
#pragma unroll
  for (int d = 8; d >= 1; d >>= 1){
#pragma unroll
    for (int i = 0; i < 16; ++i){
      if (!(i & d)){
        ull x = c[i], y = c[i|d];
        bool lt = x < y;
        c[i]   = lt ? x : y;
        c[i|d] = lt ? y : x;
      }
    }
  }
}
// merge two sorted-ascending 16-lists -> sorted-ascending lowest 16 of union
__device__ __forceinline__ void bmerge16(ull (&a)[16], const ull (&b)[16]){
#pragma unroll
  for (int i = 0; i < 16; ++i){
    ull bv = b[15-i];
    a[i] = a[i] < bv ? a[i] : bv;
  }
  bsort16(a);
}

__device__ __forceinline__ void bsplit(float x, unsigned short& h, unsigned short& l){
  __bf16 hh = (__bf16)x;
  __bf16 ll = (__bf16)(x - (float)hh);
  h = __builtin_bit_cast(unsigned short, hh);
  l = __builtin_bit_cast(unsigned short, ll);
}

#define GLDS16(l, g) __builtin_amdgcn_global_load_lds((const __attribute__((address_space(1))) void*)(g), (__attribute__((address_space(3))) void*)(l), 16, 0, 0)
#define GLDS4(l, g)  __builtin_amdgcn_global_load_lds((const __attribute__((address_space(1))) void*)(g), (__attribute__((address_space(3))) void*)(l), 4, 0, 0)

#define KEY_INF 0xFF800000FFFFFFFFull

// ---------- init ----------
__global__ void k_init(unsigned int* glob){
  int i = blockIdx.x*256 + threadIdx.x;
  if (i < B_*1024) glob[i] = 0x007FFFFFu;   // fmap(-inf)
}

// ---------- KNN #1: nearest other point (exact fp32, float4 LDS) ----------
__global__ __launch_bounds__(256) void k_nn1(const float* __restrict__ pts,
                                             unsigned long long* __restrict__ nn64){
  __shared__ __align__(16) float sp4[2048][4];
  int b = blockIdx.z, s = blockIdx.y;
  int c0 = s*2048;
  const float* P = pts + (size_t)b*N_*3;
  for (int p = threadIdx.x; p < 2048; p += 256){
    const float* src = P + (size_t)(c0 + p)*3;
    sp4[p][0] = src[0]; sp4[p][1] = src[1]; sp4[p][2] = src[2]; sp4[p][3] = 0.f;
  }
  __syncthreads();
  int n = blockIdx.x*256 + threadIdx.x;
  float qx = P[n*3], qy = P[n*3+1], qz = P[n*3+2];
  float best = 1e30f; int bi = 0;
  for (int j = 0; j < 2048; ++j){
    float4 sv = *(const float4*)sp4[j];
    float dx = qx - sv.x, dy = qy - sv.y, dz = qz - sv.z;
    float d2 = fmaf(dx,dx, fmaf(dy,dy, dz*dz));
    int cj = c0 + j;
    if (d2 < best && cj != n){ best = d2; bi = cj; }
  }
  unsigned long long key = ((unsigned long long)__float_as_uint(best) << 32) | (unsigned int)bi;
  atomicMin(&nn64[(size_t)b*N_ + n], key);
}

// ---------- local_cov + 3 convs + fused T64/cc emit ----------
__global__ __launch_bounds__(256) void k_cov_mlp(const float* __restrict__ pts,
    const unsigned long long* __restrict__ nn64,
    const float* __restrict__ w1, const float* __restrict__ b1,
    const float* __restrict__ w2, const float* __restrict__ b2,
    const float* __restrict__ w3, const float* __restrict__ b3,
    float* __restrict__ xout, unsigned short* __restrict__ T,
    float* __restrict__ cc){
  __shared__ __align__(16) float W1t[12*64];
  __shared__ __align__(16) float W2t[64*64];
  __shared__ __align__(16) float W3t[64*64];
  __shared__ float B1[64], B2[64], B3[64];
  __shared__ __align__(16) float x0[64][12];
  __shared__ __align__(16) float h1[64][64];
  __shared__ __align__(16) float h2[64][64];
  int b = blockIdx.y; int n0 = blockIdx.x*64; int tid = threadIdx.x;
  for (int i = tid; i < 12*64; i += 256){ int o = i % 64, ci = i / 64; W1t[i] = w1[o*12 + ci]; }
  for (int i = tid; i < 64*64; i += 256){ int o = i % 64, ci = i / 64; W2t[i] = w2[o*64 + ci]; W3t[i] = w3[o*64 + ci]; }
  if (tid < 64){ B1[tid]=b1[tid]; B2[tid]=b2[tid]; B3[tid]=b3[tid]; }
  {
    int p = tid % 64, cg = tid / 64;
    int n = n0 + p;
    const float* P = pts + ((size_t)b*N_ + n)*3;
    int nb = (int)(nn64[(size_t)b*N_ + n] & 0xFFFFFFFFull);
    const float* Q = pts + ((size_t)b*N_ + nb)*3;
    if (cg == 0){ x0[p][0]=P[0]; x0[p][1]=P[1]; x0[p][2]=P[2]; }
    else { int i = cg-1; float pi = P[i];
      x0[p][3+i*3+0]=pi*Q[0]; x0[p][3+i*3+1]=pi*Q[1]; x0[p][3+i*3+2]=pi*Q[2]; }
  }
  __syncthreads();
  { int o = tid % 64, pg = tid / 64;
    for (int p = pg; p < 64; p += 4){
      float acc = B1[o];
#pragma unroll
      for (int ci = 0; ci < 12; ++ci) acc = fmaf(W1t[ci*64+o], x0[p][ci], acc);
      h1[p][o] = fmaxf(acc, 0.f);
    } }
  __syncthreads();
  { int o = tid % 64, pg = tid / 64;
    for (int p = pg; p < 64; p += 4){
      float acc = B2[o];
#pragma unroll
      for (int ci = 0; ci < 64; ++ci) acc = fmaf(W2t[ci*64+o], h1[p][ci], acc);
      h2[p][o] = fmaxf(acc, 0.f);
    } }
  __syncthreads();
  { int o = tid % 64, pg = tid / 64;
    for (int p = pg; p < 64; p += 4){
      float acc = B3[o];
#pragma unroll
      for (int ci = 0; ci < 64; ++ci) acc = fmaf(W3t[ci*64+o], h2[p][ci], acc);
      float r = fmaxf(acc, 0.f);
      xout[((size_t)b*N_ + n0 + p)*64 + o] = r;
      h1[p][o] = r;                       // h1 free after phase 2: reuse for x3
    } }
  __syncthreads();
  // fused prep<4>: granule emit (8 bf16 ch per 16B) + per-row norms
  {
    char* Tb = (char*)T;
    const size_t HS = (size_t)N_*16, PS = 2*HS, KS = 4*HS;
    const size_t Bb = (size_t)b*4*KS;
    for (int e = tid; e < 64*8; e += 256){
      int p = e >> 3, gg = e & 7;
      int kf = gg >> 1, h = gg & 1;
      unsigned short hs[8], ls[8];
#pragma unroll
      for (int j = 0; j < 8; ++j) bsplit(h1[p][gg*8+j], hs[j], ls[j]);
      size_t base = Bb + (size_t)kf*KS + (size_t)h*HS + (size_t)(n0+p)*16;
      *(uint4*)(Tb + base)      = *(uint4*)hs;
      *(uint4*)(Tb + base + PS) = *(uint4*)ls;
    }
    if (tid < 64){
      float ss = 0.f;
#pragma unroll 8
      for (int c = 0; c < 64; ++c){ float v = h1[tid][(c + tid) & 63]; ss = fmaf(v, v, ss); }
      cc[(size_t)b*N_ + n0 + tid] = ss;
    }
  }
}

// ---------- prep: bf16 hi/lo split into K-major granule layout + norms ----------
template<int KF>
__global__ __launch_bounds__(256) void k_prep4(const float* __restrict__ f,
    unsigned short* __restrict__ T, float* __restrict__ cc){
  int b = blockIdx.y; int n = blockIdx.x*256 + threadIdx.x;
  const float* src = f + ((size_t)b*N_ + n)*(KF*16);
  char* Tb = (char*)T;
  float ss = 0.f;
#pragma unroll
  for (int kf = 0; kf < KF; ++kf){
    float v[16];
#pragma unroll
    for (int c4 = 0; c4 < 4; ++c4){
      float4 t4 = *(const float4*)&src[kf*16 + c4*4];
      v[c4*4]=t4.x; v[c4*4+1]=t4.y; v[c4*4+2]=t4.z; v[c4*4+3]=t4.w;
    }
    unsigned short hs[16], ls[16];
#pragma unroll
    for (int c = 0; c < 16; ++c){
      float x = v[c];
      ss = fmaf(x, x, ss);
      bsplit(x, hs[c], ls[c]);
    }
    size_t base = ((((size_t)b*KF + kf)*2)*2)*(size_t)(N_*16) + (size_t)n*16;
    const size_t HS = (size_t)N_*16;
    const size_t PS = 2*HS;
    *(uint4*)(Tb + base)            = *(uint4*)&hs[0];
    *(uint4*)(Tb + base + HS)       = *(uint4*)&hs[8];
    *(uint4*)(Tb + base + PS)       = *(uint4*)&ls[0];
    *(uint4*)(Tb + base + PS + HS)  = *(uint4*)&ls[8];
  }
  cc[(size_t)b*N_ + n] = ss;
}

// ---------- fused single-pass KNN: MFMA + gated stable u32 top-16 ----------
template<int KF, int MW, int S>
__global__ __launch_bounds__(256, MW) void k_knnF(const unsigned short* __restrict__ T,
    const float* __restrict__ ccg, ull* __restrict__ qkeys){
  extern __shared__ char smem[];
  constexpr int NT = (N_/S)/64;
  char* As = smem;                    // KF*4096
  char* Cs = smem + KF*4096;          // 256

  const int tid = threadIdx.x, lane = tid & 63, wid = tid >> 6;
  const int hi = lane >> 5, l31 = lane & 31;
  const int b = blockIdx.z, sp = blockIdx.y, q0 = blockIdx.x*128;
  const int c0 = sp*(N_/S);
  const char* Tb = (const char*)T;
  const size_t HS = (size_t)N_*16, PS = 2*HS, KS = 4*HS;
  const size_t Bb = (size_t)b*KF*KS;
  const float* ccb = ccg + (size_t)b*N_;

  const int q = q0 + wid*32 + l31;
  bf16x8 qh[KF], ql[KF];
#pragma unroll
  for (int kf = 0; kf < KF; ++kf){
    size_t o = Bb + kf*KS + hi*HS + (size_t)q*16;
    qh[kf] = *(const bf16x8*)(Tb + o);
    ql[kf] = *(const bf16x8*)(Tb + o + PS);
  }

  unsigned dk[16], di[16];
#pragma unroll
  for (int t = 0; t < 16; ++t){ dk[t] = 0xFFFFFFFFu; di[t] = 0xFFFFFFFFu; }
  float kapf = __builtin_inff();

  auto stage = [&](int t0){
#pragma unroll
    for (int si = 0; si < KF; ++si){
      int s = wid + 4*si;
      int kf = s >> 2, pl = (s >> 1) & 1, h = s & 1;
      GLDS16(As + s*1024,
             Tb + Bb + kf*KS + pl*PS + h*HS + (size_t)(c0 + t0)*16);
    }
    if (wid == 0) GLDS4(Cs, (const char*)(ccb + c0 + t0));
  };

  for (int t = 0; t < NT; ++t){
    const int t0 = t*64;
    __syncthreads();
    stage(t0);
    asm volatile("s_waitcnt vmcnt(0)" ::: "memory");
    __syncthreads();

    const char* Ab = As + hi*1024 + l31*16;
    const float* cct = (const float*)Cs;
#pragma unroll
    for (int i = 0; i < 2; ++i){
      f32x16 acc = (f32x16)(0.f);
#pragma unroll
      for (int kf = 0; kf < KF; ++kf){
        bf16x8 ah = *(const bf16x8*)(Ab + kf*4096 + i*512);
        bf16x8 al = *(const bf16x8*)(Ab + kf*4096 + 2048 + i*512);
        acc = __builtin_amdgcn_mfma_f32_32x32x16_bf16(ah, qh[kf], acc, 0, 0, 0);
        acc = __builtin_amdgcn_mfma_f32_32x32x16_bf16(ah, ql[kf], acc, 0, 0, 0);
        acc = __builtin_amdgcn_mfma_f32_32x32x16_bf16(al, qh[kf], acc, 0, 0, 0);
      }
#pragma unroll
      for (int rq = 0; rq < 4; ++rq){
        float4 c4 = *(const float4*)(cct + i*32 + 4*hi + 8*rq);
        int rowb = c0 + t0 + i*32 + 4*hi + 8*rq;
        float v0 = fmaf(-2.f, acc[rq*4+0], c4.x);
        float v1 = fmaf(-2.f, acc[rq*4+1], c4.y);
        float v2 = fmaf(-2.f, acc[rq*4+2], c4.z);
        float v3 = fmaf(-2.f, acc[rq*4+3], c4.w);
        if (fminf(fminf(v0, v1), fminf(v2, v3)) < kapf){
          if (v0 < kapf) ins16b(dk, di, fmap(v0), (unsigned)(rowb+0));
          if (v1 < kapf) ins16b(dk, di, fmap(v1), (unsigned)(rowb+1));
          if (v2 < kapf) ins16b(dk, di, fmap(v2), (unsigned)(rowb+2));
          if (v3 < kapf) ins16b(dk, di, fmap(v3), (unsigned)(rowb+3));
          unsigned kk = dk[15];
          kapf = (kk >= 0xFF800000u) ? __builtin_inff() : funmap(kk);
        }
      }
    }
  }
  ull* op = qkeys + (((size_t)((size_t)b*N_ + q)*S + sp)*2 + hi)*16;
#pragma unroll
  for (int t = 0; t < 16; ++t) op[t] = ((ull)dk[t] << 32) | di[t];
}

// ---------- final exact top-16: bitonic tree-merge of S*2 sorted regions ----------
template<int S>
__global__ void k_sel(const ull* __restrict__ qkeys, int* __restrict__ idxout){
  int i = blockIdx.x*256 + threadIdx.x;
  if (i >= B_*N_) return;
  const ull* kp = qkeys + (size_t)i*(S*32);
  ull a[16], t[16];
#pragma unroll
  for (int u = 0; u < 16; ++u) a[u] = kp[u];
#pragma unroll
  for (int r = 1; r < S*2; ++r){
#pragma unroll
    for (int u = 0; u < 16; ++u) t[u] = kp[r*16 + u];
    bmerge16(a, t);
  }
  int* op = idxout + (size_t)i*16;
#pragma unroll
  for (int u = 0; u < 16; ++u) op[u] = (int)(a[u] & 0xffffffffu);
}

// ---------- maxpool(x) + conv 64->64 relu + conv 64->128 ----------
__global__ __launch_bounds__(256) void k_gpool_mlp(const float* __restrict__ x,
    const int* __restrict__ idx,
    const float* __restrict__ g1a, const float* __restrict__ g1ab,
    const float* __restrict__ g1b, const float* __restrict__ g1bb,
    float* __restrict__ gout){
  __shared__ __align__(16) float Wt1[64*64];
  __shared__ __align__(16) float Wt2[64*128];
  __shared__ float Ba[64], Bb[128];
  __shared__ __align__(16) float m[64][64];
  __shared__ __align__(16) float r[64][64];
  int b = blockIdx.y; int n0 = blockIdx.x*64; int tid = threadIdx.x;
  for (int i = tid; i < 64*64; i += 256){ int o = i%64, ci = i/64; Wt1[i] = g1a[o*64+ci]; }
  for (int i = tid; i < 64*128; i += 256){ int o = i%128, ci = i/128; Wt2[i] = g1b[o*64+ci]; }
  if (tid < 64) Ba[tid] = g1ab[tid];
  if (tid < 128) Bb[tid] = g1bb[tid];
  { int p = tid/4, cg = tid%4; int n = n0 + p;
    const int* ip = idx + ((size_t)b*N_ + n)*16;
    float mm[16];
#pragma unroll
    for (int u = 0; u < 16; ++u) mm[u] = -1e30f;
    for (int k = 0; k < 16; ++k){
      int nb = ip[k];
      const float4* src = (const float4*)(x + ((size_t)b*N_ + nb)*64 + cg*16);
#pragma unroll
      for (int u = 0; u < 4; ++u){
        float4 v = src[u];
        mm[4*u  ] = fmaxf(mm[4*u  ], v.x); mm[4*u+1] = fmaxf(mm[4*u+1], v.y);
        mm[4*u+2] = fmaxf(mm[4*u+2], v.z); mm[4*u+3] = fmaxf(mm[4*u+3], v.w);
      }
    }
#pragma unroll
    for (int u = 0; u < 16; ++u) m[p][cg*16+u] = mm[u];
  }
  __syncthreads();
  { int o = tid%64, pg = tid/64;
    float acc[16];
#pragma unroll
    for (int u = 0; u < 16; ++u) acc[u] = Ba[o];
    for (int ci = 0; ci < 64; ci += 4){
      float w0 = Wt1[ci*64+o], w1_ = Wt1[(ci+1)*64+o], w2_ = Wt1[(ci+2)*64+o], w3_ = Wt1[(ci+3)*64+o];
#pragma unroll
      for (int u = 0; u < 16; ++u){
        float4 mv = *(const float4*)&m[pg*16+u][ci];
        acc[u] = fmaf(w0, mv.x, acc[u]); acc[u] = fmaf(w1_, mv.y, acc[u]);
        acc[u] = fmaf(w2_, mv.z, acc[u]); acc[u] = fmaf(w3_, mv.w, acc[u]);
      }
    }
#pragma unroll
    for (int u = 0; u < 16; ++u) r[pg*16+u][o] = fmaxf(acc[u], 0.f);
  }
  __syncthreads();
  { int o = tid%128, pg = tid/128;   // no relu on this conv
    float acc[32];
#pragma unroll
    for (int u = 0; u < 32; ++u) acc[u] = Bb[o];
    for (int ci = 0; ci < 64; ci += 4){
      float w0 = Wt2[ci*128+o], w1_ = Wt2[(ci+1)*128+o], w2_ = Wt2[(ci+2)*128+o], w3_ = Wt2[(ci+3)*128+o];
#pragma unroll
      for (int u = 0; u < 32; ++u){
        float4 rv = *(const float4*)&r[pg*32+u][ci];
        acc[u] = fmaf(w0, rv.x, acc[u]); acc[u] = fmaf(w1_, rv.y, acc[u]);
        acc[u] = fmaf(w2_, rv.z, acc[u]); acc[u] = fmaf(w3_, rv.w, acc[u]);
      }
    }
#pragma unroll
    for (int u = 0; u < 32; ++u)
      gout[((size_t)b*N_ + n0 + pg*32 + u)*128 + o] = acc[u];
  }
}

// ---------- maxpool(g) + conv 128->128 relu + conv 128->1024 + global max ----------
// phase 3 register-tiled: 2 channels/thread per pass -> LDS reads halved
__global__ __launch_bounds__(256) void k_hpool_max(const float* __restrict__ g,
    const int* __restrict__ idx,
    const float* __restrict__ g2a, const float* __restrict__ g2ab,
    const float* __restrict__ g2b, const float* __restrict__ g2bb,
    unsigned int* __restrict__ glob){
  __shared__ __align__(16) float m[32][128];
  __shared__ __align__(16) float t[32][128];
  int b = blockIdx.y; int n0 = blockIdx.x*32; int tid = threadIdx.x;
  { int p = tid/8, cg = tid%8; int n = n0+p;
    const int* ip = idx + ((size_t)b*N_+n)*16;
    float mm[16];
#pragma unroll
    for (int u = 0; u < 16; ++u) mm[u] = -1e30f;
    for (int k = 0; k < 16; ++k){
      int nb = ip[k];
      const float4* src = (const float4*)(g + ((size_t)b*N_+nb)*128 + cg*16);
#pragma unroll
      for (int u = 0; u < 4; ++u){
        float4 v = src[u];
        mm[4*u  ] = fmaxf(mm[4*u  ], v.x); mm[4*u+1] = fmaxf(mm[4*u+1], v.y);
        mm[4*u+2] = fmaxf(mm[4*u+2], v.z); mm[4*u+3] = fmaxf(mm[4*u+3], v.w);
      }
    }
#pragma unroll
    for (int u = 0; u < 16; ++u) m[p][cg*16+u] = mm[u];
  }
  __syncthreads();
  { int o = tid%128, pg = tid/128;
    float acc[16];
#pragma unroll
    for (int u = 0; u < 16; ++u) acc[u] = g2ab[o];
    const float4* wrow = (const float4*)(g2a + (size_t)o*128);
    for (int c4 = 0; c4 < 32; ++c4){
      float4 wv = wrow[c4];
#pragma unroll
      for (int u = 0; u < 16; ++u){
        float4 mv = *(const float4*)&m[pg*16+u][c4*4];
        acc[u] = fmaf(wv.x,mv.x,acc[u]); acc[u] = fmaf(wv.y,mv.y,acc[u]);
        acc[u] = fmaf(wv.z,mv.z,acc[u]); acc[u] = fmaf(wv.w,mv.w,acc[u]);
      }
    }
#pragma unroll
    for (int u = 0; u < 16; ++u) t[pg*16+u][o] = fmaxf(acc[u], 0.f);
  }
  __syncthreads();
  for (int op = 0; op < 2; ++op){
    int o0 = op*512 + tid;          // channels o0 and o0+256
    const float4* wr0 = (const float4*)(g2b + (size_t)o0*128);
    const float4* wr1 = (const float4*)(g2b + (size_t)(o0+256)*128);
    float a0[32], a1[32];
#pragma unroll
    for (int u = 0; u < 32; ++u){ a0[u] = 0.f; a1[u] = 0.f; }
    for (int c4 = 0; c4 < 32; ++c4){
      float4 w0 = wr0[c4], w1 = wr1[c4];
#pragma unroll
      for (int u = 0; u < 32; ++u){
        float4 tv = *(const float4*)&t[u][c4*4];
        a0[u] = fmaf(w0.x,tv.x,a0[u]); a0[u] = fmaf(w0.y,tv.y,a0[u]);
        a0[u] = fmaf(w0.z,tv.z,a0[u]); a0[u] = fmaf(w0.w,tv.w,a0[u]);
        a1[u] = fmaf(w1.x,tv.x,a1[u]); a1[u] = fmaf(w1.y,tv.y,a1[u]);
        a1[u] = fmaf(w1.z,tv.z,a1[u]); a1[u] = fmaf(w1.w,tv.w,a1[u]);
      }
    }
    float b0 = g2bb[o0], b1 = g2bb[o0+256];
    float mx0 = -1e30f, mx1 = -1e30f;
#pragma unroll
    for (int u = 0; u < 32; ++u){
      mx0 = fmaxf(mx0, a0[u] + b0);
      mx1 = fmaxf(mx1, a1[u] + b1);
    }
    atomicMax(&glob[b*1024 + o0],       fmap(mx0));
    atomicMax(&glob[b*1024 + o0 + 256], fmap(mx1));
  }
}

// ---------- code MLP + decoder base precompute ----------
__global__ __launch_bounds__(512) void k_code(const unsigned int* __restrict__ glob,
    const float* __restrict__ m1, const float* __restrict__ m1b,
    const float* __restrict__ m2, const float* __restrict__ m2b,
    const float* __restrict__ f1a, const float* __restrict__ f1ab,
    const float* __restrict__ f2a, const float* __restrict__ f2ab,
    float* __restrict__ base1, float* __restrict__ base2){
  __shared__ __align__(16) float gl_s[1024];
  __shared__ __align__(16) float hid_s[512];
  __shared__ __align__(16) float code_s[512];
  int b = blockIdx.x; int tid = threadIdx.x;
  for (int i = tid; i < 1024; i += 512) gl_s[i] = funmap(glob[b*1024+i]);
  __syncthreads();
  { float acc = m1b[tid];
    const float4* wr = (const float4*)(m1 + (size_t)tid*1024);
    for (int c4 = 0; c4 < 256; ++c4){ float4 wv = wr[c4]; float4 gv = *(const float4*)&gl_s[c4*4];
      acc = fmaf(wv.x,gv.x,acc); acc = fmaf(wv.y,gv.y,acc);
      acc = fmaf(wv.z,gv.z,acc); acc = fmaf(wv.w,gv.w,acc); }
    hid_s[tid] = fmaxf(acc, 0.f);
  }
  __syncthreads();
  { float acc = m2b[tid];
    const float4* wr = (const float4*)(m2 + (size_t)tid*512);
    for (int c4 = 0; c4 < 128; ++c4){ float4 wv = wr[c4]; float4 hv = *(const float4*)&hid_s[c4*4];
      acc = fmaf(wv.x,hv.x,acc); acc = fmaf(wv.y,hv.y,acc);
      acc = fmaf(wv.z,hv.z,acc); acc = fmaf(wv.w,hv.w,acc); }
    code_s[tid] = acc;
  }
  __syncthreads();
  { float acc = f1ab[tid];
    const float* wr = f1a + (size_t)tid*514;
    for (int c = 0; c < 512; ++c) acc = fmaf(wr[c], code_s[c], acc);
    base1[b*512 + tid] = acc;
  }
  { float acc = f2ab[tid];
    const float* wr = f2a + (size_t)tid*515;
    for (int c = 0; c < 512; ++c) acc = fmaf(wr[c], code_s[c], acc);
    base2[b*512 + tid] = acc;
  }
}

// ---------- folding decoder (16-pt tiles; phase-b: 2 channels/thread) ----------
template<int NIN>
__global__ __launch_bounds__(256) void k_fold(const float* __restrict__ base,
    const float* __restrict__ fa,
    const float* __restrict__ fb, const float* __restrict__ fbb,
    const float* __restrict__ fc, const float* __restrict__ fcb,
    const float* __restrict__ pin, float* __restrict__ pout){
  __shared__ __align__(16) float y1[16][512];
  __shared__ __align__(16) float y2[16][516];
  __shared__ float pcoord[16][NIN];
  int b = blockIdx.y; int m0 = blockIdx.x*16; int tid = threadIdx.x;
  if (tid < 16*NIN){
    int p = tid / NIN, c = tid % NIN;
    int mm = min(m0 + p, M_-1);
    float v;
    if (NIN == 2){
      const float step = 0.6f/44.f;
      int ii = (c == 0) ? (mm/GRID_) : (mm%GRID_);
      v = -0.3f + step*ii;
    } else {
      v = pin[((size_t)b*M_ + mm)*3 + c];
    }
    pcoord[p][c] = v;
  }
  __syncthreads();
  const int stride_a = 512 + NIN;
  for (int rep = 0; rep < 2; ++rep){
    int o = rep*256 + tid;
    float av[NIN];
#pragma unroll
    for (int c = 0; c < NIN; ++c) av[c] = fa[(size_t)o*stride_a + 512 + c];
    float bv = base[b*512 + o];
#pragma unroll
    for (int p = 0; p < 16; ++p){
      float acc = bv;
#pragma unroll
      for (int c = 0; c < NIN; ++c) acc = fmaf(av[c], pcoord[p][c], acc);
      y1[p][o] = fmaxf(acc, 0.f);
    }
  }
  __syncthreads();
  {
    const float* wr0 = fb + (size_t)tid*512;
    const float* wr1 = fb + (size_t)(tid+256)*512;
    float a0[16], a1[16];
#pragma unroll
    for (int u = 0; u < 16; ++u){ a0[u] = 0.f; a1[u] = 0.f; }
    for (int c4 = 0; c4 < 128; ++c4){
      float4 w0 = *(const float4*)&wr0[c4*4];
      float4 w1 = *(const float4*)&wr1[c4*4];
#pragma unroll
      for (int u = 0; u < 16; ++u){
        float4 yv = *(const float4*)&y1[u][c4*4];
        a0[u] = fmaf(w0.x,yv.x,a0[u]); a0[u] = fmaf(w0.y,yv.y,a0[u]);
        a0[u] = fmaf(w0.z,yv.z,a0[u]); a0[u] = fmaf(w0.w,yv.w,a0[u]);
        a1[u] = fmaf(w1.x,yv.x,a1[u]); a1[u] = fmaf(w1.y,yv.y,a1[u]);
        a1[u] = fmaf(w1.z,yv.z,a1[u]); a1[u] = fmaf(w1.w,yv.w,a1[u]);
      }
    }
    float b0 = fbb[tid], b1 = fbb[tid+256];
#pragma unroll
    for (int u = 0; u < 16; ++u){
      y2[u][tid]     = fmaxf(a0[u] + b0, 0.f);
      y2[u][tid+256] = fmaxf(a1[u] + b1, 0.f);
    }
  }
  __syncthreads();
  if (tid < 48){
    int p = tid / 3, c = tid % 3;
    const float* wr = fc + (size_t)c*512;
    float acc = fcb[c];
    for (int o4 = 0; o4 < 128; ++o4){
      float4 wv = *(const float4*)&wr[o4*4];
      float4 yv = *(const float4*)&y2[p][o4*4];
      acc = fmaf(wv.x,yv.x,acc); acc = fmaf(wv.y,yv.y,acc);
      acc = fmaf(wv.z,yv.z,acc); acc = fmaf(wv.w,yv.w,acc);
    }
    int mm = m0 + p;
    if (mm < M_) pout[((size_t)b*M_ + mm)*3 + c] = acc;
  }
}

// ---------- launcher ----------
extern "C" void kernel_launch(void* const* d_in, const int* in_sizes, int n_in,
                              void* d_out, int out_size, void* d_ws, size_t ws_size,
                              hipStream_t stream){
  const float* pts  = (const float*)d_in[0];
  const float* w1   = (const float*)d_in[1];  const float* b1   = (const float*)d_in[2];
  const float* w2   = (const float*)d_in[3];  const float* b2   = (const float*)d_in[4];
  const float* w3   = (const float*)d_in[5];  const float* b3   = (const float*)d_in[6];
  const float* g1a  = (const float*)d_in[7];  const float* g1ab = (const float*)d_in[8];
  const float* g1b  = (const float*)d_in[9];  const float* g1bb = (const float*)d_in[10];
  const float* g2a  = (const float*)d_in[11]; const float* g2ab = (const float*)d_in[12];
  const float* g2b  = (const float*)d_in[13]; const float* g2bb = (const float*)d_in[14];
  const float* m1   = (const float*)d_in[15]; const float* m1b  = (const float*)d_in[16];
  const float* m2   = (const float*)d_in[17]; const float* m2b  = (const float*)d_in[18];
  const float* f1a  = (const float*)d_in[19]; const float* f1ab = (const float*)d_in[20];
  const float* f1b  = (const float*)d_in[21]; const float* f1bb = (const float*)d_in[22];
  const float* f1c  = (const float*)d_in[23]; const float* f1cb = (const float*)d_in[24];
  const float* f2a  = (const float*)d_in[25]; const float* f2ab = (const float*)d_in[26];
  const float* f2b  = (const float*)d_in[27]; const float* f2bb = (const float*)d_in[28];
  const float* f2c  = (const float*)d_in[29]; const float* f2cb = (const float*)d_in[30];
  float* out = (float*)d_out;

  char* w = (char*)d_ws;
  auto alloc = [&](size_t bytes){ char* p = w; w += (bytes + 255) & ~(size_t)255; return p; };
  unsigned long long* nn64 = (unsigned long long*)alloc((size_t)B_*N_*8);
  float* x    = (float*)alloc((size_t)B_*N_*64*4);
  float* g    = (float*)alloc((size_t)B_*N_*128*4);
  unsigned short* T64  = (unsigned short*)alloc((size_t)B_*4*4*N_*16);   //  8MB
  unsigned short* T128 = (unsigned short*)alloc((size_t)B_*8*4*N_*16);   // 16MB
  float* ccf  = (float*)alloc((size_t)B_*N_*4);
  int*   idx  = (int*)alloc((size_t)B_*N_*16*4);
  ull*   qkeys = (ull*)alloc((size_t)B_*N_*4*2*16*8);                    // 32MB
  unsigned int* glob = (unsigned int*)alloc((size_t)B_*1024*4);
  float* base1 = (float*)alloc((size_t)B_*512*4);
  float* base2 = (float*)alloc((size_t)B_*512*4);
  float* mid   = (float*)alloc((size_t)B_*M_*3*4);
  (void)ws_size; (void)in_sizes; (void)n_in; (void)out_size;

  const int SMEM4 = 4*4096 + 256;    // 16,640 B
  const int SMEM8 = 8*4096 + 256;    // 33,024 B
  hipFuncSetAttribute((const void*)k_knnF<4,2,2>, hipFuncAttributeMaxDynamicSharedMemorySize, SMEM4);
  hipFuncSetAttribute((const void*)k_knnF<8,2,2>, hipFuncAttributeMaxDynamicSharedMemorySize, SMEM8);

  hipMemsetAsync(nn64, 0xFF, (size_t)B_*N_*8, stream);
  k_init<<<dim3((B_*1024+255)/256), 256, 0, stream>>>(glob);
  k_nn1<<<dim3(N_/256, 4, B_), 256, 0, stream>>>(pts, nn64);
  k_cov_mlp<<<dim3(N_/64, B_), 256, 0, stream>>>(pts, nn64, w1,b1,w2,b2,w3,b3, x, T64, ccf);

  k_knnF<4,2,2><<<dim3(N_/128, 2, B_), 256, SMEM4, stream>>>(T64, ccf, qkeys);
  k_sel<2><<<dim3(B_*N_/256), 256, 0, stream>>>(qkeys, idx);

  k_gpool_mlp<<<dim3(N_/64, B_), 256, 0, stream>>>(x, idx, g1a,g1ab,g1b,g1bb, g);

  k_prep4<8><<<dim3(N_/256, B_), 256, 0, stream>>>(g, T128, ccf);
  k_knnF<8,2,2><<<dim3(N_/128, 2, B_), 256, SMEM8, stream>>>(T128, ccf, qkeys);
  k_sel<2><<<dim3(B_*N_/256), 256, 0, stream>>>(qkeys, idx);

  k_hpool_max<<<dim3(N_/32, B_), 256, 0, stream>>>(g, idx, g2a,g2ab,g2b,g2bb, glob);
  k_code<<<dim3(B_), 512, 0, stream>>>(glob, m1,m1b,m2,m2b, f1a,f1ab, f2a,f2ab, base1, base2);
  k_fold<2><<<dim3((M_+15)/16, B_), 256, 0, stream>>>(base1, f1a, f1b, f1bb, f1c, f1cb, nullptr, mid);
  k_fold<3><<<dim3((M_+15)/16, B_), 256, 0, stream>>>(base2, f2a, f2b, f2bb, f2c, f2cb, mid, out);
}

// Round 17
// 1499.590 us; speedup vs baseline: 1.2482x; 1.0452x over previous
//
#include <hip/hip_runtime.h>
#include <stdint.h>

#define B_ 4
#define N_ 8192
#define K_ 16
#define FEAT_ 512
#define GRID_ 45
#define M_ (GRID_*GRID_)

typedef unsigned long long ull;
typedef __bf16 bf16x8 __attribute__((ext_vector_type(8)));
typedef float f32x16 __attribute__((ext_vector_type(16)));

// ---------- helpers ----------

__device__ __forceinline__ unsigned int fmap(float f){
  unsigned int u = __float_as_uint(f);
  return (u & 0x80000000u) ? ~u : (u | 0x80000000u);
}
__device__ __forceinline__ float funmap(unsigned int u){
  return (u & 0x80000000u) ? __uint_as_float(u ^ 0x80000000u) : __uint_as_float(~u);
}

// stable u32-key/u32-idx sorted insert, strict < : ascending-idx scan order
// reproduces (dist, idx) lex semantics exactly.
__device__ __forceinline__ void ins16b(unsigned (&dk)[16], unsigned (&di)[16],
                                       unsigned k, unsigned id){
  if (k < dk[15]){
    bool c[16];
#pragma unroll
    for (int s = 0; s < 16; ++s) c[s] = k < dk[s];
#pragma unroll
    for (int s = 15; s >= 1; --s){
      dk[s] = c[s-1] ? dk[s-1] : (c[s] ? k  : dk[s]);
      di[s] = c[s-1] ? di[s-1] : (c[s] ? id : di[s]);
    }
    if (c[0]){ dk[0] = k; di[0] = id; }
  }
}

// bitonic cleanup sort of a 16-element bitonic sequence (ascending)
__device__ __forceinline__ void bsort16(ull (&c)[16]){
#pragma unroll
  for (int d = 8; d >= 1; d >>= 1){
#pragma unroll
    for (int i = 0; i < 16; ++i){
      if (!(i & d)){
        ull x = c[i], y = c[i|d];
        bool lt = x < y;
        c[i]   = lt ? x : y;
        c[i|d] = lt ? y : x;
      }
    }
  }
}
// merge two sorted-ascending 16-lists -> sorted-ascending lowest 16 of union
__device__ __forceinline__ void bmerge16(ull (&a)[16], const ull (&b)[16]){
#pragma unroll
  for (int i = 0; i < 16; ++i){
    ull bv = b[15-i];
    a[i] = a[i] < bv ? a[i] : bv;
  }
  bsort16(a);
}

__device__ __forceinline__ void bsplit(float x, unsigned short& h, unsigned short& l){
  __bf16 hh = (__bf16)x;
  __bf16 ll = (__bf16)(x - (float)hh);
  h = __builtin_bit_cast(unsigned short, hh);
  l = __builtin_bit_cast(unsigned short, ll);
}

#define GLDS16(l, g) __builtin_amdgcn_global_load_lds((const __attribute__((address_space(1))) void*)(g), (__attribute__((address_space(3))) void*)(l), 16, 0, 0)
#define GLDS4(l, g)  __builtin_amdgcn_global_load_lds((const __attribute__((address_space(1))) void*)(g), (__attribute__((address_space(3))) void*)(l), 4, 0, 0)

#define KEY_INF 0xFF800000FFFFFFFFull

// ---------- init ----------
__global__ void k_init(unsigned int* glob){
  int i = blockIdx.x*256 + threadIdx.x;
  if (i < B_*1024) glob[i] = 0x007FFFFFu;   // fmap(-inf)
}

// ---------- KNN #1: nearest other point (exact fp32, float4 LDS) ----------
__global__ __launch_bounds__(256) void k_nn1(const float* __restrict__ pts,
                                             unsigned long long* __restrict__ nn64){
  __shared__ __align__(16) float sp4[2048][4];
  int b = blockIdx.z, s = blockIdx.y;
  int c0 = s*2048;
  const float* P = pts + (size_t)b*N_*3;
  for (int p = threadIdx.x; p < 2048; p += 256){
    const float* src = P + (size_t)(c0 + p)*3;
    sp4[p][0] = src[0]; sp4[p][1] = src[1]; sp4[p][2] = src[2]; sp4[p][3] = 0.f;
  }
  __syncthreads();
  int n = blockIdx.x*256 + threadIdx.x;
  float qx = P[n*3], qy = P[n*3+1], qz = P[n*3+2];
  float best = 1e30f; int bi = 0;
  for (int j = 0; j < 2048; ++j){
    float4 sv = *(const float4*)sp4[j];
    float dx = qx - sv.x, dy = qy - sv.y, dz = qz - sv.z;
    float d2 = fmaf(dx,dx, fmaf(dy,dy, dz*dz));
    int cj = c0 + j;
    if (d2 < best && cj != n){ best = d2; bi = cj; }
  }
  unsigned long long key = ((unsigned long long)__float_as_uint(best) << 32) | (unsigned int)bi;
  atomicMin(&nn64[(size_t)b*N_ + n], key);
}

// ---------- local_cov + 3 convs + fused T64/cc emit (phases 2/3 reg-tiled) ----------
__global__ __launch_bounds__(256) void k_cov_mlp(const float* __restrict__ pts,
    const unsigned long long* __restrict__ nn64,
    const float* __restrict__ w1, const float* __restrict__ b1,
    const float* __restrict__ w2, const float* __restrict__ b2,
    const float* __restrict__ w3, const float* __restrict__ b3,
    float* __restrict__ xout, unsigned short* __restrict__ T,
    float* __restrict__ cc){
  __shared__ __align__(16) float W1t[12*64];
  __shared__ __align__(16) float W2t[64*64];
  __shared__ __align__(16) float W3t[64*64];
  __shared__ float B1[64], B2[64], B3[64];
  __shared__ __align__(16) float x0[64][12];
  __shared__ __align__(16) float h1[64][64];
  __shared__ __align__(16) float h2[64][64];
  int b = blockIdx.y; int n0 = blockIdx.x*64; int tid = threadIdx.x;
  for (int i = tid; i < 12*64; i += 256){ int o = i % 64, ci = i / 64; W1t[i] = w1[o*12 + ci]; }
  for (int i = tid; i < 64*64; i += 256){ int o = i % 64, ci = i / 64; W2t[i] = w2[o*64 + ci]; W3t[i] = w3[o*64 + ci]; }
  if (tid < 64){ B1[tid]=b1[tid]; B2[tid]=b2[tid]; B3[tid]=b3[tid]; }
  {
    int p = tid % 64, cg = tid / 64;
    int n = n0 + p;
    const float* P = pts + ((size_t)b*N_ + n)*3;
    int nb = (int)(nn64[(size_t)b*N_ + n] & 0xFFFFFFFFull);
    const float* Q = pts + ((size_t)b*N_ + nb)*3;
    if (cg == 0){ x0[p][0]=P[0]; x0[p][1]=P[1]; x0[p][2]=P[2]; }
    else { int i = cg-1; float pi = P[i];
      x0[p][3+i*3+0]=pi*Q[0]; x0[p][3+i*3+1]=pi*Q[1]; x0[p][3+i*3+2]=pi*Q[2]; }
  }
  __syncthreads();
  { int o = tid % 64, pg = tid / 64;
    for (int p = pg; p < 64; p += 4){
      float acc = B1[o];
#pragma unroll
      for (int ci = 0; ci < 12; ++ci) acc = fmaf(W1t[ci*64+o], x0[p][ci], acc);
      h1[p][o] = fmaxf(acc, 0.f);
    } }
  __syncthreads();
  { // phase 2: 2ch x 8pt register tile
    int o = tid & 31, pg = tid >> 5;
    float a0[8], a1[8];
#pragma unroll
    for (int u = 0; u < 8; ++u){ a0[u] = B2[o]; a1[u] = B2[o+32]; }
    for (int ci = 0; ci < 64; ci += 4){
      float w00=W2t[ci*64+o],      w01=W2t[(ci+1)*64+o],      w02=W2t[(ci+2)*64+o],      w03=W2t[(ci+3)*64+o];
      float w10=W2t[ci*64+o+32],   w11=W2t[(ci+1)*64+o+32],   w12=W2t[(ci+2)*64+o+32],   w13=W2t[(ci+3)*64+o+32];
#pragma unroll
      for (int u = 0; u < 8; ++u){
        float4 hv = *(const float4*)&h1[pg*8+u][ci];
        a0[u] = fmaf(w00,hv.x,a0[u]); a0[u] = fmaf(w01,hv.y,a0[u]);
        a0[u] = fmaf(w02,hv.z,a0[u]); a0[u] = fmaf(w03,hv.w,a0[u]);
        a1[u] = fmaf(w10,hv.x,a1[u]); a1[u] = fmaf(w11,hv.y,a1[u]);
        a1[u] = fmaf(w12,hv.z,a1[u]); a1[u] = fmaf(w13,hv.w,a1[u]);
      }
    }
#pragma unroll
    for (int u = 0; u < 8; ++u){
      h2[pg*8+u][o]    = fmaxf(a0[u], 0.f);
      h2[pg*8+u][o+32] = fmaxf(a1[u], 0.f);
    }
  }
  __syncthreads();
  { // phase 3: 2ch x 8pt register tile; write x + stash in h1
    int o = tid & 31, pg = tid >> 5;
    float a0[8], a1[8];
#pragma unroll
    for (int u = 0; u < 8; ++u){ a0[u] = B3[o]; a1[u] = B3[o+32]; }
    for (int ci = 0; ci < 64; ci += 4){
      float w00=W3t[ci*64+o],      w01=W3t[(ci+1)*64+o],      w02=W3t[(ci+2)*64+o],      w03=W3t[(ci+3)*64+o];
      float w10=W3t[ci*64+o+32],   w11=W3t[(ci+1)*64+o+32],   w12=W3t[(ci+2)*64+o+32],   w13=W3t[(ci+3)*64+o+32];
#pragma unroll
      for (int u = 0; u < 8; ++u){
        float4 hv = *(const float4*)&h2[pg*8+u][ci];
        a0[u] = fmaf(w00,hv.x,a0[u]); a0[u] = fmaf(w01,hv.y,a0[u]);
        a0[u] = fmaf(w02,hv.z,a0[u]); a0[u] = fmaf(w03,hv.w,a0[u]);
        a1[u] = fmaf(w10,hv.x,a1[u]); a1[u] = fmaf(w11,hv.y,a1[u]);
        a1[u] = fmaf(w12,hv.z,a1[u]); a1[u] = fmaf(w13,hv.w,a1[u]);
      }
    }
#pragma unroll
    for (int u = 0; u < 8; ++u){
      int p = pg*8 + u;
      float r0 = fmaxf(a0[u], 0.f), r1 = fmaxf(a1[u], 0.f);
      xout[((size_t)b*N_ + n0 + p)*64 + o]      = r0;
      xout[((size_t)b*N_ + n0 + p)*64 + o + 32] = r1;
      h1[p][o] = r0; h1[p][o+32] = r1;
    }
  }
  __syncthreads();
  // fused prep<4>: granule emit (8 bf16 ch per 16B) + per-row norms
  {
    char* Tb = (char*)T;
    const size_t HS = (size_t)N_*16, PS = 2*HS, KS = 4*HS;
    const size_t Bb = (size_t)b*4*KS;
    for (int e = tid; e < 64*8; e += 256){
      int p = e >> 3, gg = e & 7;
      int kf = gg >> 1, h = gg & 1;
      unsigned short hs[8], ls[8];
#pragma unroll
      for (int j = 0; j < 8; ++j) bsplit(h1[p][gg*8+j], hs[j], ls[j]);
      size_t base = Bb + (size_t)kf*KS + (size_t)h*HS + (size_t)(n0+p)*16;
      *(uint4*)(Tb + base)      = *(uint4*)hs;
      *(uint4*)(Tb + base + PS) = *(uint4*)ls;
    }
    if (tid < 64){
      float ss = 0.f;
#pragma unroll 8
      for (int c = 0; c < 64; ++c){ float v = h1[tid][(c + tid) & 63]; ss = fmaf(v, v, ss); }
      cc[(size_t)b*N_ + n0 + tid] = ss;
    }
  }
}

// ---------- prep: bf16 hi/lo split into K-major granule layout + norms ----------
template<int KF>
__global__ __launch_bounds__(256) void k_prep4(const float* __restrict__ f,
    unsigned short* __restrict__ T, float* __restrict__ cc){
  int b = blockIdx.y; int n = blockIdx.x*256 + threadIdx.x;
  const float* src = f + ((size_t)b*N_ + n)*(KF*16);
  char* Tb = (char*)T;
  float ss = 0.f;
#pragma unroll
  for (int kf = 0; kf < KF; ++kf){
    float v[16];
#pragma unroll
    for (int c4 = 0; c4 < 4; ++c4){
      float4 t4 = *(const float4*)&src[kf*16 + c4*4];
      v[c4*4]=t4.x; v[c4*4+1]=t4.y; v[c4*4+2]=t4.z; v[c4*4+3]=t4.w;
    }
    unsigned short hs[16], ls[16];
#pragma unroll
    for (int c = 0; c < 16; ++c){
      float x = v[c];
      ss = fmaf(x, x, ss);
      bsplit(x, hs[c], ls[c]);
    }
    size_t base = ((((size_t)b*KF + kf)*2)*2)*(size_t)(N_*16) + (size_t)n*16;
    const size_t HS = (size_t)N_*16;
    const size_t PS = 2*HS;
    *(uint4*)(Tb + base)            = *(uint4*)&hs[0];
    *(uint4*)(Tb + base + HS)       = *(uint4*)&hs[8];
    *(uint4*)(Tb + base + PS)       = *(uint4*)&ls[0];
    *(uint4*)(Tb + base + PS + HS)  = *(uint4*)&ls[8];
  }
  cc[(size_t)b*N_ + n] = ss;
}

// ---------- fused single-pass KNN: MFMA + gated stable u32 top-16 ----------
template<int KF, int MW, int S>
__global__ __launch_bounds__(256, MW) void k_knnF(const unsigned short* __restrict__ T,
    const float* __restrict__ ccg, ull* __restrict__ qkeys){
  extern __shared__ char smem[];
  constexpr int NT = (N_/S)/64;
  char* As = smem;                    // KF*4096
  char* Cs = smem + KF*4096;          // 256

  const int tid = threadIdx.x, lane = tid & 63, wid = tid >> 6;
  const int hi = lane >> 5, l31 = lane & 31;
  const int b = blockIdx.z, sp = blockIdx.y, q0 = blockIdx.x*128;
  const int c0 = sp*(N_/S);
  const char* Tb = (const char*)T;
  const size_t HS = (size_t)N_*16, PS = 2*HS, KS = 4*HS;
  const size_t Bb = (size_t)b*KF*KS;
  const float* ccb = ccg + (size_t)b*N_;

  const int q = q0 + wid*32 + l31;
  bf16x8 qh[KF], ql[KF];
#pragma unroll
  for (int kf = 0; kf < KF; ++kf){
    size_t o = Bb + kf*KS + hi*HS + (size_t)q*16;
    qh[kf] = *(const bf16x8*)(Tb + o);
    ql[kf] = *(const bf16x8*)(Tb + o + PS);
  }

  unsigned dk[16], di[16];
#pragma unroll
  for (int t = 0; t < 16; ++t){ dk[t] = 0xFFFFFFFFu; di[t] = 0xFFFFFFFFu; }
  float kapf = __builtin_inff();

  auto stage = [&](int t0){
#pragma unroll
    for (int si = 0; si < KF; ++si){
      int s = wid + 4*si;
      int kf = s >> 2, pl = (s >> 1) & 1, h = s & 1;
      GLDS16(As + s*1024,
             Tb + Bb + kf*KS + pl*PS + h*HS + (size_t)(c0 + t0)*16);
    }
    if (wid == 0) GLDS4(Cs, (const char*)(ccb + c0 + t0));
  };

  for (int t = 0; t < NT; ++t){
    const int t0 = t*64;
    __syncthreads();
    stage(t0);
    asm volatile("s_waitcnt vmcnt(0)" ::: "memory");
    __syncthreads();

    const char* Ab = As + hi*1024 + l31*16;
    const float* cct = (const float*)Cs;
#pragma unroll
    for (int i = 0; i < 2; ++i){
      f32x16 acc = (f32x16)(0.f);
#pragma unroll
      for (int kf = 0; kf < KF; ++kf){
        bf16x8 ah = *(const bf16x8*)(Ab + kf*4096 + i*512);
        bf16x8 al = *(const bf16x8*)(Ab + kf*4096 + 2048 + i*512);
        acc = __builtin_amdgcn_mfma_f32_32x32x16_bf16(ah, qh[kf], acc, 0, 0, 0);
        acc = __builtin_amdgcn_mfma_f32_32x32x16_bf16(ah, ql[kf], acc, 0, 0, 0);
        acc = __builtin_amdgcn_mfma_f32_32x32x16_bf16(al, qh[kf], acc, 0, 0, 0);
      }
#pragma unroll
      for (int rq = 0; rq < 4; ++rq){
        float4 c4 = *(const float4*)(cct + i*32 + 4*hi + 8*rq);
        int rowb = c0 + t0 + i*32 + 4*hi + 8*rq;
        float v0 = fmaf(-2.f, acc[rq*4+0], c4.x);
        float v1 = fmaf(-2.f, acc[rq*4+1], c4.y);
        float v2 = fmaf(-2.f, acc[rq*4+2], c4.z);
        float v3 = fmaf(-2.f, acc[rq*4+3], c4.w);
        if (fminf(fminf(v0, v1), fminf(v2, v3)) < kapf){
          if (v0 < kapf) ins16b(dk, di, fmap(v0), (unsigned)(rowb+0));
          if (v1 < kapf) ins16b(dk, di, fmap(v1), (unsigned)(rowb+1));
          if (v2 < kapf) ins16b(dk, di, fmap(v2), (unsigned)(rowb+2));
          if (v3 < kapf) ins16b(dk, di, fmap(v3), (unsigned)(rowb+3));
          unsigned kk = dk[15];
          kapf = (kk >= 0xFF800000u) ? __builtin_inff() : funmap(kk);
        }
      }
    }
  }
  ull* op = qkeys + (((size_t)((size_t)b*N_ + q)*S + sp)*2 + hi)*16;
#pragma unroll
  for (int t = 0; t < 16; ++t) op[t] = ((ull)dk[t] << 32) | di[t];
}

// ---------- final exact top-16: bitonic tree-merge of S*2 sorted regions ----------
template<int S>
__global__ void k_sel(const ull* __restrict__ qkeys, int* __restrict__ idxout){
  int i = blockIdx.x*256 + threadIdx.x;
  if (i >= B_*N_) return;
  const ull* kp = qkeys + (size_t)i*(S*32);
  ull a[16], t[16];
#pragma unroll
  for (int u = 0; u < 16; ++u) a[u] = kp[u];
#pragma unroll
  for (int r = 1; r < S*2; ++r){
#pragma unroll
    for (int u = 0; u < 16; ++u) t[u] = kp[r*16 + u];
    bmerge16(a, t);
  }
  int* op = idxout + (size_t)i*16;
#pragma unroll
  for (int u = 0; u < 16; ++u) op[u] = (int)(a[u] & 0xffffffffu);
}

// ---------- maxpool(x) + conv 64->64 relu + conv 64->128 (reg-tiled) ----------
__global__ __launch_bounds__(256) void k_gpool_mlp(const float* __restrict__ x,
    const int* __restrict__ idx,
    const float* __restrict__ g1a, const float* __restrict__ g1ab,
    const float* __restrict__ g1b, const float* __restrict__ g1bb,
    float* __restrict__ gout){
  __shared__ __align__(16) float Wt1[64*64];
  __shared__ __align__(16) float Wt2[64*128];
  __shared__ float Ba[64], Bb[128];
  __shared__ __align__(16) float m[64][64];
  __shared__ __align__(16) float r[64][64];
  int b = blockIdx.y; int n0 = blockIdx.x*64; int tid = threadIdx.x;
  for (int i = tid; i < 64*64; i += 256){ int o = i%64, ci = i/64; Wt1[i] = g1a[o*64+ci]; }
  for (int i = tid; i < 64*128; i += 256){ int o = i%128, ci = i/128; Wt2[i] = g1b[o*64+ci]; }
  if (tid < 64) Ba[tid] = g1ab[tid];
  if (tid < 128) Bb[tid] = g1bb[tid];
  { int p = tid/4, cg = tid%4; int n = n0 + p;
    const int* ip = idx + ((size_t)b*N_ + n)*16;
    float mm[16];
#pragma unroll
    for (int u = 0; u < 16; ++u) mm[u] = -1e30f;
    for (int k = 0; k < 16; ++k){
      int nb = ip[k];
      const float4* src = (const float4*)(x + ((size_t)b*N_ + nb)*64 + cg*16);
#pragma unroll
      for (int u = 0; u < 4; ++u){
        float4 v = src[u];
        mm[4*u  ] = fmaxf(mm[4*u  ], v.x); mm[4*u+1] = fmaxf(mm[4*u+1], v.y);
        mm[4*u+2] = fmaxf(mm[4*u+2], v.z); mm[4*u+3] = fmaxf(mm[4*u+3], v.w);
      }
    }
#pragma unroll
    for (int u = 0; u < 16; ++u) m[p][cg*16+u] = mm[u];
  }
  __syncthreads();
  { // conv1 64->64: 2ch x 8pt register tile
    int o = tid & 31, pg = tid >> 5;
    float a0[8], a1[8];
#pragma unroll
    for (int u = 0; u < 8; ++u){ a0[u] = Ba[o]; a1[u] = Ba[o+32]; }
    for (int ci = 0; ci < 64; ci += 4){
      float w00=Wt1[ci*64+o],      w01=Wt1[(ci+1)*64+o],      w02=Wt1[(ci+2)*64+o],      w03=Wt1[(ci+3)*64+o];
      float w10=Wt1[ci*64+o+32],   w11=Wt1[(ci+1)*64+o+32],   w12=Wt1[(ci+2)*64+o+32],   w13=Wt1[(ci+3)*64+o+32];
#pragma unroll
      for (int u = 0; u < 8; ++u){
        float4 mv = *(const float4*)&m[pg*8+u][ci];
        a0[u] = fmaf(w00,mv.x,a0[u]); a0[u] = fmaf(w01,mv.y,a0[u]);
        a0[u] = fmaf(w02,mv.z,a0[u]); a0[u] = fmaf(w03,mv.w,a0[u]);
        a1[u] = fmaf(w10,mv.x,a1[u]); a1[u] = fmaf(w11,mv.y,a1[u]);
        a1[u] = fmaf(w12,mv.z,a1[u]); a1[u] = fmaf(w13,mv.w,a1[u]);
      }
    }
#pragma unroll
    for (int u = 0; u < 8; ++u){
      r[pg*8+u][o]    = fmaxf(a0[u], 0.f);
      r[pg*8+u][o+32] = fmaxf(a1[u], 0.f);
    }
  }
  __syncthreads();
  { // conv2 64->128 (no relu): 2ch x 16pt register tile
    int o = tid & 63, pg = tid >> 6;
    float a0[16], a1[16];
#pragma unroll
    for (int u = 0; u < 16; ++u){ a0[u] = Bb[o]; a1[u] = Bb[o+64]; }
    for (int ci = 0; ci < 64; ci += 4){
      float w00=Wt2[ci*128+o],      w01=Wt2[(ci+1)*128+o],      w02=Wt2[(ci+2)*128+o],      w03=Wt2[(ci+3)*128+o];
      float w10=Wt2[ci*128+o+64],   w11=Wt2[(ci+1)*128+o+64],   w12=Wt2[(ci+2)*128+o+64],   w13=Wt2[(ci+3)*128+o+64];
#pragma unroll
      for (int u = 0; u < 16; ++u){
        float4 rv = *(const float4*)&r[pg*16+u][ci];
        a0[u] = fmaf(w00,rv.x,a0[u]); a0[u] = fmaf(w01,rv.y,a0[u]);
        a0[u] = fmaf(w02,rv.z,a0[u]); a0[u] = fmaf(w03,rv.w,a0[u]);
        a1[u] = fmaf(w10,rv.x,a1[u]); a1[u] = fmaf(w11,rv.y,a1[u]);
        a1[u] = fmaf(w12,rv.z,a1[u]); a1[u] = fmaf(w13,rv.w,a1[u]);
      }
    }
#pragma unroll
    for (int u = 0; u < 16; ++u){
      gout[((size_t)b*N_ + n0 + pg*16 + u)*128 + o]      = a0[u];
      gout[((size_t)b*N_ + n0 + pg*16 + u)*128 + o + 64] = a1[u];
    }
  }
}

// ---------- maxpool(g) + conv 128->128 relu + conv 128->1024 + global max ----------
__global__ __launch_bounds__(256) void k_hpool_max(const float* __restrict__ g,
    const int* __restrict__ idx,
    const float* __restrict__ g2a, const float* __restrict__ g2ab,
    const float* __restrict__ g2b, const float* __restrict__ g2bb,
    unsigned int* __restrict__ glob){
  __shared__ __align__(16) float m[32][128];
  __shared__ __align__(16) float t[32][128];
  int b = blockIdx.y; int n0 = blockIdx.x*32; int tid = threadIdx.x;
  { int p = tid/8, cg = tid%8; int n = n0+p;
    const int* ip = idx + ((size_t)b*N_+n)*16;
    float mm[16];
#pragma unroll
    for (int u = 0; u < 16; ++u) mm[u] = -1e30f;
    for (int k = 0; k < 16; ++k){
      int nb = ip[k];
      const float4* src = (const float4*)(g + ((size_t)b*N_+nb)*128 + cg*16);
#pragma unroll
      for (int u = 0; u < 4; ++u){
        float4 v = src[u];
        mm[4*u  ] = fmaxf(mm[4*u  ], v.x); mm[4*u+1] = fmaxf(mm[4*u+1], v.y);
        mm[4*u+2] = fmaxf(mm[4*u+2], v.z); mm[4*u+3] = fmaxf(mm[4*u+3], v.w);
      }
    }
#pragma unroll
    for (int u = 0; u < 16; ++u) m[p][cg*16+u] = mm[u];
  }
  __syncthreads();
  { int o = tid%128, pg = tid/128;
    float acc[16];
#pragma unroll
    for (int u = 0; u < 16; ++u) acc[u] = g2ab[o];
    const float4* wrow = (const float4*)(g2a + (size_t)o*128);
    for (int c4 = 0; c4 < 32; ++c4){
      float4 wv = wrow[c4];
#pragma unroll
      for (int u = 0; u < 16; ++u){
        float4 mv = *(const float4*)&m[pg*16+u][c4*4];
        acc[u] = fmaf(wv.x,mv.x,acc[u]); acc[u] = fmaf(wv.y,mv.y,acc[u]);
        acc[u] = fmaf(wv.z,mv.z,acc[u]); acc[u] = fmaf(wv.w,mv.w,acc[u]);
      }
    }
#pragma unroll
    for (int u = 0; u < 16; ++u) t[pg*16+u][o] = fmaxf(acc[u], 0.f);
  }
  __syncthreads();
  for (int op = 0; op < 2; ++op){
    int o0 = op*512 + tid;          // channels o0 and o0+256
    const float4* wr0 = (const float4*)(g2b + (size_t)o0*128);
    const float4* wr1 = (const float4*)(g2b + (size_t)(o0+256)*128);
    float a0[32], a1[32];
#pragma unroll
    for (int u = 0; u < 32; ++u){ a0[u] = 0.f; a1[u] = 0.f; }
    for (int c4 = 0; c4 < 32; ++c4){
      float4 w0 = wr0[c4], w1 = wr1[c4];
#pragma unroll
      for (int u = 0; u < 32; ++u){
        float4 tv = *(const float4*)&t[u][c4*4];
        a0[u] = fmaf(w0.x,tv.x,a0[u]); a0[u] = fmaf(w0.y,tv.y,a0[u]);
        a0[u] = fmaf(w0.z,tv.z,a0[u]); a0[u] = fmaf(w0.w,tv.w,a0[u]);
        a1[u] = fmaf(w1.x,tv.x,a1[u]); a1[u] = fmaf(w1.y,tv.y,a1[u]);
        a1[u] = fmaf(w1.z,tv.z,a1[u]); a1[u] = fmaf(w1.w,tv.w,a1[u]);
      }
    }
    float b0 = g2bb[o0], b1 = g2bb[o0+256];
    float mx0 = -1e30f, mx1 = -1e30f;
#pragma unroll
    for (int u = 0; u < 32; ++u){
      mx0 = fmaxf(mx0, a0[u] + b0);
      mx1 = fmaxf(mx1, a1[u] + b1);
    }
    atomicMax(&glob[b*1024 + o0],       fmap(mx0));
    atomicMax(&glob[b*1024 + o0 + 256], fmap(mx1));
  }
}

// ---------- code MLP + decoder base precompute ----------
__global__ __launch_bounds__(512) void k_code(const unsigned int* __restrict__ glob,
    const float* __restrict__ m1, const float* __restrict__ m1b,
    const float* __restrict__ m2, const float* __restrict__ m2b,
    const float* __restrict__ f1a, const float* __restrict__ f1ab,
    const float* __restrict__ f2a, const float* __restrict__ f2ab,
    float* __restrict__ base1, float* __restrict__ base2){
  __shared__ __align__(16) float gl_s[1024];
  __shared__ __align__(16) float hid_s[512];
  __shared__ __align__(16) float code_s[512];
  int b = blockIdx.x; int tid = threadIdx.x;
  for (int i = tid; i < 1024; i += 512) gl_s[i] = funmap(glob[b*1024+i]);
  __syncthreads();
  { float acc = m1b[tid];
    const float4* wr = (const float4*)(m1 + (size_t)tid*1024);
    for (int c4 = 0; c4 < 256; ++c4){ float4 wv = wr[c4]; float4 gv = *(const float4*)&gl_s[c4*4];
      acc = fmaf(wv.x,gv.x,acc); acc = fmaf(wv.y,gv.y,acc);
      acc = fmaf(wv.z,gv.z,acc); acc = fmaf(wv.w,gv.w,acc); }
    hid_s[tid] = fmaxf(acc, 0.f);
  }
  __syncthreads();
  { float acc = m2b[tid];
    const float4* wr = (const float4*)(m2 + (size_t)tid*512);
    for (int c4 = 0; c4 < 128; ++c4){ float4 wv = wr[c4]; float4 hv = *(const float4*)&hid_s[c4*4];
      acc = fmaf(wv.x,hv.x,acc); acc = fmaf(wv.y,hv.y,acc);
      acc = fmaf(wv.z,hv.z,acc); acc = fmaf(wv.w,hv.w,acc); }
    code_s[tid] = acc;
  }
  __syncthreads();
  { float acc = f1ab[tid];
    const float* wr = f1a + (size_t)tid*514;
    for (int c = 0; c < 512; ++c) acc = fmaf(wr[c], code_s[c], acc);
    base1[b*512 + tid] = acc;
  }
  { float acc = f2ab[tid];
    const float* wr = f2a + (size_t)tid*515;
    for (int c = 0; c < 512; ++c) acc = fmaf(wr[c], code_s[c], acc);
    base2[b*512 + tid] = acc;
  }
}

// ---------- folding decoder (16-pt tiles; phase-b: 2 channels/thread) ----------
template<int NIN>
__global__ __launch_bounds__(256) void k_fold(const float* __restrict__ base,
    const float* __restrict__ fa,
    const float* __restrict__ fb, const float* __restrict__ fbb,
    const float* __restrict__ fc, const float* __restrict__ fcb,
    const float* __restrict__ pin, float* __restrict__ pout){
  __shared__ __align__(16) float y1[16][512];
  __shared__ __align__(16) float y2[16][516];
  __shared__ float pcoord[16][NIN];
  int b = blockIdx.y; int m0 = blockIdx.x*16; int tid = threadIdx.x;
  if (tid < 16*NIN){
    int p = tid / NIN, c = tid % NIN;
    int mm = min(m0 + p, M_-1);
    float v;
    if (NIN == 2){
      const float step = 0.6f/44.f;
      int ii = (c == 0) ? (mm/GRID_) : (mm%GRID_);
      v = -0.3f + step*ii;
    } else {
      v = pin[((size_t)b*M_ + mm)*3 + c];
    }
    pcoord[p][c] = v;
  }
  __syncthreads();
  const int stride_a = 512 + NIN;
  for (int rep = 0; rep < 2; ++rep){
    int o = rep*256 + tid;
    float av[NIN];
#pragma unroll
    for (int c = 0; c < NIN; ++c) av[c] = fa[(size_t)o*stride_a + 512 + c];
    float bv = base[b*512 + o];
#pragma unroll
    for (int p = 0; p < 16; ++p){
      float acc = bv;
#pragma unroll
      for (int c = 0; c < NIN; ++c) acc = fmaf(av[c], pcoord[p][c], acc);
      y1[p][o] = fmaxf(acc, 0.f);
    }
  }
  __syncthreads();
  {
    const float* wr0 = fb + (size_t)tid*512;
    const float* wr1 = fb + (size_t)(tid+256)*512;
    float a0[16], a1[16];
#pragma unroll
    for (int u = 0; u < 16; ++u){ a0[u] = 0.f; a1[u] = 0.f; }
    for (int c4 = 0; c4 < 128; ++c4){
      float4 w0 = *(const float4*)&wr0[c4*4];
      float4 w1 = *(const float4*)&wr1[c4*4];
#pragma unroll
      for (int u = 0; u < 16; ++u){
        float4 yv = *(const float4*)&y1[u][c4*4];
        a0[u] = fmaf(w0.x,yv.x,a0[u]); a0[u] = fmaf(w0.y,yv.y,a0[u]);
        a0[u] = fmaf(w0.z,yv.z,a0[u]); a0[u] = fmaf(w0.w,yv.w,a0[u]);
        a1[u] = fmaf(w1.x,yv.x,a1[u]); a1[u] = fmaf(w1.y,yv.y,a1[u]);
        a1[u] = fmaf(w1.z,yv.z,a1[u]); a1[u] = fmaf(w1.w,yv.w,a1[u]);
      }
    }
    float b0 = fbb[tid], b1 = fbb[tid+256];
#pragma unroll
    for (int u = 0; u < 16; ++u){
      y2[u][tid]     = fmaxf(a0[u] + b0, 0.f);
      y2[u][tid+256] = fmaxf(a1[u] + b1, 0.f);
    }
  }
  __syncthreads();
  if (tid < 48){
    int p = tid / 3, c = tid % 3;
    const float* wr = fc + (size_t)c*512;
    float acc = fcb[c];
    for (int o4 = 0; o4 < 128; ++o4){
      float4 wv = *(const float4*)&wr[o4*4];
      float4 yv = *(const float4*)&y2[p][o4*4];
      acc = fmaf(wv.x,yv.x,acc); acc = fmaf(wv.y,yv.y,acc);
      acc = fmaf(wv.z,yv.z,acc); acc = fmaf(wv.w,yv.w,acc);
    }
    int mm = m0 + p;
    if (mm < M_) pout[((size_t)b*M_ + mm)*3 + c] = acc;
  }
}

// ---------- launcher ----------
extern "C" void kernel_launch(void* const* d_in, const int* in_sizes, int n_in,
                              void* d_out, int out_size, void* d_ws, size_t ws_size,
                              hipStream_t stream){
  const float* pts  = (const float*)d_in[0];
  const float* w1   = (const float*)d_in[1];  const float* b1   = (const float*)d_in[2];
  const float* w2   = (const float*)d_in[3];  const float* b2   = (const float*)d_in[4];
  const float* w3   = (const float*)d_in[5];  const float* b3   = (const float*)d_in[6];
  const float* g1a  = (const float*)d_in[7];  const float* g1ab = (const float*)d_in[8];
  const float* g1b  = (const float*)d_in[9];  const float* g1bb = (const float*)d_in[10];
  const float* g2a  = (const float*)d_in[11]; const float* g2ab = (const float*)d_in[12];
  const float* g2b  = (const float*)d_in[13]; const float* g2bb = (const float*)d_in[14];
  const float* m1   = (const float*)d_in[15]; const float* m1b  = (const float*)d_in[16];
  const float* m2   = (const float*)d_in[17]; const float* m2b  = (const float*)d_in[18];
  const float* f1a  = (const float*)d_in[19]; const float* f1ab = (const float*)d_in[20];
  const float* f1b  = (const float*)d_in[21]; const float* f1bb = (const float*)d_in[22];
  const float* f1c  = (const float*)d_in[23]; const float* f1cb = (const float*)d_in[24];
  const float* f2a  = (const float*)d_in[25]; const float* f2ab = (const float*)d_in[26];
  const float* f2b  = (const float*)d_in[27]; const float* f2bb = (const float*)d_in[28];
  const float* f2c  = (const float*)d_in[29]; const float* f2cb = (const float*)d_in[30];
  float* out = (float*)d_out;

  char* w = (char*)d_ws;
  auto alloc = [&](size_t bytes){ char* p = w; w += (bytes + 255) & ~(size_t)255; return p; };
  unsigned long long* nn64 = (unsigned long long*)alloc((size_t)B_*N_*8);
  float* x    = (float*)alloc((size_t)B_*N_*64*4);
  float* g    = (float*)alloc((size_t)B_*N_*128*4);
  unsigned short* T64  = (unsigned short*)alloc((size_t)B_*4*4*N_*16);   //  8MB
  unsigned short* T128 = (unsigned short*)alloc((size_t)B_*8*4*N_*16);   // 16MB
  float* ccf  = (float*)alloc((size_t)B_*N_*4);
  int*   idx  = (int*)alloc((size_t)B_*N_*16*4);
  ull*   qkeys = (ull*)alloc((size_t)B_*N_*4*2*16*8);                    // 32MB
  unsigned int* glob = (unsigned int*)alloc((size_t)B_*1024*4);
  float* base1 = (float*)alloc((size_t)B_*512*4);
  float* base2 = (float*)alloc((size_t)B_*512*4);
  float* mid   = (float*)alloc((size_t)B_*M_*3*4);
  (void)ws_size; (void)in_sizes; (void)n_in; (void)out_size;

  const int SMEM4 = 4*4096 + 256;    // 16,640 B
  const int SMEM8 = 8*4096 + 256;    // 33,024 B
  hipFuncSetAttribute((const void*)k_knnF<4,4,4>, hipFuncAttributeMaxDynamicSharedMemorySize, SMEM4);
  hipFuncSetAttribute((const void*)k_knnF<8,3,4>, hipFuncAttributeMaxDynamicSharedMemorySize, SMEM8);

  hipMemsetAsync(nn64, 0xFF, (size_t)B_*N_*8, stream);
  k_init<<<dim3((B_*1024+255)/256), 256, 0, stream>>>(glob);
  k_nn1<<<dim3(N_/256, 4, B_), 256, 0, stream>>>(pts, nn64);
  k_cov_mlp<<<dim3(N_/64, B_), 256, 0, stream>>>(pts, nn64, w1,b1,w2,b2,w3,b3, x, T64, ccf);

  k_knnF<4,4,4><<<dim3(N_/128, 4, B_), 256, SMEM4, stream>>>(T64, ccf, qkeys);
  k_sel<4><<<dim3(B_*N_/256), 256, 0, stream>>>(qkeys, idx);

  k_gpool_mlp<<<dim3(N_/64, B_), 256, 0, stream>>>(x, idx, g1a,g1ab,g1b,g1bb, g);

  k_prep4<8><<<dim3(N_/256, B_), 256, 0, stream>>>(g, T128, ccf);
  k_knnF<8,3,4><<<dim3(N_/128, 4, B_), 256, SMEM8, stream>>>(T128, ccf, qkeys);
  k_sel<4><<<dim3(B_*N_/256), 256, 0, stream>>>(qkeys, idx);

  k_hpool_max<<<dim3(N_/32, B_), 256, 0, stream>>>(g, idx, g2a,g2ab,g2b,g2bb, glob);
  k_code<<<dim3(B_), 512, 0, stream>>>(glob, m1,m1b,m2,m2b, f1a,f1ab, f2a,f2ab, base1, base2);
  k_fold<2><<<dim3((M_+15)/16, B_), 256, 0, stream>>>(base1, f1a, f1b, f1bb, f1c, f1cb, nullptr, mid);
  k_fold<3><<<dim3((M_+15)/16, B_), 256, 0, stream>>>(base2, f2a, f2b, f2bb, f2c, f2cb, mid, out);
}